// Round 7
// baseline (597.267 us; speedup 1.0000x reference)
//
#include <hip/hip_runtime.h>
#include <math.h>

#define NB 8
#define NC 64
#define NH 128
#define NW 128
#define NS 119
#define NPIX 113288   // 8*119*119

__device__ __forceinline__ float gelu_f(float v) {
    return 0.5f * v * (1.0f + erff(v * 0.70710678118654752f));
}

// ---------------- trig table: trig[t] = (cos, sin)(2*pi*t/128) ----------------
__global__ void __launch_bounds__(128) k_trig(float2* __restrict__ trig) {
    int t = threadIdx.x;
    double a = (double)t * (3.14159265358979323846 / 64.0);
    trig[t] = make_float2((float)cos(a), (float)sin(a));
}

// ---------------- DFT-W matrix: wd[ky*128+w] = e^{-2pi i ky w/128} ----------------
__global__ void __launch_bounds__(128) k_tab(float2* __restrict__ wd) {
    int idx = blockIdx.x * 128 + threadIdx.x;   // 0..2047
    int ky = idx >> 7, w = idx & 127;
    int prod = (ky * w) & 127;
    double a = (double)prod * (3.14159265358979323846 / 64.0);
    wd[idx] = make_float2((float)cos(a), (float)(-sin(a)));
}

// ---------------- transposes: fc1wT[c][j] = fc1w[j][c]; cwT[l][c][o] = cw[l][o][c] ----------------
__global__ void __launch_bounds__(256) k_tc(const float* __restrict__ fc1w,
                                            const float* __restrict__ cw,
                                            float* __restrict__ fc1wT,
                                            float* __restrict__ cwT) {
    int u = blockIdx.x * 256 + threadIdx.x;   // 0..24575
    if (u < 8192) {
        int c = u >> 7, j = u & 127;
        fc1wT[u] = fc1w[j * 64 + c];
    } else {
        int v = u - 8192;                      // 0..16383
        int l = v >> 12, idx = v & 4095;
        int c = idx >> 6, o = idx & 63;
        cwT[v] = cw[l * 4096 + o * 64 + c];
    }
}

// ---------------- fc0 + grid concat + transpose + zero pad ----------------
__global__ void __launch_bounds__(256) k_fc0(const float* __restrict__ x,
                                             const float* __restrict__ w,
                                             const float* __restrict__ bia,
                                             float* __restrict__ h) {
    __shared__ float sw[320];
    __shared__ float sb[64];
    int t = threadIdx.x;
    for (int u = t; u < 320; u += 256) sw[u] = w[u];
    if (t < 64) sb[t] = bia[t];
    __syncthreads();
    int p = blockIdx.x * 256 + t;            // 0 .. 131071
    int b = p >> 14;
    int rem = p & 16383;
    int r = rem >> 7, wc = rem & 127;
    float v0 = 0.f, v1 = 0.f, v2 = 0.f, gx = 0.f, gy = 0.f;
    bool inside = (r < NS) && (wc < NS);
    if (inside) {
        const float* xp = x + ((size_t)(b * NS + r) * NS + wc) * 3;
        v0 = xp[0]; v1 = xp[1]; v2 = xp[2];
        gx = (float)r * (1.0f / 118.0f);
        gy = (float)wc * (1.0f / 118.0f);
    }
    float* hp = h + (size_t)b * NC * NH * NW + rem;
    for (int c = 0; c < 64; ++c) {
        float val = 0.f;
        if (inside) {
            const float* wr = sw + c * 5;
            val = v0 * wr[0] + v1 * wr[1] + v2 * wr[2] + gx * wr[3] + gy * wr[4] + sb[c];
        }
        hp[c * (NH * NW)] = val;
    }
}

// ---------------- CFT coeffs: cr[b][c][16] ----------------
__global__ void __launch_bounds__(256) k_cft(const float* __restrict__ h,
                                             float* __restrict__ cr) {
    __shared__ float sv[256][9];
    __shared__ float sq[256];
    int t = threadIdx.x;
    int bc = blockIdx.x;                      // b*64 + c
    int r = t >> 3;
    int g8 = (t & 7) << 3;                    // 0,8,...,56
    const float* rowp = h + ((size_t)bc * NH + r) * NW + g8;
    float s2 = 0.f;
#pragma unroll
    for (int j = 0; j < 8; ++j) {
        float v = rowp[j];
        sv[t][j] = v;
        s2 += v * v;
    }
    sq[t] = s2;
    __syncthreads();
    if (t < 16) {
        int half = t >> 3, k = t & 7;
        float sum = 0.f, ssq = 0.f;
        for (int gg = 0; gg < 32; ++gg) {
            int tt = gg * 8 + half * 4;
#pragma unroll
            for (int i = 0; i < 4; ++i) {
                sum += sv[tt + i][k];
                ssq += sq[tt + i];
            }
        }
        float norm = fmaxf(sqrtf(ssq), 1e-12f);
        cr[bc * 16 + t] = sum / (128.0f * norm);
    }
}

// ---------------- MLP stage 1 ----------------
__global__ void __launch_bounds__(256) k_mlp1(const float* __restrict__ cr,
                                              const float* __restrict__ g1w,
                                              const float* __restrict__ g1b,
                                              float* __restrict__ hmid) {
    __shared__ float s_cr[8][1024];
    __shared__ float s_wave[4][8];
    int j = blockIdx.x;
    int t = threadIdx.x;
    {
        float* sp = &s_cr[0][0];
        for (int u = t; u < 8192; u += 256) sp[u] = cr[u];
    }
    const float* wrow = g1w + (size_t)j * 2048;
    int v0 = t * 4;
    float w0 = wrow[2 * v0], w1 = wrow[2 * v0 + 2], w2 = wrow[2 * v0 + 4], w3 = wrow[2 * v0 + 6];
    __syncthreads();
    float acc[8];
#pragma unroll
    for (int b = 0; b < 8; ++b) {
        const float* cp = s_cr[b] + v0;
        acc[b] = cp[0] * w0 + cp[1] * w1 + cp[2] * w2 + cp[3] * w3;
    }
#pragma unroll
    for (int d = 32; d > 0; d >>= 1) {
#pragma unroll
        for (int b = 0; b < 8; ++b) acc[b] += __shfl_down(acc[b], d, 64);
    }
    int wv = t >> 6;
    if ((t & 63) == 0) {
#pragma unroll
        for (int b = 0; b < 8; ++b) s_wave[wv][b] = acc[b];
    }
    __syncthreads();
    if (t < 8) {
        float a = s_wave[0][t] + s_wave[1][t] + s_wave[2][t] + s_wave[3][t] + g1b[j];
        hmid[t * 256 + j] = gelu_f(a);
    }
}

// ---------------- MLP stage 2 ----------------
__global__ void __launch_bounds__(256) k_mlp2(const float* __restrict__ hmid,
                                              const float* __restrict__ g2w,
                                              const float* __restrict__ g2b,
                                              float* __restrict__ corr) {
    __shared__ float s_h[2048];
    __shared__ float s_w[256];
    int o = blockIdx.x;
    int t = threadIdx.x;
    s_w[t] = g2w[o * 256 + t];
    for (int u = t; u < 2048; u += 256) s_h[u] = hmid[u];
    __syncthreads();
    int b = t >> 5, k = t & 31;
    const float* hp = s_h + b * 256 + k * 8;
    const float* wp = s_w + k * 8;
    float acc = 0.f;
#pragma unroll
    for (int i = 0; i < 8; ++i) acc += hp[i] * wp[i];
#pragma unroll
    for (int d = 16; d > 0; d >>= 1) acc += __shfl_down(acc, d, 32);
    if (k == 0) corr[b * 64 + o] = acc + g2b[o];
}

// ---------------- fused 2D partial DFT: one block per (b,c) ----------------
__global__ void __launch_bounds__(256) k_dft2(const float* __restrict__ h,
                                              float2* __restrict__ xft,
                                              const float2* __restrict__ wd,
                                              const float2* __restrict__ trig) {
    __shared__ __align__(16) float sx[16][132];
    __shared__ __align__(16) float2 sW[16][134];
    __shared__ float2 sT[128][17];
    __shared__ float2 st[128];
    int t = threadIdx.x;
    int bc = blockIdx.x;
    if (t < 128) st[t] = trig[t];
    for (int u = t; u < 2048; u += 256) sW[u >> 7][u & 127] = wd[u];
    const float* src = h + (size_t)bc * 16384;
    int r = t >> 4, ky = t & 15;
    for (int ch = 0; ch < 8; ++ch) {
        __syncthreads();
        for (int u = t; u < 2048; u += 256) sx[u >> 7][u & 127] = src[ch * 2048 + u];
        __syncthreads();
        const float* xr = sx[r];
        const float2* wk = sW[ky];
        float re = 0.f, im = 0.f;
#pragma unroll 8
        for (int w0 = 0; w0 < 128; w0 += 4) {
            float4 x4 = *(const float4*)(xr + w0);
            float4 w01 = *(const float4*)(wk + w0);
            float4 w23 = *(const float4*)(wk + w0 + 2);
            re += x4.x * w01.x; im += x4.x * w01.y;
            re += x4.y * w01.z; im += x4.y * w01.w;
            re += x4.z * w23.x; im += x4.z * w23.y;
            re += x4.w * w23.z; im += x4.w * w23.w;
        }
        sT[ch * 16 + r][ky] = make_float2(re, im);
    }
    __syncthreads();
    int mlo = t >> 4;
    int kxa = mlo, kxb = 112 + mlo;
    float2 sva = st[kxa]; float sca = sva.x, ssa = -sva.y;
    float2 svb = st[kxb]; float scb = svb.x, ssb = -svb.y;
    float rea = 0.f, ima = 0.f, reb = 0.f, imb = 0.f;
    for (int h0 = 0; h0 < 128; h0 += 16) {
        float2 bva = st[(kxa * h0) & 127]; float cca = bva.x, csa = -bva.y;
        float2 bvb = st[(kxb * h0) & 127]; float ccb = bvb.x, csb = -bvb.y;
#pragma unroll
        for (int j = 0; j < 16; ++j) {
            float2 Tv = sT[h0 + j][ky];
            rea += Tv.x * cca - Tv.y * csa;
            ima += Tv.x * csa + Tv.y * cca;
            reb += Tv.x * ccb - Tv.y * csb;
            imb += Tv.x * csb + Tv.y * ccb;
            float na = cca * sca - csa * ssa; csa = cca * ssa + csa * sca; cca = na;
            float nb = ccb * scb - csb * ssb; csb = ccb * ssb + csb * scb; ccb = nb;
        }
    }
    float2* xp = xft + (size_t)bc * 512;
    xp[mlo * 16 + ky] = make_float2(rea, ima);
    xp[(mlo + 16) * 16 + ky] = make_float2(reb, imb);
}

// ---------------- spectral channel mix ----------------
__global__ void __launch_bounds__(512) k_mix(const float2* __restrict__ xft,
                                             const float* __restrict__ w1r,
                                             const float* __restrict__ w1i,
                                             const float* __restrict__ w2r,
                                             const float* __restrict__ w2i,
                                             float2* __restrict__ F) {
    int rbid = blockIdx.x;
    int m = (rbid & 7) + 8 * ((rbid >> 3) & 3);   // XCD swizzle
    int e = rbid >> 5;                             // ky
    __shared__ float2 s_w[64][64];                 // [i][o]
    __shared__ float2 s_x[8][64];                  // [b][i]
    int t = threadIdx.x;
    const float* wr; const float* wi; int mm;
    if (m < 16) { wr = w1r; wi = w1i; mm = m; } else { wr = w2r; wi = w2i; mm = m - 16; }
    int off = mm * 16 + e;
    for (int u = t; u < 4096; u += 512) {
        s_w[u >> 6][u & 63] = make_float2(wr[(u << 8) + off], wi[(u << 8) + off]);
    }
    {
        int bb = t >> 6, i = t & 63;
        s_x[bb][i] = xft[((size_t)(bb * 64 + i) * 32 + m) * 16 + e];
    }
    __syncthreads();
    int bb = t >> 6, o = t & 63;
    float re = 0.f, im = 0.f;
#pragma unroll 8
    for (int i = 0; i < 64; ++i) {
        float2 xv = s_x[bb][i];
        float2 wv = s_w[i][o];
        re += xv.x * wv.x - xv.y * wv.y;
        im += xv.x * wv.y + xv.y * wv.x;
    }
    F[((size_t)(bb * 16 + e) * 32 + m) * 64 + o] = make_float2(re, im);
}

// ---------------- inverse step A ----------------
__global__ void __launch_bounds__(256) k_inva(const float2* __restrict__ F,
                                              float2* __restrict__ G,
                                              const float2* __restrict__ trig) {
    int blk = blockIdx.x;                     // (b, ky, hhalf)
    int hh = blk & 1;
    int ky = (blk >> 1) & 15;
    int b  = blk >> 5;
    __shared__ float2 s_f[32][64];
    __shared__ float2 s_t[128];
    int t = threadIdx.x;
    if (t < 128) s_t[t] = trig[t];
    for (int u = t; u < 2048; u += 256)
        s_f[u >> 6][u & 63] = F[(size_t)(b * 16 + ky) * 2048 + u];
    __syncthreads();
    int o = t & 63, hq = t >> 6;
    int h0 = hh * 64 + hq * 16;
    float accr[16], acci[16];
#pragma unroll
    for (int u = 0; u < 16; ++u) { accr[u] = 0.f; acci[u] = 0.f; }
    for (int m = 0; m < 32; ++m) {
        int kx = (m < 16) ? m : (96 + m);
        float2 f  = s_f[m][o];
        float2 stp = s_t[kx];
        float2 c0  = s_t[(kx * h0) & 127];
        float zr = f.x * c0.x - f.y * c0.y;
        float zi = f.x * c0.y + f.y * c0.x;
#pragma unroll
        for (int u = 0; u < 16; ++u) {
            accr[u] += zr; acci[u] += zi;
            float nz = zr * stp.x - zi * stp.y;
            zi = zr * stp.y + zi * stp.x;
            zr = nz;
        }
    }
    size_t gbase = ((size_t)(b * 128 + h0) * 16 + ky) * 64 + o;
#pragma unroll
    for (int u = 0; u < 16; ++u)
        G[gbase + (size_t)u * 1024] = make_float2(accr[u], acci[u]);
}

// ---------------- inverse step B + 1x1 conv + corr + bias (+GELU) ----------------
// cwT is pre-transposed [c][o] -> linear conflict-free staging.
__global__ void __launch_bounds__(256, 4) k_invb(const float2* __restrict__ G,
                                                 const float* __restrict__ hin,
                                                 const float* __restrict__ cwTl,
                                                 const float* __restrict__ cbl,
                                                 const float* __restrict__ corr,
                                                 const float2* __restrict__ trig,
                                                 float* __restrict__ hout,
                                                 int do_gelu) {
    int blk = blockIdx.x;
    int b = blk >> 7, h = blk & 127;
    __shared__ __align__(16) float s_cwT[64][64];   // [c][o]
    __shared__ __align__(16) float2 s_g[16][64];    // [ky][o]
    __shared__ __align__(16) float s_h[16][128];    // chunk of 16 c
    __shared__ float2 s_t[128];
    __shared__ float s_co[64];
    int t = threadIdx.x;
    if (t < 128) s_t[t] = trig[t];
    if (t < 64) s_co[t] = corr[b * 64 + t] + cbl[t];
    {
        float* cw0 = &s_cwT[0][0];
        for (int u = t; u < 4096; u += 256) cw0[u] = cwTl[u];   // linear, conflict-free
    }
    {
        const float2* gp = G + (size_t)(b * 128 + h) * 1024;
        for (int u = t; u < 1024; u += 256) s_g[u >> 6][u & 63] = gp[u];
    }
    __syncthreads();
    int ot2 = t >> 6;          // wave id 0..3 -> o0 = ot2*16 (wave-uniform)
    int wt6 = t & 63;          // lane -> w base
    int o0 = ot2 * 16;
    float acc[16][2];
#pragma unroll
    for (int i = 0; i < 16; ++i) { acc[i][0] = 0.f; acc[i][1] = 0.f; }
    float2 rw0 = s_t[wt6];          // e^{+2pi i w0/128}
    float2 rw1 = s_t[wt6 + 64];
    float z0r = 1.f, z0i = 0.f, z1r = 1.f, z1i = 0.f;
    for (int ky = 0; ky < 16; ++ky) {
        float fs = (ky == 0) ? 1.f : 2.f;
        float tc0 = fs * z0r, ts0 = fs * z0i;
        float tc1 = fs * z1r, ts1 = fs * z1i;
        const float4* gk = (const float4*)(&s_g[ky][o0]);
#pragma unroll
        for (int i2 = 0; i2 < 8; ++i2) {
            float4 g2 = gk[i2];
            acc[2*i2][0]   += g2.x * tc0 - g2.y * ts0;
            acc[2*i2][1]   += g2.x * tc1 - g2.y * ts1;
            acc[2*i2+1][0] += g2.z * tc0 - g2.w * ts0;
            acc[2*i2+1][1] += g2.z * tc1 - g2.w * ts1;
        }
        float nz0 = z0r * rw0.x - z0i * rw0.y; z0i = z0r * rw0.y + z0i * rw0.x; z0r = nz0;
        float nz1 = z1r * rw1.x - z1i * rw1.y; z1i = z1r * rw1.y + z1i * rw1.x; z1r = nz1;
    }
    const float invn = 1.0f / 16384.0f;
#pragma unroll
    for (int i = 0; i < 16; ++i) { acc[i][0] *= invn; acc[i][1] *= invn; }
    for (int cc = 0; cc < 64; cc += 16) {
        __syncthreads();
        for (int u = t; u < 2048; u += 256) {
            int c = u >> 7, w = u & 127;
            s_h[c][w] = hin[((size_t)(b * 64 + cc + c) * 128 + h) * 128 + w];
        }
        __syncthreads();
        for (int c = 0; c < 16; ++c) {
            float hv0 = s_h[c][wt6];
            float hv1 = s_h[c][wt6 + 64];
            const float4* cwp = (const float4*)(&s_cwT[cc + c][o0]);
#pragma unroll
            for (int i4 = 0; i4 < 4; ++i4) {
                float4 cv = cwp[i4];
                acc[4*i4][0]   += cv.x * hv0; acc[4*i4][1]   += cv.x * hv1;
                acc[4*i4+1][0] += cv.y * hv0; acc[4*i4+1][1] += cv.y * hv1;
                acc[4*i4+2][0] += cv.z * hv0; acc[4*i4+2][1] += cv.z * hv1;
                acc[4*i4+3][0] += cv.w * hv0; acc[4*i4+3][1] += cv.w * hv1;
            }
        }
    }
#pragma unroll
    for (int i = 0; i < 16; ++i) {
        int o = o0 + i;
        float co = s_co[o];
        float* outp = hout + ((size_t)(b * 64 + o) * 128 + h) * 128;
        float v0 = acc[i][0] + co;
        float v1 = acc[i][1] + co;
        if (do_gelu) { v0 = gelu_f(v0); v1 = gelu_f(v1); }
        outp[wt6] = v0;
        outp[wt6 + 64] = v1;
    }
}

// ---------------- FINAL layer: inverse B + conv + corr fused with head ----------------
// grid = 8*119 (b, h<119), 256 threads. Head weights staged in LDS per c-chunk.
__global__ void __launch_bounds__(256, 3) k_invbh(const float2* __restrict__ G,
                                                  const float* __restrict__ hin,
                                                  const float* __restrict__ cwTl,
                                                  const float* __restrict__ cbl,
                                                  const float* __restrict__ corr,
                                                  const float2* __restrict__ trig,
                                                  const float* __restrict__ fc1wT,
                                                  const float* __restrict__ fc1b,
                                                  const float* __restrict__ fc2w,
                                                  const float* __restrict__ fc2b,
                                                  float* __restrict__ out) {
    int blk = blockIdx.x;                 // 0..951
    int b = blk / 119;
    int h = blk - b * 119;
    __shared__ __align__(16) char smem[32768];
    float*  s_cwT = (float*)smem;                 // [64][64]  (phase A)
    float2* s_g   = (float2*)(smem + 16384);      // [16][64]  (phase A)
    float*  s_hh  = (float*)(smem + 24576);       // [16][128] (phase A)
    float*  s_hall= (float*)smem;                 // [64][128] (head phase overlay)
    __shared__ __align__(16) float s_w8[16][128]; // head weight chunk
    __shared__ float2 s_t[128];
    __shared__ float s_co[64];
    __shared__ float s_b1[128];
    __shared__ float s_w2[128];
    __shared__ float s_red[4][132];
    int t = threadIdx.x;
    if (t < 128) s_t[t] = trig[t];
    else { s_b1[t - 128] = fc1b[t - 128]; s_w2[t - 128] = fc2w[t - 128]; }
    if (t < 64) s_co[t] = corr[b * 64 + t] + cbl[t];
    for (int u = t; u < 4096; u += 256) s_cwT[u] = cwTl[u];   // linear, conflict-free
    {
        const float2* gp = G + (size_t)(b * 128 + h) * 1024;
        for (int u = t; u < 1024; u += 256) s_g[u] = gp[u];
    }
    __syncthreads();
    int ot2 = t >> 6;
    int wt6 = t & 63;
    int o0 = ot2 * 16;
    float acc[16][2];
#pragma unroll
    for (int i = 0; i < 16; ++i) { acc[i][0] = 0.f; acc[i][1] = 0.f; }
    float2 rw0 = s_t[wt6];
    float2 rw1 = s_t[wt6 + 64];
    float z0r = 1.f, z0i = 0.f, z1r = 1.f, z1i = 0.f;
    for (int ky = 0; ky < 16; ++ky) {
        float fs = (ky == 0) ? 1.f : 2.f;
        float tc0 = fs * z0r, ts0 = fs * z0i;
        float tc1 = fs * z1r, ts1 = fs * z1i;
        const float4* gk = (const float4*)(s_g + ky * 64 + o0);
#pragma unroll
        for (int i2 = 0; i2 < 8; ++i2) {
            float4 g2 = gk[i2];
            acc[2*i2][0]   += g2.x * tc0 - g2.y * ts0;
            acc[2*i2][1]   += g2.x * tc1 - g2.y * ts1;
            acc[2*i2+1][0] += g2.z * tc0 - g2.w * ts0;
            acc[2*i2+1][1] += g2.z * tc1 - g2.w * ts1;
        }
        float nz0 = z0r * rw0.x - z0i * rw0.y; z0i = z0r * rw0.y + z0i * rw0.x; z0r = nz0;
        float nz1 = z1r * rw1.x - z1i * rw1.y; z1i = z1r * rw1.y + z1i * rw1.x; z1r = nz1;
    }
    const float invn = 1.0f / 16384.0f;
#pragma unroll
    for (int i = 0; i < 16; ++i) { acc[i][0] *= invn; acc[i][1] *= invn; }
    for (int cc = 0; cc < 64; cc += 16) {
        __syncthreads();
        for (int u = t; u < 2048; u += 256) {
            int c = u >> 7, w = u & 127;
            s_hh[c * 128 + w] = hin[((size_t)(b * 64 + cc + c) * 128 + h) * 128 + w];
        }
        __syncthreads();
        for (int c = 0; c < 16; ++c) {
            float hv0 = s_hh[c * 128 + wt6];
            float hv1 = s_hh[c * 128 + wt6 + 64];
            const float4* cwp = (const float4*)(s_cwT + (cc + c) * 64 + o0);
#pragma unroll
            for (int i4 = 0; i4 < 4; ++i4) {
                float4 cv = cwp[i4];
                acc[4*i4][0]   += cv.x * hv0; acc[4*i4][1]   += cv.x * hv1;
                acc[4*i4+1][0] += cv.y * hv0; acc[4*i4+1][1] += cv.y * hv1;
                acc[4*i4+2][0] += cv.z * hv0; acc[4*i4+2][1] += cv.z * hv1;
                acc[4*i4+3][0] += cv.w * hv0; acc[4*i4+3][1] += cv.w * hv1;
            }
        }
    }
    // ---- transpose features into LDS overlay (no GELU on final layer) ----
    __syncthreads();
#pragma unroll
    for (int i = 0; i < 16; ++i) {
        float co = s_co[o0 + i];
        s_hall[(o0 + i) * 128 + wt6]      = acc[i][0] + co;
        s_hall[(o0 + i) * 128 + wt6 + 64] = acc[i][1] + co;
    }
    // ---- head: fc1 (wave-uniform j-tile of 32) + GELU + fc2, c-chunked LDS weights ----
    int j0 = ot2 * 32;
    float a32[32][2];
#pragma unroll
    for (int i = 0; i < 32; ++i) { a32[i][0] = 0.f; a32[i][1] = 0.f; }
    for (int cc = 0; cc < 64; cc += 16) {
        __syncthreads();
        for (int u = t; u < 2048; u += 256)
            s_w8[u >> 7][u & 127] = fc1wT[(cc + (u >> 7)) * 128 + (u & 127)];
        __syncthreads();
        for (int c = 0; c < 16; ++c) {
            float hv0 = s_hall[(cc + c) * 128 + wt6];
            float hv1 = s_hall[(cc + c) * 128 + wt6 + 64];
            const float4* wp = (const float4*)(&s_w8[c][j0]);
#pragma unroll
            for (int q = 0; q < 8; ++q) {
                float4 wx = wp[q];
                a32[4*q][0]   += wx.x * hv0; a32[4*q][1]   += wx.x * hv1;
                a32[4*q+1][0] += wx.y * hv0; a32[4*q+1][1] += wx.y * hv1;
                a32[4*q+2][0] += wx.z * hv0; a32[4*q+2][1] += wx.z * hv1;
                a32[4*q+3][0] += wx.w * hv0; a32[4*q+3][1] += wx.w * hv1;
            }
        }
    }
    float sum0 = 0.f, sum1 = 0.f;
#pragma unroll
    for (int i = 0; i < 32; ++i) {
        float b1 = s_b1[j0 + i];
        float w2 = s_w2[j0 + i];
        sum0 += gelu_f(a32[i][0] + b1) * w2;
        sum1 += gelu_f(a32[i][1] + b1) * w2;
    }
    s_red[ot2][wt6] = sum0;
    s_red[ot2][wt6 + 64] = sum1;
    __syncthreads();
    if (t < NS) {
        out[b * (NS * NS) + h * NS + t] =
            fc2b[0] + s_red[0][t] + s_red[1][t] + s_red[2][t] + s_red[3][t];
    }
}

extern "C" void kernel_launch(void* const* d_in, const int* in_sizes, int n_in,
                              void* d_out, int out_size, void* d_ws, size_t ws_size,
                              hipStream_t stream) {
    const float* x    = (const float*)d_in[0];
    const float* sw1r = (const float*)d_in[1];
    const float* sw1i = (const float*)d_in[2];
    const float* sw2r = (const float*)d_in[3];
    const float* sw2i = (const float*)d_in[4];
    const float* g1w  = (const float*)d_in[5];
    const float* g1b  = (const float*)d_in[6];
    const float* g2w  = (const float*)d_in[7];
    const float* g2b  = (const float*)d_in[8];
    const float* cw   = (const float*)d_in[9];
    const float* cb   = (const float*)d_in[10];
    const float* fc0w = (const float*)d_in[11];
    const float* fc0b = (const float*)d_in[12];
    const float* fc1w = (const float*)d_in[13];
    const float* fc1b = (const float*)d_in[14];
    const float* fc2w = (const float*)d_in[15];
    const float* fc2b = (const float*)d_in[16];
    float* out = (float*)d_out;

    char* ws = (char*)d_ws;
    const size_t SZ_H   = (size_t)NB * NC * NH * NW * 4;      // 33554432
    const size_t SZ_XFT = (size_t)NB * NC * 32 * 16 * 8;      // 2097152
    const size_t SZ_F   = SZ_XFT;                             // 2097152
    const size_t SZ_G   = (size_t)NB * NH * 16 * 64 * 8;      // 8388608
    size_t off = 0;
    float2* trig = (float2*)(ws + off); off += 1024;
    float2* wdft = (float2*)(ws + off); off += 2048 * 8;
    float*  f1T  = (float*)(ws + off);  off += 8192 * 4;
    float*  cwT  = (float*)(ws + off);  off += 16384 * 4;
    float*  hA   = (float*)(ws + off);  off += SZ_H;
    float*  hB   = (float*)(ws + off);  off += SZ_H;
    float2* xft  = (float2*)(ws + off); off += SZ_XFT;
    float2* F    = (float2*)(ws + off); off += SZ_F;
    float2* G    = (float2*)(ws + off); off += SZ_G;
    float*  cr   = (float*)(ws + off);  off += (size_t)NB * NC * 16 * 4;
    float*  hmid = (float*)(ws + off);  off += (size_t)NB * 256 * 4;
    float*  corr = (float*)(ws + off);  off += (size_t)NB * 64 * 4;
    (void)ws_size; (void)in_sizes; (void)n_in; (void)out_size;

    k_trig<<<1, 128, 0, stream>>>(trig);
    k_tab<<<16, 128, 0, stream>>>(wdft);
    k_tc<<<96, 256, 0, stream>>>(fc1w, cw, f1T, cwT);
    k_fc0<<<512, 256, 0, stream>>>(x, fc0w, fc0b, hA);

    float* hcur = hA;
    float* hnxt = hB;
    for (int l = 0; l < 4; ++l) {
        const float* w1r = sw1r + (size_t)l * 1048576;
        const float* w1i = sw1i + (size_t)l * 1048576;
        const float* w2r = sw2r + (size_t)l * 1048576;
        const float* w2i = sw2i + (size_t)l * 1048576;
        const float* g1w_l = g1w + (size_t)l * 524288;
        const float* g1b_l = g1b + l * 256;
        const float* g2w_l = g2w + (size_t)l * 16384;
        const float* g2b_l = g2b + l * 64;
        const float* cwT_l = cwT + (size_t)l * 4096;
        const float* cb_l  = cb + l * 64;

        k_cft<<<512, 256, 0, stream>>>(hcur, cr);
        k_mlp1<<<256, 256, 0, stream>>>(cr, g1w_l, g1b_l, hmid);
        k_mlp2<<<64, 256, 0, stream>>>(hmid, g2w_l, g2b_l, corr);
        k_dft2<<<512, 256, 0, stream>>>(hcur, xft, wdft, trig);
        k_mix<<<512, 512, 0, stream>>>(xft, w1r, w1i, w2r, w2i, F);
        k_inva<<<256, 256, 0, stream>>>(F, G, trig);
        if (l < 3) {
            k_invb<<<1024, 256, 0, stream>>>(G, hcur, cwT_l, cb_l, corr, trig, hnxt, 1);
            float* tmp = hcur; hcur = hnxt; hnxt = tmp;
        } else {
            k_invbh<<<NB * NS, 256, 0, stream>>>(G, hcur, cwT_l, cb_l, corr, trig,
                                                 f1T, fc1b, fc2w, fc2b, out);
        }
    }
}

// Round 8
// 544.730 us; speedup vs baseline: 1.0964x; 1.0964x over previous
//
#include <hip/hip_runtime.h>
#include <math.h>

#define NB 8
#define NC 64
#define NH 128
#define NW 128
#define NS 119
#define NPIX 113288   // 8*119*119

__device__ __forceinline__ float gelu_f(float v) {
    return 0.5f * v * (1.0f + erff(v * 0.70710678118654752f));
}

// ---------------- trig table: trig[t] = (cos, sin)(2*pi*t/128) ----------------
__global__ void __launch_bounds__(128) k_trig(float2* __restrict__ trig) {
    int t = threadIdx.x;
    double a = (double)t * (3.14159265358979323846 / 64.0);
    trig[t] = make_float2((float)cos(a), (float)sin(a));
}

// ---------------- DFT-W matrix: wd[ky*128+w] = e^{-2pi i ky w/128} ----------------
__global__ void __launch_bounds__(128) k_tab(float2* __restrict__ wd) {
    int idx = blockIdx.x * 128 + threadIdx.x;   // 0..2047
    int ky = idx >> 7, w = idx & 127;
    int prod = (ky * w) & 127;
    double a = (double)prod * (3.14159265358979323846 / 64.0);
    wd[idx] = make_float2((float)cos(a), (float)(-sin(a)));
}

// ---------------- transposes: fc1wT[c][j] = fc1w[j][c]; cwT[l][c][o] = cw[l][o][c] ----------------
__global__ void __launch_bounds__(256) k_tc(const float* __restrict__ fc1w,
                                            const float* __restrict__ cw,
                                            float* __restrict__ fc1wT,
                                            float* __restrict__ cwT) {
    int u = blockIdx.x * 256 + threadIdx.x;   // 0..24575
    if (u < 8192) {
        int c = u >> 7, j = u & 127;
        fc1wT[u] = fc1w[j * 64 + c];
    } else {
        int v = u - 8192;                      // 0..16383
        int l = v >> 12, idx = v & 4095;
        int c = idx >> 6, o = idx & 63;
        cwT[v] = cw[l * 4096 + o * 64 + c];
    }
}

// ---------------- fc0 + grid concat + transpose + zero pad ----------------
__global__ void __launch_bounds__(256) k_fc0(const float* __restrict__ x,
                                             const float* __restrict__ w,
                                             const float* __restrict__ bia,
                                             float* __restrict__ h) {
    __shared__ float sw[320];
    __shared__ float sb[64];
    int t = threadIdx.x;
    for (int u = t; u < 320; u += 256) sw[u] = w[u];
    if (t < 64) sb[t] = bia[t];
    __syncthreads();
    int p = blockIdx.x * 256 + t;            // 0 .. 131071
    int b = p >> 14;
    int rem = p & 16383;
    int r = rem >> 7, wc = rem & 127;
    float v0 = 0.f, v1 = 0.f, v2 = 0.f, gx = 0.f, gy = 0.f;
    bool inside = (r < NS) && (wc < NS);
    if (inside) {
        const float* xp = x + ((size_t)(b * NS + r) * NS + wc) * 3;
        v0 = xp[0]; v1 = xp[1]; v2 = xp[2];
        gx = (float)r * (1.0f / 118.0f);
        gy = (float)wc * (1.0f / 118.0f);
    }
    float* hp = h + (size_t)b * NC * NH * NW + rem;
    for (int c = 0; c < 64; ++c) {
        float val = 0.f;
        if (inside) {
            const float* wr = sw + c * 5;
            val = v0 * wr[0] + v1 * wr[1] + v2 * wr[2] + gx * wr[3] + gy * wr[4] + sb[c];
        }
        hp[c * (NH * NW)] = val;
    }
}

// ---------------- MLP stage 1 (reads cr produced by k_dft2) ----------------
__global__ void __launch_bounds__(256) k_mlp1(const float* __restrict__ cr,
                                              const float* __restrict__ g1w,
                                              const float* __restrict__ g1b,
                                              float* __restrict__ hmid) {
    __shared__ float s_cr[8][1024];
    __shared__ float s_wave[4][8];
    int j = blockIdx.x;
    int t = threadIdx.x;
    {
        float* sp = &s_cr[0][0];
        for (int u = t; u < 8192; u += 256) sp[u] = cr[u];
    }
    const float* wrow = g1w + (size_t)j * 2048;
    int v0 = t * 4;
    float w0 = wrow[2 * v0], w1 = wrow[2 * v0 + 2], w2 = wrow[2 * v0 + 4], w3 = wrow[2 * v0 + 6];
    __syncthreads();
    float acc[8];
#pragma unroll
    for (int b = 0; b < 8; ++b) {
        const float* cp = s_cr[b] + v0;
        acc[b] = cp[0] * w0 + cp[1] * w1 + cp[2] * w2 + cp[3] * w3;
    }
#pragma unroll
    for (int d = 32; d > 0; d >>= 1) {
#pragma unroll
        for (int b = 0; b < 8; ++b) acc[b] += __shfl_down(acc[b], d, 64);
    }
    int wv = t >> 6;
    if ((t & 63) == 0) {
#pragma unroll
        for (int b = 0; b < 8; ++b) s_wave[wv][b] = acc[b];
    }
    __syncthreads();
    if (t < 8) {
        float a = s_wave[0][t] + s_wave[1][t] + s_wave[2][t] + s_wave[3][t] + g1b[j];
        hmid[t * 256 + j] = gelu_f(a);
    }
}

// ---------------- MLP stage 2 ----------------
__global__ void __launch_bounds__(256) k_mlp2(const float* __restrict__ hmid,
                                              const float* __restrict__ g2w,
                                              const float* __restrict__ g2b,
                                              float* __restrict__ corr) {
    __shared__ float s_h[2048];
    __shared__ float s_w[256];
    int o = blockIdx.x;
    int t = threadIdx.x;
    s_w[t] = g2w[o * 256 + t];
    for (int u = t; u < 2048; u += 256) s_h[u] = hmid[u];
    __syncthreads();
    int b = t >> 5, k = t & 31;
    const float* hp = s_h + b * 256 + k * 8;
    const float* wp = s_w + k * 8;
    float acc = 0.f;
#pragma unroll
    for (int i = 0; i < 8; ++i) acc += hp[i] * wp[i];
#pragma unroll
    for (int d = 16; d > 0; d >>= 1) acc += __shfl_down(acc, d, 32);
    if (k == 0) corr[b * 64 + o] = acc + g2b[o];
}

// ---------------- fused 2D partial DFT + CFT: one block per (b,c) ----------------
// phase 1: T[r][ky] into LDS; CFT partials accumulated during chunks 0-1 (rows 0..31)
// phase 2: xft[m][ky] = sum_h T[h][ky] e^{-2pi i kx(m) h/128}; tail: cr[bc][16]
__global__ void __launch_bounds__(256) k_dft2(const float* __restrict__ h,
                                              float2* __restrict__ xft,
                                              float* __restrict__ cr,
                                              const float2* __restrict__ wd,
                                              const float2* __restrict__ trig) {
    __shared__ __align__(16) float sx[16][132];
    __shared__ __align__(16) float2 sW[16][134];
    __shared__ float2 sT[128][17];
    __shared__ float2 st[128];
    __shared__ float s_cs[2][16][8];
    __shared__ float s_cq[2][16][8];
    int t = threadIdx.x;
    int bc = blockIdx.x;
    if (t < 128) st[t] = trig[t];
    for (int u = t; u < 2048; u += 256) sW[u >> 7][u & 127] = wd[u];
    const float* src = h + (size_t)bc * 16384;
    int r = t >> 4, ky = t & 15;
    float c0a = 0.f, c1a = 0.f, q0a = 0.f, q1a = 0.f;   // CFT partials
    for (int ch = 0; ch < 8; ++ch) {
        __syncthreads();
        for (int u = t; u < 2048; u += 256) sx[u >> 7][u & 127] = src[ch * 2048 + u];
        __syncthreads();
        const float* xr = sx[r];
        const float2* wk = sW[ky];
        float re = 0.f, im = 0.f;
#pragma unroll 8
        for (int w0 = 0; w0 < 128; w0 += 4) {
            float4 x4 = *(const float4*)(xr + w0);
            float4 w01 = *(const float4*)(wk + w0);
            float4 w23 = *(const float4*)(wk + w0 + 2);
            re += x4.x * w01.x; im += x4.x * w01.y;
            re += x4.y * w01.z; im += x4.y * w01.w;
            re += x4.z * w23.x; im += x4.z * w23.y;
            re += x4.w * w23.z; im += x4.w * w23.w;
        }
        sT[ch * 16 + r][ky] = make_float2(re, im);
        // CFT accumulation over rows 0..31 (chunks 0,1), cols 0..63
        if (ch < 2 && t < 128) {
            int rr = t >> 3, k = t & 7;
            const float* row = sx[rr];
#pragma unroll
            for (int g = 0; g < 4; ++g) {
                float a = row[g * 8 + k];       c0a += a;  q0a += a * a;
                float bv = row[32 + g * 8 + k]; c1a += bv; q1a += bv * bv;
            }
            if (ch == 1) {
                s_cs[0][rr][k] = c0a; s_cs[1][rr][k] = c1a;
                s_cq[0][rr][k] = q0a; s_cq[1][rr][k] = q1a;
            }
        }
    }
    __syncthreads();
    int mlo = t >> 4;
    int kxa = mlo, kxb = 112 + mlo;
    float2 sva = st[kxa]; float sca = sva.x, ssa = -sva.y;
    float2 svb = st[kxb]; float scb = svb.x, ssb = -svb.y;
    float rea = 0.f, ima = 0.f, reb = 0.f, imb = 0.f;
    for (int h0 = 0; h0 < 128; h0 += 16) {
        float2 bva = st[(kxa * h0) & 127]; float cca = bva.x, csa = -bva.y;
        float2 bvb = st[(kxb * h0) & 127]; float ccb = bvb.x, csb = -bvb.y;
#pragma unroll
        for (int j = 0; j < 16; ++j) {
            float2 Tv = sT[h0 + j][ky];
            rea += Tv.x * cca - Tv.y * csa;
            ima += Tv.x * csa + Tv.y * cca;
            reb += Tv.x * ccb - Tv.y * csb;
            imb += Tv.x * csb + Tv.y * ccb;
            float na = cca * sca - csa * ssa; csa = cca * ssa + csa * sca; cca = na;
            float nb = ccb * scb - csb * ssb; csb = ccb * ssb + csb * scb; ccb = nb;
        }
    }
    float2* xp = xft + (size_t)bc * 512;
    xp[mlo * 16 + ky] = make_float2(rea, ima);
    xp[(mlo + 16) * 16 + ky] = make_float2(reb, imb);
    // CFT finalize (s_cs/s_cq visible since the ch=2 staging barrier)
    if (t < 16) {
        int half = t >> 3, k = t & 7;
        float s = 0.f, q = 0.f;
#pragma unroll
        for (int rr = 0; rr < 16; ++rr) s += s_cs[half][rr][k];
        for (int rr = 0; rr < 16; ++rr)
#pragma unroll
            for (int kk = 0; kk < 8; ++kk) q += s_cq[half][rr][kk];
        float norm = fmaxf(sqrtf(q), 1e-12f);
        cr[bc * 16 + t] = s / (128.0f * norm);
    }
}

// ---------------- spectral channel mix ----------------
__global__ void __launch_bounds__(512) k_mix(const float2* __restrict__ xft,
                                             const float* __restrict__ w1r,
                                             const float* __restrict__ w1i,
                                             const float* __restrict__ w2r,
                                             const float* __restrict__ w2i,
                                             float2* __restrict__ F) {
    int rbid = blockIdx.x;
    int m = (rbid & 7) + 8 * ((rbid >> 3) & 3);   // XCD swizzle
    int e = rbid >> 5;                             // ky
    __shared__ float2 s_w[64][64];                 // [i][o]
    __shared__ float2 s_x[8][64];                  // [b][i]
    int t = threadIdx.x;
    const float* wr; const float* wi; int mm;
    if (m < 16) { wr = w1r; wi = w1i; mm = m; } else { wr = w2r; wi = w2i; mm = m - 16; }
    int off = mm * 16 + e;
    for (int u = t; u < 4096; u += 512) {
        s_w[u >> 6][u & 63] = make_float2(wr[(u << 8) + off], wi[(u << 8) + off]);
    }
    {
        int bb = t >> 6, i = t & 63;
        s_x[bb][i] = xft[((size_t)(bb * 64 + i) * 32 + m) * 16 + e];
    }
    __syncthreads();
    int bb = t >> 6, o = t & 63;
    float re = 0.f, im = 0.f;
#pragma unroll 8
    for (int i = 0; i < 64; ++i) {
        float2 xv = s_x[bb][i];
        float2 wv = s_w[i][o];
        re += xv.x * wv.x - xv.y * wv.y;
        im += xv.x * wv.y + xv.y * wv.x;
    }
    F[((size_t)(bb * 16 + e) * 32 + m) * 64 + o] = make_float2(re, im);
}

// ---------------- inverse step A (1024 blocks, 4 h per thread) ----------------
__global__ void __launch_bounds__(256) k_inva(const float2* __restrict__ F,
                                              float2* __restrict__ G,
                                              const float2* __restrict__ trig) {
    int blk = blockIdx.x;                 // b(8) x ky(16) x hh(8)
    int hh = blk & 7;
    int ky = (blk >> 3) & 15;
    int b  = blk >> 7;
    __shared__ float2 s_f[32][64];
    __shared__ float2 s_t[128];
    int t = threadIdx.x;
    if (t < 128) s_t[t] = trig[t];
    for (int u = t; u < 2048; u += 256)
        s_f[u >> 6][u & 63] = F[(size_t)(b * 16 + ky) * 2048 + u];
    __syncthreads();
    int o = t & 63, hq = t >> 6;
    int h0 = hh * 16 + hq * 4;
    float accr[4], acci[4];
#pragma unroll
    for (int u = 0; u < 4; ++u) { accr[u] = 0.f; acci[u] = 0.f; }
    for (int m = 0; m < 32; ++m) {
        int kx = (m < 16) ? m : (96 + m);
        float2 f  = s_f[m][o];
        float2 stp = s_t[kx];
        float2 c0  = s_t[(kx * h0) & 127];
        float zr = f.x * c0.x - f.y * c0.y;
        float zi = f.x * c0.y + f.y * c0.x;
#pragma unroll
        for (int u = 0; u < 4; ++u) {
            accr[u] += zr; acci[u] += zi;
            float nz = zr * stp.x - zi * stp.y;
            zi = zr * stp.y + zi * stp.x;
            zr = nz;
        }
    }
    size_t gbase = ((size_t)(b * 128 + h0) * 16 + ky) * 64 + o;
#pragma unroll
    for (int u = 0; u < 4; ++u)
        G[gbase + (size_t)u * 1024] = make_float2(accr[u], acci[u]);
}

// ---------------- inverse step B + 1x1 conv + corr + bias (+GELU) ----------------
__global__ void __launch_bounds__(256, 4) k_invb(const float2* __restrict__ G,
                                                 const float* __restrict__ hin,
                                                 const float* __restrict__ cwTl,
                                                 const float* __restrict__ cbl,
                                                 const float* __restrict__ corr,
                                                 const float2* __restrict__ trig,
                                                 float* __restrict__ hout,
                                                 int do_gelu) {
    int blk = blockIdx.x;
    int b = blk >> 7, h = blk & 127;
    __shared__ __align__(16) float s_cwT[64][64];   // [c][o]
    __shared__ __align__(16) float2 s_g[16][64];    // [ky][o]
    __shared__ __align__(16) float s_h[16][128];    // chunk of 16 c
    __shared__ float2 s_t[128];
    __shared__ float s_co[64];
    int t = threadIdx.x;
    if (t < 128) s_t[t] = trig[t];
    if (t < 64) s_co[t] = corr[b * 64 + t] + cbl[t];
    {
        float* cw0 = &s_cwT[0][0];
        for (int u = t; u < 4096; u += 256) cw0[u] = cwTl[u];   // linear, conflict-free
    }
    {
        const float2* gp = G + (size_t)(b * 128 + h) * 1024;
        for (int u = t; u < 1024; u += 256) s_g[u >> 6][u & 63] = gp[u];
    }
    __syncthreads();
    int ot2 = t >> 6;          // wave id 0..3 -> o0 = ot2*16 (wave-uniform)
    int wt6 = t & 63;          // lane -> w base
    int o0 = ot2 * 16;
    float acc[16][2];
#pragma unroll
    for (int i = 0; i < 16; ++i) { acc[i][0] = 0.f; acc[i][1] = 0.f; }
    float2 rw0 = s_t[wt6];          // e^{+2pi i w0/128}
    float2 rw1 = s_t[wt6 + 64];
    float z0r = 1.f, z0i = 0.f, z1r = 1.f, z1i = 0.f;
    for (int ky = 0; ky < 16; ++ky) {
        float fs = (ky == 0) ? 1.f : 2.f;
        float tc0 = fs * z0r, ts0 = fs * z0i;
        float tc1 = fs * z1r, ts1 = fs * z1i;
        const float4* gk = (const float4*)(&s_g[ky][o0]);
#pragma unroll
        for (int i2 = 0; i2 < 8; ++i2) {
            float4 g2 = gk[i2];
            acc[2*i2][0]   += g2.x * tc0 - g2.y * ts0;
            acc[2*i2][1]   += g2.x * tc1 - g2.y * ts1;
            acc[2*i2+1][0] += g2.z * tc0 - g2.w * ts0;
            acc[2*i2+1][1] += g2.z * tc1 - g2.w * ts1;
        }
        float nz0 = z0r * rw0.x - z0i * rw0.y; z0i = z0r * rw0.y + z0i * rw0.x; z0r = nz0;
        float nz1 = z1r * rw1.x - z1i * rw1.y; z1i = z1r * rw1.y + z1i * rw1.x; z1r = nz1;
    }
    const float invn = 1.0f / 16384.0f;
#pragma unroll
    for (int i = 0; i < 16; ++i) { acc[i][0] *= invn; acc[i][1] *= invn; }
    for (int cc = 0; cc < 64; cc += 16) {
        __syncthreads();
        for (int u = t; u < 2048; u += 256) {
            int c = u >> 7, w = u & 127;
            s_h[c][w] = hin[((size_t)(b * 64 + cc + c) * 128 + h) * 128 + w];
        }
        __syncthreads();
        for (int c = 0; c < 16; ++c) {
            float hv0 = s_h[c][wt6];
            float hv1 = s_h[c][wt6 + 64];
            const float4* cwp = (const float4*)(&s_cwT[cc + c][o0]);
#pragma unroll
            for (int i4 = 0; i4 < 4; ++i4) {
                float4 cv = cwp[i4];
                acc[4*i4][0]   += cv.x * hv0; acc[4*i4][1]   += cv.x * hv1;
                acc[4*i4+1][0] += cv.y * hv0; acc[4*i4+1][1] += cv.y * hv1;
                acc[4*i4+2][0] += cv.z * hv0; acc[4*i4+2][1] += cv.z * hv1;
                acc[4*i4+3][0] += cv.w * hv0; acc[4*i4+3][1] += cv.w * hv1;
            }
        }
    }
#pragma unroll
    for (int i = 0; i < 16; ++i) {
        int o = o0 + i;
        float co = s_co[o];
        float* outp = hout + ((size_t)(b * 64 + o) * 128 + h) * 128;
        float v0 = acc[i][0] + co;
        float v1 = acc[i][1] + co;
        if (do_gelu) { v0 = gelu_f(v0); v1 = gelu_f(v1); }
        outp[wt6] = v0;
        outp[wt6 + 64] = v1;
    }
}

// ---------------- FINAL layer: inverse B + conv + corr fused with head ----------------
// launch_bounds (256,2): MUST keep >=128 VGPR budget (acc[16][2] + a32[32][2]);
// (256,3) spilled to scratch -> 70 MB HBM writes (R7 post-mortem).
__global__ void __launch_bounds__(256, 2) k_invbh(const float2* __restrict__ G,
                                                  const float* __restrict__ hin,
                                                  const float* __restrict__ cwTl,
                                                  const float* __restrict__ cbl,
                                                  const float* __restrict__ corr,
                                                  const float2* __restrict__ trig,
                                                  const float* __restrict__ fc1wT,
                                                  const float* __restrict__ fc1b,
                                                  const float* __restrict__ fc2w,
                                                  const float* __restrict__ fc2b,
                                                  float* __restrict__ out) {
    int blk = blockIdx.x;                 // 0..951
    int b = blk / 119;
    int h = blk - b * 119;
    __shared__ __align__(16) char smem[32768];
    float*  s_cwT = (float*)smem;                 // [64][64]  (phase A)
    float2* s_g   = (float2*)(smem + 16384);      // [16][64]  (phase A)
    float*  s_hh  = (float*)(smem + 24576);       // [16][128] (phase A)
    float*  s_hall= (float*)smem;                 // [64][128] (head phase overlay)
    __shared__ __align__(16) float s_w8[16][128]; // head weight chunk
    __shared__ float2 s_t[128];
    __shared__ float s_co[64];
    __shared__ float s_b1[128];
    __shared__ float s_w2[128];
    __shared__ float s_red[4][132];
    int t = threadIdx.x;
    if (t < 128) s_t[t] = trig[t];
    else { s_b1[t - 128] = fc1b[t - 128]; s_w2[t - 128] = fc2w[t - 128]; }
    if (t < 64) s_co[t] = corr[b * 64 + t] + cbl[t];
    for (int u = t; u < 4096; u += 256) s_cwT[u] = cwTl[u];   // linear, conflict-free
    {
        const float2* gp = G + (size_t)(b * 128 + h) * 1024;
        for (int u = t; u < 1024; u += 256) s_g[u] = gp[u];
    }
    __syncthreads();
    int ot2 = t >> 6;
    int wt6 = t & 63;
    int o0 = ot2 * 16;
    float acc[16][2];
#pragma unroll
    for (int i = 0; i < 16; ++i) { acc[i][0] = 0.f; acc[i][1] = 0.f; }
    float2 rw0 = s_t[wt6];
    float2 rw1 = s_t[wt6 + 64];
    float z0r = 1.f, z0i = 0.f, z1r = 1.f, z1i = 0.f;
    for (int ky = 0; ky < 16; ++ky) {
        float fs = (ky == 0) ? 1.f : 2.f;
        float tc0 = fs * z0r, ts0 = fs * z0i;
        float tc1 = fs * z1r, ts1 = fs * z1i;
        const float4* gk = (const float4*)(s_g + ky * 64 + o0);
#pragma unroll
        for (int i2 = 0; i2 < 8; ++i2) {
            float4 g2 = gk[i2];
            acc[2*i2][0]   += g2.x * tc0 - g2.y * ts0;
            acc[2*i2][1]   += g2.x * tc1 - g2.y * ts1;
            acc[2*i2+1][0] += g2.z * tc0 - g2.w * ts0;
            acc[2*i2+1][1] += g2.z * tc1 - g2.w * ts1;
        }
        float nz0 = z0r * rw0.x - z0i * rw0.y; z0i = z0r * rw0.y + z0i * rw0.x; z0r = nz0;
        float nz1 = z1r * rw1.x - z1i * rw1.y; z1i = z1r * rw1.y + z1i * rw1.x; z1r = nz1;
    }
    const float invn = 1.0f / 16384.0f;
#pragma unroll
    for (int i = 0; i < 16; ++i) { acc[i][0] *= invn; acc[i][1] *= invn; }
    for (int cc = 0; cc < 64; cc += 16) {
        __syncthreads();
        for (int u = t; u < 2048; u += 256) {
            int c = u >> 7, w = u & 127;
            s_hh[c * 128 + w] = hin[((size_t)(b * 64 + cc + c) * 128 + h) * 128 + w];
        }
        __syncthreads();
        for (int c = 0; c < 16; ++c) {
            float hv0 = s_hh[c * 128 + wt6];
            float hv1 = s_hh[c * 128 + wt6 + 64];
            const float4* cwp = (const float4*)(s_cwT + (cc + c) * 64 + o0);
#pragma unroll
            for (int i4 = 0; i4 < 4; ++i4) {
                float4 cv = cwp[i4];
                acc[4*i4][0]   += cv.x * hv0; acc[4*i4][1]   += cv.x * hv1;
                acc[4*i4+1][0] += cv.y * hv0; acc[4*i4+1][1] += cv.y * hv1;
                acc[4*i4+2][0] += cv.z * hv0; acc[4*i4+2][1] += cv.z * hv1;
                acc[4*i4+3][0] += cv.w * hv0; acc[4*i4+3][1] += cv.w * hv1;
            }
        }
    }
    // ---- transpose features into LDS overlay (no GELU on final layer) ----
    __syncthreads();
#pragma unroll
    for (int i = 0; i < 16; ++i) {
        float co = s_co[o0 + i];
        s_hall[(o0 + i) * 128 + wt6]      = acc[i][0] + co;
        s_hall[(o0 + i) * 128 + wt6 + 64] = acc[i][1] + co;
    }
    // ---- head: fc1 (wave-uniform j-tile of 32) + GELU + fc2, c-chunked LDS weights ----
    int j0 = ot2 * 32;
    float a32[32][2];
#pragma unroll
    for (int i = 0; i < 32; ++i) { a32[i][0] = 0.f; a32[i][1] = 0.f; }
    for (int cc = 0; cc < 64; cc += 16) {
        __syncthreads();
        for (int u = t; u < 2048; u += 256)
            s_w8[u >> 7][u & 127] = fc1wT[(cc + (u >> 7)) * 128 + (u & 127)];
        __syncthreads();
        for (int c = 0; c < 16; ++c) {
            float hv0 = s_hall[(cc + c) * 128 + wt6];
            float hv1 = s_hall[(cc + c) * 128 + wt6 + 64];
            const float4* wp = (const float4*)(&s_w8[c][j0]);
#pragma unroll
            for (int q = 0; q < 8; ++q) {
                float4 wx = wp[q];
                a32[4*q][0]   += wx.x * hv0; a32[4*q][1]   += wx.x * hv1;
                a32[4*q+1][0] += wx.y * hv0; a32[4*q+1][1] += wx.y * hv1;
                a32[4*q+2][0] += wx.z * hv0; a32[4*q+2][1] += wx.z * hv1;
                a32[4*q+3][0] += wx.w * hv0; a32[4*q+3][1] += wx.w * hv1;
            }
        }
    }
    float sum0 = 0.f, sum1 = 0.f;
#pragma unroll
    for (int i = 0; i < 32; ++i) {
        float b1 = s_b1[j0 + i];
        float w2 = s_w2[j0 + i];
        sum0 += gelu_f(a32[i][0] + b1) * w2;
        sum1 += gelu_f(a32[i][1] + b1) * w2;
    }
    s_red[ot2][wt6] = sum0;
    s_red[ot2][wt6 + 64] = sum1;
    __syncthreads();
    if (t < NS) {
        out[b * (NS * NS) + h * NS + t] =
            fc2b[0] + s_red[0][t] + s_red[1][t] + s_red[2][t] + s_red[3][t];
    }
}

extern "C" void kernel_launch(void* const* d_in, const int* in_sizes, int n_in,
                              void* d_out, int out_size, void* d_ws, size_t ws_size,
                              hipStream_t stream) {
    const float* x    = (const float*)d_in[0];
    const float* sw1r = (const float*)d_in[1];
    const float* sw1i = (const float*)d_in[2];
    const float* sw2r = (const float*)d_in[3];
    const float* sw2i = (const float*)d_in[4];
    const float* g1w  = (const float*)d_in[5];
    const float* g1b  = (const float*)d_in[6];
    const float* g2w  = (const float*)d_in[7];
    const float* g2b  = (const float*)d_in[8];
    const float* cw   = (const float*)d_in[9];
    const float* cb   = (const float*)d_in[10];
    const float* fc0w = (const float*)d_in[11];
    const float* fc0b = (const float*)d_in[12];
    const float* fc1w = (const float*)d_in[13];
    const float* fc1b = (const float*)d_in[14];
    const float* fc2w = (const float*)d_in[15];
    const float* fc2b = (const float*)d_in[16];
    float* out = (float*)d_out;

    char* ws = (char*)d_ws;
    const size_t SZ_H   = (size_t)NB * NC * NH * NW * 4;      // 33554432
    const size_t SZ_XFT = (size_t)NB * NC * 32 * 16 * 8;      // 2097152
    const size_t SZ_F   = SZ_XFT;                             // 2097152
    const size_t SZ_G   = (size_t)NB * NH * 16 * 64 * 8;      // 8388608
    size_t off = 0;
    float2* trig = (float2*)(ws + off); off += 1024;
    float2* wdft = (float2*)(ws + off); off += 2048 * 8;
    float*  f1T  = (float*)(ws + off);  off += 8192 * 4;
    float*  cwT  = (float*)(ws + off);  off += 16384 * 4;
    float*  hA   = (float*)(ws + off);  off += SZ_H;
    float*  hB   = (float*)(ws + off);  off += SZ_H;
    float2* xft  = (float2*)(ws + off); off += SZ_XFT;
    float2* F    = (float2*)(ws + off); off += SZ_F;
    float2* G    = (float2*)(ws + off); off += SZ_G;
    float*  cr   = (float*)(ws + off);  off += (size_t)NB * NC * 16 * 4;
    float*  hmid = (float*)(ws + off);  off += (size_t)NB * 256 * 4;
    float*  corr = (float*)(ws + off);  off += (size_t)NB * 64 * 4;
    (void)ws_size; (void)in_sizes; (void)n_in; (void)out_size;

    k_trig<<<1, 128, 0, stream>>>(trig);
    k_tab<<<16, 128, 0, stream>>>(wdft);
    k_tc<<<96, 256, 0, stream>>>(fc1w, cw, f1T, cwT);
    k_fc0<<<512, 256, 0, stream>>>(x, fc0w, fc0b, hA);

    float* hcur = hA;
    float* hnxt = hB;
    for (int l = 0; l < 4; ++l) {
        const float* w1r = sw1r + (size_t)l * 1048576;
        const float* w1i = sw1i + (size_t)l * 1048576;
        const float* w2r = sw2r + (size_t)l * 1048576;
        const float* w2i = sw2i + (size_t)l * 1048576;
        const float* g1w_l = g1w + (size_t)l * 524288;
        const float* g1b_l = g1b + l * 256;
        const float* g2w_l = g2w + (size_t)l * 16384;
        const float* g2b_l = g2b + l * 64;
        const float* cwT_l = cwT + (size_t)l * 4096;
        const float* cb_l  = cb + l * 64;

        k_dft2<<<512, 256, 0, stream>>>(hcur, xft, cr, wdft, trig);
        k_mlp1<<<256, 256, 0, stream>>>(cr, g1w_l, g1b_l, hmid);
        k_mlp2<<<64, 256, 0, stream>>>(hmid, g2w_l, g2b_l, corr);
        k_mix<<<512, 512, 0, stream>>>(xft, w1r, w1i, w2r, w2i, F);
        k_inva<<<1024, 256, 0, stream>>>(F, G, trig);
        if (l < 3) {
            k_invb<<<1024, 256, 0, stream>>>(G, hcur, cwT_l, cb_l, corr, trig, hnxt, 1);
            float* tmp = hcur; hcur = hnxt; hnxt = tmp;
        } else {
            k_invbh<<<NB * NS, 256, 0, stream>>>(G, hcur, cwT_l, cb_l, corr, trig,
                                                 f1T, fc1b, fc2w, fc2b, out);
        }
    }
}

// Round 9
// 510.770 us; speedup vs baseline: 1.1693x; 1.0665x over previous
//
#include <hip/hip_runtime.h>
#include <math.h>

#define NB 8
#define NC 64
#define NH 128
#define NW 128
#define NS 119
#define NPIX 113288   // 8*119*119

__device__ __forceinline__ float gelu_f(float v) {
    return 0.5f * v * (1.0f + erff(v * 0.70710678118654752f));
}

// ---------------- trig table: trig[t] = (cos, sin)(2*pi*t/128) ----------------
__global__ void __launch_bounds__(128) k_trig(float2* __restrict__ trig) {
    int t = threadIdx.x;
    double a = (double)t * (3.14159265358979323846 / 64.0);
    trig[t] = make_float2((float)cos(a), (float)sin(a));
}

// ---------------- DFT-W matrix: wd[ky*128+w] = e^{-2pi i ky w/128} ----------------
__global__ void __launch_bounds__(128) k_tab(float2* __restrict__ wd) {
    int idx = blockIdx.x * 128 + threadIdx.x;   // 0..2047
    int ky = idx >> 7, w = idx & 127;
    int prod = (ky * w) & 127;
    double a = (double)prod * (3.14159265358979323846 / 64.0);
    wd[idx] = make_float2((float)cos(a), (float)(-sin(a)));
}

// ---------------- transposes: fc1wT[c][j] = fc1w[j][c]; cwT[l][c][o] = cw[l][o][c] ----------------
__global__ void __launch_bounds__(256) k_tc(const float* __restrict__ fc1w,
                                            const float* __restrict__ cw,
                                            float* __restrict__ fc1wT,
                                            float* __restrict__ cwT) {
    int u = blockIdx.x * 256 + threadIdx.x;   // 0..24575
    if (u < 8192) {
        int c = u >> 7, j = u & 127;
        fc1wT[u] = fc1w[j * 64 + c];
    } else {
        int v = u - 8192;                      // 0..16383
        int l = v >> 12, idx = v & 4095;
        int c = idx >> 6, o = idx & 63;
        cwT[v] = cw[l * 4096 + o * 64 + c];
    }
}

// ---------------- fc0 + grid concat + transpose + zero pad ----------------
__global__ void __launch_bounds__(256) k_fc0(const float* __restrict__ x,
                                             const float* __restrict__ w,
                                             const float* __restrict__ bia,
                                             float* __restrict__ h) {
    __shared__ float sw[320];
    __shared__ float sb[64];
    int t = threadIdx.x;
    for (int u = t; u < 320; u += 256) sw[u] = w[u];
    if (t < 64) sb[t] = bia[t];
    __syncthreads();
    int p = blockIdx.x * 256 + t;            // 0 .. 131071
    int b = p >> 14;
    int rem = p & 16383;
    int r = rem >> 7, wc = rem & 127;
    float v0 = 0.f, v1 = 0.f, v2 = 0.f, gx = 0.f, gy = 0.f;
    bool inside = (r < NS) && (wc < NS);
    if (inside) {
        const float* xp = x + ((size_t)(b * NS + r) * NS + wc) * 3;
        v0 = xp[0]; v1 = xp[1]; v2 = xp[2];
        gx = (float)r * (1.0f / 118.0f);
        gy = (float)wc * (1.0f / 118.0f);
    }
    float* hp = h + (size_t)b * NC * NH * NW + rem;
    for (int c = 0; c < 64; ++c) {
        float val = 0.f;
        if (inside) {
            const float* wr = sw + c * 5;
            val = v0 * wr[0] + v1 * wr[1] + v2 * wr[2] + gx * wr[3] + gy * wr[4] + sb[c];
        }
        hp[c * (NH * NW)] = val;
    }
}

// ---------------- MLP stage 1 (reads cr produced by k_dft2) ----------------
__global__ void __launch_bounds__(256) k_mlp1(const float* __restrict__ cr,
                                              const float* __restrict__ g1w,
                                              const float* __restrict__ g1b,
                                              float* __restrict__ hmid) {
    __shared__ float s_cr[8][1024];
    __shared__ float s_wave[4][8];
    int j = blockIdx.x;
    int t = threadIdx.x;
    {
        float* sp = &s_cr[0][0];
        for (int u = t; u < 8192; u += 256) sp[u] = cr[u];
    }
    const float* wrow = g1w + (size_t)j * 2048;
    int v0 = t * 4;
    float w0 = wrow[2 * v0], w1 = wrow[2 * v0 + 2], w2 = wrow[2 * v0 + 4], w3 = wrow[2 * v0 + 6];
    __syncthreads();
    float acc[8];
#pragma unroll
    for (int b = 0; b < 8; ++b) {
        const float* cp = s_cr[b] + v0;
        acc[b] = cp[0] * w0 + cp[1] * w1 + cp[2] * w2 + cp[3] * w3;
    }
#pragma unroll
    for (int d = 32; d > 0; d >>= 1) {
#pragma unroll
        for (int b = 0; b < 8; ++b) acc[b] += __shfl_down(acc[b], d, 64);
    }
    int wv = t >> 6;
    if ((t & 63) == 0) {
#pragma unroll
        for (int b = 0; b < 8; ++b) s_wave[wv][b] = acc[b];
    }
    __syncthreads();
    if (t < 8) {
        float a = s_wave[0][t] + s_wave[1][t] + s_wave[2][t] + s_wave[3][t] + g1b[j];
        hmid[t * 256 + j] = gelu_f(a);
    }
}

// ---------------- MLP stage 2 ----------------
__global__ void __launch_bounds__(256) k_mlp2(const float* __restrict__ hmid,
                                              const float* __restrict__ g2w,
                                              const float* __restrict__ g2b,
                                              float* __restrict__ corr) {
    __shared__ float s_h[2048];
    __shared__ float s_w[256];
    int o = blockIdx.x;
    int t = threadIdx.x;
    s_w[t] = g2w[o * 256 + t];
    for (int u = t; u < 2048; u += 256) s_h[u] = hmid[u];
    __syncthreads();
    int b = t >> 5, k = t & 31;
    const float* hp = s_h + b * 256 + k * 8;
    const float* wp = s_w + k * 8;
    float acc = 0.f;
#pragma unroll
    for (int i = 0; i < 8; ++i) acc += hp[i] * wp[i];
#pragma unroll
    for (int d = 16; d > 0; d >>= 1) acc += __shfl_down(acc, d, 32);
    if (k == 0) corr[b * 64 + o] = acc + g2b[o];
}

// ---------------- fused 2D partial DFT + CFT: one block per (b,c) ----------------
__global__ void __launch_bounds__(256) k_dft2(const float* __restrict__ h,
                                              float2* __restrict__ xft,
                                              float* __restrict__ cr,
                                              const float2* __restrict__ wd,
                                              const float2* __restrict__ trig) {
    __shared__ __align__(16) float sx[16][132];
    __shared__ __align__(16) float2 sW[16][134];
    __shared__ float2 sT[128][17];
    __shared__ float2 st[128];
    __shared__ float s_cs[2][16][8];
    __shared__ float s_cq[2][16][8];
    int t = threadIdx.x;
    int bc = blockIdx.x;
    if (t < 128) st[t] = trig[t];
    for (int u = t; u < 2048; u += 256) sW[u >> 7][u & 127] = wd[u];
    const float* src = h + (size_t)bc * 16384;
    int r = t >> 4, ky = t & 15;
    float c0a = 0.f, c1a = 0.f, q0a = 0.f, q1a = 0.f;   // CFT partials
    for (int ch = 0; ch < 8; ++ch) {
        __syncthreads();
        for (int u = t; u < 2048; u += 256) sx[u >> 7][u & 127] = src[ch * 2048 + u];
        __syncthreads();
        const float* xr = sx[r];
        const float2* wk = sW[ky];
        float re = 0.f, im = 0.f;
#pragma unroll 8
        for (int w0 = 0; w0 < 128; w0 += 4) {
            float4 x4 = *(const float4*)(xr + w0);
            float4 w01 = *(const float4*)(wk + w0);
            float4 w23 = *(const float4*)(wk + w0 + 2);
            re += x4.x * w01.x; im += x4.x * w01.y;
            re += x4.y * w01.z; im += x4.y * w01.w;
            re += x4.z * w23.x; im += x4.z * w23.y;
            re += x4.w * w23.z; im += x4.w * w23.w;
        }
        sT[ch * 16 + r][ky] = make_float2(re, im);
        if (ch < 2 && t < 128) {
            int rr = t >> 3, k = t & 7;
            const float* row = sx[rr];
#pragma unroll
            for (int g = 0; g < 4; ++g) {
                float a = row[g * 8 + k];       c0a += a;  q0a += a * a;
                float bv = row[32 + g * 8 + k]; c1a += bv; q1a += bv * bv;
            }
            if (ch == 1) {
                s_cs[0][rr][k] = c0a; s_cs[1][rr][k] = c1a;
                s_cq[0][rr][k] = q0a; s_cq[1][rr][k] = q1a;
            }
        }
    }
    __syncthreads();
    int mlo = t >> 4;
    int kxa = mlo, kxb = 112 + mlo;
    float2 sva = st[kxa]; float sca = sva.x, ssa = -sva.y;
    float2 svb = st[kxb]; float scb = svb.x, ssb = -svb.y;
    float rea = 0.f, ima = 0.f, reb = 0.f, imb = 0.f;
    for (int h0 = 0; h0 < 128; h0 += 16) {
        float2 bva = st[(kxa * h0) & 127]; float cca = bva.x, csa = -bva.y;
        float2 bvb = st[(kxb * h0) & 127]; float ccb = bvb.x, csb = -bvb.y;
#pragma unroll
        for (int j = 0; j < 16; ++j) {
            float2 Tv = sT[h0 + j][ky];
            rea += Tv.x * cca - Tv.y * csa;
            ima += Tv.x * csa + Tv.y * cca;
            reb += Tv.x * ccb - Tv.y * csb;
            imb += Tv.x * csb + Tv.y * ccb;
            float na = cca * sca - csa * ssa; csa = cca * ssa + csa * sca; cca = na;
            float nb = ccb * scb - csb * ssb; csb = ccb * ssb + csb * scb; ccb = nb;
        }
    }
    float2* xp = xft + (size_t)bc * 512;
    xp[mlo * 16 + ky] = make_float2(rea, ima);
    xp[(mlo + 16) * 16 + ky] = make_float2(reb, imb);
    if (t < 16) {
        int half = t >> 3, k = t & 7;
        float s = 0.f, q = 0.f;
#pragma unroll
        for (int rr = 0; rr < 16; ++rr) s += s_cs[half][rr][k];
        for (int rr = 0; rr < 16; ++rr)
#pragma unroll
            for (int kk = 0; kk < 8; ++kk) q += s_cq[half][rr][kk];
        float norm = fmaxf(sqrtf(q), 1e-12f);
        cr[bc * 16 + t] = s / (128.0f * norm);
    }
}

// ---------------- spectral channel mix ----------------
__global__ void __launch_bounds__(512) k_mix(const float2* __restrict__ xft,
                                             const float* __restrict__ w1r,
                                             const float* __restrict__ w1i,
                                             const float* __restrict__ w2r,
                                             const float* __restrict__ w2i,
                                             float2* __restrict__ F) {
    int rbid = blockIdx.x;
    int m = (rbid & 7) + 8 * ((rbid >> 3) & 3);   // XCD swizzle
    int e = rbid >> 5;                             // ky
    __shared__ float2 s_w[64][64];                 // [i][o]
    __shared__ float2 s_x[8][64];                  // [b][i]
    int t = threadIdx.x;
    const float* wr; const float* wi; int mm;
    if (m < 16) { wr = w1r; wi = w1i; mm = m; } else { wr = w2r; wi = w2i; mm = m - 16; }
    int off = mm * 16 + e;
    for (int u = t; u < 4096; u += 512) {
        s_w[u >> 6][u & 63] = make_float2(wr[(u << 8) + off], wi[(u << 8) + off]);
    }
    {
        int bb = t >> 6, i = t & 63;
        s_x[bb][i] = xft[((size_t)(bb * 64 + i) * 32 + m) * 16 + e];
    }
    __syncthreads();
    int bb = t >> 6, o = t & 63;
    float re = 0.f, im = 0.f;
#pragma unroll 8
    for (int i = 0; i < 64; ++i) {
        float2 xv = s_x[bb][i];
        float2 wv = s_w[i][o];
        re += xv.x * wv.x - xv.y * wv.y;
        im += xv.x * wv.y + xv.y * wv.x;
    }
    F[((size_t)(bb * 16 + e) * 32 + m) * 64 + o] = make_float2(re, im);
}

// ---------------- inverse B (fused inva) + 1x1 conv + corr + bias (+GELU) ----------------
// G-phase in-block: s_g[ky][o] = sum_m F[b][ky][m][o] e^{+2pi i kx(m) h/128}
__global__ void __launch_bounds__(256, 4) k_invb(const float2* __restrict__ F,
                                                 const float* __restrict__ hin,
                                                 const float* __restrict__ cwTl,
                                                 const float* __restrict__ cbl,
                                                 const float* __restrict__ corr,
                                                 const float2* __restrict__ trig,
                                                 float* __restrict__ hout,
                                                 int do_gelu) {
    int blk = blockIdx.x;
    int b = blk >> 7, h = blk & 127;
    __shared__ __align__(16) float s_cwT[64][64];   // [c][o]
    __shared__ __align__(16) float2 s_g[16][64];    // [ky][o]
    __shared__ float2 s_t[128];
    __shared__ float s_co[64];
    int t = threadIdx.x;
    if (t < 128) s_t[t] = trig[t];
    if (t < 64) s_co[t] = corr[b * 64 + t] + cbl[t];
    {
        float* cw0 = &s_cwT[0][0];
        for (int u = t; u < 4096; u += 256) cw0[u] = cwTl[u];
    }
    // ---- G-phase (replaces k_inva) ----
    {
        float2 rot = trig[h];              // e^{+2pi i h/128}, uniform
        int o = t & 63, ky0 = t >> 6;
        const float2* Fb = F + (size_t)b * 32768 + o;
        float a0r=0.f,a0i=0.f,a1r=0.f,a1i=0.f,a2r=0.f,a2i=0.f,a3r=0.f,a3i=0.f;
        float zr = 1.f, zi = 0.f;
        for (int m = 0; m < 16; ++m) {
            const float2* fm = Fb + m * 64;
            float2 f0 = fm[(ky0     ) * 2048];
            float2 f1 = fm[(ky0 +  4) * 2048];
            float2 f2 = fm[(ky0 +  8) * 2048];
            float2 f3 = fm[(ky0 + 12) * 2048];
            a0r += f0.x*zr - f0.y*zi; a0i += f0.x*zi + f0.y*zr;
            a1r += f1.x*zr - f1.y*zi; a1i += f1.x*zi + f1.y*zr;
            a2r += f2.x*zr - f2.y*zi; a2i += f2.x*zi + f2.y*zr;
            a3r += f3.x*zr - f3.y*zi; a3i += f3.x*zi + f3.y*zr;
            float nz = zr*rot.x - zi*rot.y; zi = zr*rot.y + zi*rot.x; zr = nz;
        }
        float z2r = zr, z2i = -zi;         // m=16 -> kx=112 = conj(e^{i16h})
        for (int m = 16; m < 32; ++m) {
            const float2* fm = Fb + m * 64;
            float2 f0 = fm[(ky0     ) * 2048];
            float2 f1 = fm[(ky0 +  4) * 2048];
            float2 f2 = fm[(ky0 +  8) * 2048];
            float2 f3 = fm[(ky0 + 12) * 2048];
            a0r += f0.x*z2r - f0.y*z2i; a0i += f0.x*z2i + f0.y*z2r;
            a1r += f1.x*z2r - f1.y*z2i; a1i += f1.x*z2i + f1.y*z2r;
            a2r += f2.x*z2r - f2.y*z2i; a2i += f2.x*z2i + f2.y*z2r;
            a3r += f3.x*z2r - f3.y*z2i; a3i += f3.x*z2i + f3.y*z2r;
            float nz = z2r*rot.x - z2i*rot.y; z2i = z2r*rot.y + z2i*rot.x; z2r = nz;
        }
        s_g[ky0     ][o] = make_float2(a0r, a0i);
        s_g[ky0 +  4][o] = make_float2(a1r, a1i);
        s_g[ky0 +  8][o] = make_float2(a2r, a2i);
        s_g[ky0 + 12][o] = make_float2(a3r, a3i);
    }
    __syncthreads();
    int ot2 = t >> 6;
    int wt6 = t & 63;
    int o0 = ot2 * 16;
    float acc[16][2];
#pragma unroll
    for (int i = 0; i < 16; ++i) { acc[i][0] = 0.f; acc[i][1] = 0.f; }
    float2 rw0 = s_t[wt6];
    float2 rw1 = s_t[wt6 + 64];
    float z0r = 1.f, z0i = 0.f, z1r = 1.f, z1i = 0.f;
    for (int ky = 0; ky < 16; ++ky) {
        float fs = (ky == 0) ? 1.f : 2.f;
        float tc0 = fs * z0r, ts0 = fs * z0i;
        float tc1 = fs * z1r, ts1 = fs * z1i;
        const float4* gk = (const float4*)(&s_g[ky][o0]);
#pragma unroll
        for (int i2 = 0; i2 < 8; ++i2) {
            float4 g2 = gk[i2];
            acc[2*i2][0]   += g2.x * tc0 - g2.y * ts0;
            acc[2*i2][1]   += g2.x * tc1 - g2.y * ts1;
            acc[2*i2+1][0] += g2.z * tc0 - g2.w * ts0;
            acc[2*i2+1][1] += g2.z * tc1 - g2.w * ts1;
        }
        float nz0 = z0r * rw0.x - z0i * rw0.y; z0i = z0r * rw0.y + z0i * rw0.x; z0r = nz0;
        float nz1 = z1r * rw1.x - z1i * rw1.y; z1i = z1r * rw1.y + z1i * rw1.x; z1r = nz1;
    }
    const float invn = 1.0f / 16384.0f;
#pragma unroll
    for (int i = 0; i < 16; ++i) { acc[i][0] *= invn; acc[i][1] *= invn; }
    // ---- conv: direct global reads (L1-served; 4 waves share rows) ----
    const float* hp = hin + ((size_t)(b * 64) * 128 + h) * 128;
    for (int cc = 0; cc < 64; cc += 4) {
        float hv0[4], hv1[4];
#pragma unroll
        for (int c = 0; c < 4; ++c) {
            hv0[c] = hp[(size_t)(cc + c) * 16384 + wt6];
            hv1[c] = hp[(size_t)(cc + c) * 16384 + wt6 + 64];
        }
#pragma unroll
        for (int c = 0; c < 4; ++c) {
            const float4* cwp = (const float4*)(&s_cwT[cc + c][o0]);
#pragma unroll
            for (int i4 = 0; i4 < 4; ++i4) {
                float4 cv = cwp[i4];
                acc[4*i4][0]   += cv.x * hv0[c]; acc[4*i4][1]   += cv.x * hv1[c];
                acc[4*i4+1][0] += cv.y * hv0[c]; acc[4*i4+1][1] += cv.y * hv1[c];
                acc[4*i4+2][0] += cv.z * hv0[c]; acc[4*i4+2][1] += cv.z * hv1[c];
                acc[4*i4+3][0] += cv.w * hv0[c]; acc[4*i4+3][1] += cv.w * hv1[c];
            }
        }
    }
#pragma unroll
    for (int i = 0; i < 16; ++i) {
        int o = o0 + i;
        float co = s_co[o];
        float* outp = hout + ((size_t)(b * 64 + o) * 128 + h) * 128;
        float v0 = acc[i][0] + co;
        float v1 = acc[i][1] + co;
        if (do_gelu) { v0 = gelu_f(v0); v1 = gelu_f(v1); }
        outp[wt6] = v0;
        outp[wt6 + 64] = v1;
    }
}

// ---------------- FINAL layer: inverse B (fused inva) + conv + corr + head ----------------
// (256,2): >=128 VGPR needed (acc[16][2] + a32[32][2]) — (256,3) spilled (R7).
__global__ void __launch_bounds__(256, 2) k_invbh(const float2* __restrict__ F,
                                                  const float* __restrict__ hin,
                                                  const float* __restrict__ cwTl,
                                                  const float* __restrict__ cbl,
                                                  const float* __restrict__ corr,
                                                  const float2* __restrict__ trig,
                                                  const float* __restrict__ fc1wT,
                                                  const float* __restrict__ fc1b,
                                                  const float* __restrict__ fc2w,
                                                  const float* __restrict__ fc2b,
                                                  float* __restrict__ out) {
    int blk = blockIdx.x;                 // 0..951
    int b = blk / 119;
    int h = blk - b * 119;
    __shared__ __align__(16) char smem[32768];
    float*  s_cwT = (float*)smem;                 // [64][64]  (phase A)
    float2* s_g   = (float2*)(smem + 16384);      // [16][64]  (phase A)
    float*  s_hall= (float*)smem;                 // [64][128] (head overlay)
    __shared__ __align__(16) float s_w8[16][128]; // head weight chunk
    __shared__ float2 s_t[128];
    __shared__ float s_co[64];
    __shared__ float s_b1[128];
    __shared__ float s_w2[128];
    __shared__ float s_red[4][132];
    int t = threadIdx.x;
    if (t < 128) s_t[t] = trig[t];
    else { s_b1[t - 128] = fc1b[t - 128]; s_w2[t - 128] = fc2w[t - 128]; }
    if (t < 64) s_co[t] = corr[b * 64 + t] + cbl[t];
    for (int u = t; u < 4096; u += 256) s_cwT[u] = cwTl[u];
    // ---- G-phase (replaces k_inva) ----
    {
        float2 rot = trig[h];
        int o = t & 63, ky0 = t >> 6;
        const float2* Fb = F + (size_t)b * 32768 + o;
        float a0r=0.f,a0i=0.f,a1r=0.f,a1i=0.f,a2r=0.f,a2i=0.f,a3r=0.f,a3i=0.f;
        float zr = 1.f, zi = 0.f;
        for (int m = 0; m < 16; ++m) {
            const float2* fm = Fb + m * 64;
            float2 f0 = fm[(ky0     ) * 2048];
            float2 f1 = fm[(ky0 +  4) * 2048];
            float2 f2 = fm[(ky0 +  8) * 2048];
            float2 f3 = fm[(ky0 + 12) * 2048];
            a0r += f0.x*zr - f0.y*zi; a0i += f0.x*zi + f0.y*zr;
            a1r += f1.x*zr - f1.y*zi; a1i += f1.x*zi + f1.y*zr;
            a2r += f2.x*zr - f2.y*zi; a2i += f2.x*zi + f2.y*zr;
            a3r += f3.x*zr - f3.y*zi; a3i += f3.x*zi + f3.y*zr;
            float nz = zr*rot.x - zi*rot.y; zi = zr*rot.y + zi*rot.x; zr = nz;
        }
        float z2r = zr, z2i = -zi;
        for (int m = 16; m < 32; ++m) {
            const float2* fm = Fb + m * 64;
            float2 f0 = fm[(ky0     ) * 2048];
            float2 f1 = fm[(ky0 +  4) * 2048];
            float2 f2 = fm[(ky0 +  8) * 2048];
            float2 f3 = fm[(ky0 + 12) * 2048];
            a0r += f0.x*z2r - f0.y*z2i; a0i += f0.x*z2i + f0.y*z2r;
            a1r += f1.x*z2r - f1.y*z2i; a1i += f1.x*z2i + f1.y*z2r;
            a2r += f2.x*z2r - f2.y*z2i; a2i += f2.x*z2i + f2.y*z2r;
            a3r += f3.x*z2r - f3.y*z2i; a3i += f3.x*z2i + f3.y*z2r;
            float nz = z2r*rot.x - z2i*rot.y; z2i = z2r*rot.y + z2i*rot.x; z2r = nz;
        }
        float2* sg = (float2*)(smem + 16384);
        sg[(ky0     ) * 64 + o] = make_float2(a0r, a0i);
        sg[(ky0 +  4) * 64 + o] = make_float2(a1r, a1i);
        sg[(ky0 +  8) * 64 + o] = make_float2(a2r, a2i);
        sg[(ky0 + 12) * 64 + o] = make_float2(a3r, a3i);
    }
    __syncthreads();
    int ot2 = t >> 6;
    int wt6 = t & 63;
    int o0 = ot2 * 16;
    float acc[16][2];
#pragma unroll
    for (int i = 0; i < 16; ++i) { acc[i][0] = 0.f; acc[i][1] = 0.f; }
    float2 rw0 = s_t[wt6];
    float2 rw1 = s_t[wt6 + 64];
    float z0r = 1.f, z0i = 0.f, z1r = 1.f, z1i = 0.f;
    for (int ky = 0; ky < 16; ++ky) {
        float fs = (ky == 0) ? 1.f : 2.f;
        float tc0 = fs * z0r, ts0 = fs * z0i;
        float tc1 = fs * z1r, ts1 = fs * z1i;
        const float4* gk = (const float4*)(s_g + ky * 64 + o0);
#pragma unroll
        for (int i2 = 0; i2 < 8; ++i2) {
            float4 g2 = gk[i2];
            acc[2*i2][0]   += g2.x * tc0 - g2.y * ts0;
            acc[2*i2][1]   += g2.x * tc1 - g2.y * ts1;
            acc[2*i2+1][0] += g2.z * tc0 - g2.w * ts0;
            acc[2*i2+1][1] += g2.z * tc1 - g2.w * ts1;
        }
        float nz0 = z0r * rw0.x - z0i * rw0.y; z0i = z0r * rw0.y + z0i * rw0.x; z0r = nz0;
        float nz1 = z1r * rw1.x - z1i * rw1.y; z1i = z1r * rw1.y + z1i * rw1.x; z1r = nz1;
    }
    const float invn = 1.0f / 16384.0f;
#pragma unroll
    for (int i = 0; i < 16; ++i) { acc[i][0] *= invn; acc[i][1] *= invn; }
    // ---- conv: direct global reads ----
    const float* hp = hin + ((size_t)(b * 64) * 128 + h) * 128;
    for (int cc = 0; cc < 64; cc += 8) {
        float hv0[8], hv1[8];
#pragma unroll
        for (int c = 0; c < 8; ++c) {
            hv0[c] = hp[(size_t)(cc + c) * 16384 + wt6];
            hv1[c] = hp[(size_t)(cc + c) * 16384 + wt6 + 64];
        }
#pragma unroll
        for (int c = 0; c < 8; ++c) {
            const float4* cwp = (const float4*)(s_cwT + (cc + c) * 64 + o0);
#pragma unroll
            for (int i4 = 0; i4 < 4; ++i4) {
                float4 cv = cwp[i4];
                acc[4*i4][0]   += cv.x * hv0[c]; acc[4*i4][1]   += cv.x * hv1[c];
                acc[4*i4+1][0] += cv.y * hv0[c]; acc[4*i4+1][1] += cv.y * hv1[c];
                acc[4*i4+2][0] += cv.z * hv0[c]; acc[4*i4+2][1] += cv.z * hv1[c];
                acc[4*i4+3][0] += cv.w * hv0[c]; acc[4*i4+3][1] += cv.w * hv1[c];
            }
        }
    }
    // ---- features into LDS overlay (no GELU final layer) ----
    __syncthreads();
#pragma unroll
    for (int i = 0; i < 16; ++i) {
        float co = s_co[o0 + i];
        s_hall[(o0 + i) * 128 + wt6]      = acc[i][0] + co;
        s_hall[(o0 + i) * 128 + wt6 + 64] = acc[i][1] + co;
    }
    // ---- head: fc1 (wave-uniform j-tile 32) + GELU + fc2, LDS-staged weights ----
    int j0 = ot2 * 32;
    float a32[32][2];
#pragma unroll
    for (int i = 0; i < 32; ++i) { a32[i][0] = 0.f; a32[i][1] = 0.f; }
    for (int cc = 0; cc < 64; cc += 16) {
        __syncthreads();
        for (int u = t; u < 2048; u += 256)
            s_w8[u >> 7][u & 127] = fc1wT[(cc + (u >> 7)) * 128 + (u & 127)];
        __syncthreads();
        for (int c = 0; c < 16; ++c) {
            float hv0 = s_hall[(cc + c) * 128 + wt6];
            float hv1 = s_hall[(cc + c) * 128 + wt6 + 64];
            const float4* wp = (const float4*)(&s_w8[c][j0]);
#pragma unroll
            for (int q = 0; q < 8; ++q) {
                float4 wx = wp[q];
                a32[4*q][0]   += wx.x * hv0; a32[4*q][1]   += wx.x * hv1;
                a32[4*q+1][0] += wx.y * hv0; a32[4*q+1][1] += wx.y * hv1;
                a32[4*q+2][0] += wx.z * hv0; a32[4*q+2][1] += wx.z * hv1;
                a32[4*q+3][0] += wx.w * hv0; a32[4*q+3][1] += wx.w * hv1;
            }
        }
    }
    float sum0 = 0.f, sum1 = 0.f;
#pragma unroll
    for (int i = 0; i < 32; ++i) {
        float b1 = s_b1[j0 + i];
        float w2 = s_w2[j0 + i];
        sum0 += gelu_f(a32[i][0] + b1) * w2;
        sum1 += gelu_f(a32[i][1] + b1) * w2;
    }
    s_red[ot2][wt6] = sum0;
    s_red[ot2][wt6 + 64] = sum1;
    __syncthreads();
    if (t < NS) {
        out[b * (NS * NS) + h * NS + t] =
            fc2b[0] + s_red[0][t] + s_red[1][t] + s_red[2][t] + s_red[3][t];
    }
}

extern "C" void kernel_launch(void* const* d_in, const int* in_sizes, int n_in,
                              void* d_out, int out_size, void* d_ws, size_t ws_size,
                              hipStream_t stream) {
    const float* x    = (const float*)d_in[0];
    const float* sw1r = (const float*)d_in[1];
    const float* sw1i = (const float*)d_in[2];
    const float* sw2r = (const float*)d_in[3];
    const float* sw2i = (const float*)d_in[4];
    const float* g1w  = (const float*)d_in[5];
    const float* g1b  = (const float*)d_in[6];
    const float* g2w  = (const float*)d_in[7];
    const float* g2b  = (const float*)d_in[8];
    const float* cw   = (const float*)d_in[9];
    const float* cb   = (const float*)d_in[10];
    const float* fc0w = (const float*)d_in[11];
    const float* fc0b = (const float*)d_in[12];
    const float* fc1w = (const float*)d_in[13];
    const float* fc1b = (const float*)d_in[14];
    const float* fc2w = (const float*)d_in[15];
    const float* fc2b = (const float*)d_in[16];
    float* out = (float*)d_out;

    char* ws = (char*)d_ws;
    const size_t SZ_H   = (size_t)NB * NC * NH * NW * 4;      // 33554432
    const size_t SZ_XFT = (size_t)NB * NC * 32 * 16 * 8;      // 2097152
    const size_t SZ_F   = SZ_XFT;                             // 2097152
    size_t off = 0;
    float2* trig = (float2*)(ws + off); off += 1024;
    float2* wdft = (float2*)(ws + off); off += 2048 * 8;
    float*  f1T  = (float*)(ws + off);  off += 8192 * 4;
    float*  cwT  = (float*)(ws + off);  off += 16384 * 4;
    float*  hA   = (float*)(ws + off);  off += SZ_H;
    float*  hB   = (float*)(ws + off);  off += SZ_H;
    float2* xft  = (float2*)(ws + off); off += SZ_XFT;
    float2* F    = (float2*)(ws + off); off += SZ_F;
    float*  cr   = (float*)(ws + off);  off += (size_t)NB * NC * 16 * 4;
    float*  hmid = (float*)(ws + off);  off += (size_t)NB * 256 * 4;
    float*  corr = (float*)(ws + off);  off += (size_t)NB * 64 * 4;
    (void)ws_size; (void)in_sizes; (void)n_in; (void)out_size;

    k_trig<<<1, 128, 0, stream>>>(trig);
    k_tab<<<16, 128, 0, stream>>>(wdft);
    k_tc<<<96, 256, 0, stream>>>(fc1w, cw, f1T, cwT);
    k_fc0<<<512, 256, 0, stream>>>(x, fc0w, fc0b, hA);

    float* hcur = hA;
    float* hnxt = hB;
    for (int l = 0; l < 4; ++l) {
        const float* w1r = sw1r + (size_t)l * 1048576;
        const float* w1i = sw1i + (size_t)l * 1048576;
        const float* w2r = sw2r + (size_t)l * 1048576;
        const float* w2i = sw2i + (size_t)l * 1048576;
        const float* g1w_l = g1w + (size_t)l * 524288;
        const float* g1b_l = g1b + l * 256;
        const float* g2w_l = g2w + (size_t)l * 16384;
        const float* g2b_l = g2b + l * 64;
        const float* cwT_l = cwT + (size_t)l * 4096;
        const float* cb_l  = cb + l * 64;

        k_dft2<<<512, 256, 0, stream>>>(hcur, xft, cr, wdft, trig);
        k_mlp1<<<256, 256, 0, stream>>>(cr, g1w_l, g1b_l, hmid);
        k_mlp2<<<64, 256, 0, stream>>>(hmid, g2w_l, g2b_l, corr);
        k_mix<<<512, 512, 0, stream>>>(xft, w1r, w1i, w2r, w2i, F);
        if (l < 3) {
            k_invb<<<1024, 256, 0, stream>>>(F, hcur, cwT_l, cb_l, corr, trig, hnxt, 1);
            float* tmp = hcur; hcur = hnxt; hnxt = tmp;
        } else {
            k_invbh<<<NB * NS, 256, 0, stream>>>(F, hcur, cwT_l, cb_l, corr, trig,
                                                 f1T, fc1b, fc2w, fc2b, out);
        }
    }
}

// Round 10
// 499.762 us; speedup vs baseline: 1.1951x; 1.0220x over previous
//
#include <hip/hip_runtime.h>
#include <math.h>

#define NB 8
#define NC 64
#define NH 128
#define NW 128
#define NS 119
#define NPIX 113288   // 8*119*119

__device__ __forceinline__ float gelu_f(float v) {
    return 0.5f * v * (1.0f + erff(v * 0.70710678118654752f));
}

// ---------------- trig table: trig[t] = (cos, sin)(2*pi*t/128) ----------------
__global__ void __launch_bounds__(128) k_trig(float2* __restrict__ trig) {
    int t = threadIdx.x;
    double a = (double)t * (3.14159265358979323846 / 64.0);
    trig[t] = make_float2((float)cos(a), (float)sin(a));
}

// ---------------- DFT-W matrix: wd[ky*128+w] = e^{-2pi i ky w/128} ----------------
__global__ void __launch_bounds__(128) k_tab(float2* __restrict__ wd) {
    int idx = blockIdx.x * 128 + threadIdx.x;   // 0..2047
    int ky = idx >> 7, w = idx & 127;
    int prod = (ky * w) & 127;
    double a = (double)prod * (3.14159265358979323846 / 64.0);
    wd[idx] = make_float2((float)cos(a), (float)(-sin(a)));
}

// ---------------- transposes: fc1wT[c][j] = fc1w[j][c]; cwT[l][c][o] = cw[l][o][c] ----------------
__global__ void __launch_bounds__(256) k_tc(const float* __restrict__ fc1w,
                                            const float* __restrict__ cw,
                                            float* __restrict__ fc1wT,
                                            float* __restrict__ cwT) {
    int u = blockIdx.x * 256 + threadIdx.x;   // 0..24575
    if (u < 8192) {
        int c = u >> 7, j = u & 127;
        fc1wT[u] = fc1w[j * 64 + c];
    } else {
        int v = u - 8192;                      // 0..16383
        int l = v >> 12, idx = v & 4095;
        int c = idx >> 6, o = idx & 63;
        cwT[v] = cw[l * 4096 + o * 64 + c];
    }
}

// ---------------- fc0 + grid concat + transpose + zero pad ----------------
__global__ void __launch_bounds__(256) k_fc0(const float* __restrict__ x,
                                             const float* __restrict__ w,
                                             const float* __restrict__ bia,
                                             float* __restrict__ h) {
    __shared__ float sw[320];
    __shared__ float sb[64];
    int t = threadIdx.x;
    for (int u = t; u < 320; u += 256) sw[u] = w[u];
    if (t < 64) sb[t] = bia[t];
    __syncthreads();
    int p = blockIdx.x * 256 + t;            // 0 .. 131071
    int b = p >> 14;
    int rem = p & 16383;
    int r = rem >> 7, wc = rem & 127;
    float v0 = 0.f, v1 = 0.f, v2 = 0.f, gx = 0.f, gy = 0.f;
    bool inside = (r < NS) && (wc < NS);
    if (inside) {
        const float* xp = x + ((size_t)(b * NS + r) * NS + wc) * 3;
        v0 = xp[0]; v1 = xp[1]; v2 = xp[2];
        gx = (float)r * (1.0f / 118.0f);
        gy = (float)wc * (1.0f / 118.0f);
    }
    float* hp = h + (size_t)b * NC * NH * NW + rem;
    for (int c = 0; c < 64; ++c) {
        float val = 0.f;
        if (inside) {
            const float* wr = sw + c * 5;
            val = v0 * wr[0] + v1 * wr[1] + v2 * wr[2] + gx * wr[3] + gy * wr[4] + sb[c];
        }
        hp[c * (NH * NW)] = val;
    }
}

// ---------------- fused 2D partial DFT + CFT: one block per (b,c) ----------------
// phase 1 (4 iters, 2 rows/thread): T[r][ky] into LDS; CFT partials during iter 0
// phase 2: xft[m][ky] = sum_h T[h][ky] e^{-2pi i kx(m) h/128}; tail: cr[bc][16]
__global__ void __launch_bounds__(256) k_dft2(const float* __restrict__ h,
                                              float2* __restrict__ xft,
                                              float* __restrict__ cr,
                                              const float2* __restrict__ wd,
                                              const float2* __restrict__ trig) {
    __shared__ __align__(16) float sx[32][132];
    __shared__ __align__(16) float2 sW[16][134];
    __shared__ float2 sT[128][17];
    __shared__ float2 st[128];
    __shared__ float s_cs[2][32][8];
    __shared__ float s_cq[2][32][8];
    int t = threadIdx.x;
    int bc = blockIdx.x;
    if (t < 128) st[t] = trig[t];
    for (int u = t; u < 2048; u += 256) sW[u >> 7][u & 127] = wd[u];
    const float* src = h + (size_t)bc * 16384;
    int rp = t >> 4, ky = t & 15;
    for (int it = 0; it < 4; ++it) {
        __syncthreads();
        for (int u = t; u < 4096; u += 256) sx[u >> 7][u & 127] = src[it * 4096 + u];
        __syncthreads();
        const float* xa = sx[2 * rp];
        const float* xb = sx[2 * rp + 1];
        const float2* wk = sW[ky];
        float rea = 0.f, ima = 0.f, reb = 0.f, imb = 0.f;
#pragma unroll 8
        for (int w0 = 0; w0 < 128; w0 += 4) {
            float4 a4 = *(const float4*)(xa + w0);
            float4 b4 = *(const float4*)(xb + w0);
            float4 w01 = *(const float4*)(wk + w0);
            float4 w23 = *(const float4*)(wk + w0 + 2);
            rea += a4.x * w01.x; ima += a4.x * w01.y;
            reb += b4.x * w01.x; imb += b4.x * w01.y;
            rea += a4.y * w01.z; ima += a4.y * w01.w;
            reb += b4.y * w01.z; imb += b4.y * w01.w;
            rea += a4.z * w23.x; ima += a4.z * w23.y;
            reb += b4.z * w23.x; imb += b4.z * w23.y;
            rea += a4.w * w23.z; ima += a4.w * w23.w;
            reb += b4.w * w23.z; imb += b4.w * w23.w;
        }
        sT[it * 32 + 2 * rp][ky] = make_float2(rea, ima);
        sT[it * 32 + 2 * rp + 1][ky] = make_float2(reb, imb);
        if (it == 0) {
            int rr = t >> 3, k = t & 7;
            const float* row = sx[rr];
            float cs0 = 0.f, cq0 = 0.f, cs1 = 0.f, cq1 = 0.f;
#pragma unroll
            for (int g = 0; g < 4; ++g) {
                float a = row[g * 8 + k];       cs0 += a;  cq0 += a * a;
                float bv = row[32 + g * 8 + k]; cs1 += bv; cq1 += bv * bv;
            }
            s_cs[0][rr][k] = cs0; s_cs[1][rr][k] = cs1;
            s_cq[0][rr][k] = cq0; s_cq[1][rr][k] = cq1;
        }
    }
    __syncthreads();
    int mlo = t >> 4;
    int kxa = mlo, kxb = 112 + mlo;
    float2 sva = st[kxa]; float sca = sva.x, ssa = -sva.y;
    float2 svb = st[kxb]; float scb = svb.x, ssb = -svb.y;
    float rea = 0.f, ima = 0.f, reb = 0.f, imb = 0.f;
    for (int h0 = 0; h0 < 128; h0 += 16) {
        float2 bva = st[(kxa * h0) & 127]; float cca = bva.x, csa = -bva.y;
        float2 bvb = st[(kxb * h0) & 127]; float ccb = bvb.x, csb = -bvb.y;
#pragma unroll
        for (int j = 0; j < 16; ++j) {
            float2 Tv = sT[h0 + j][ky];
            rea += Tv.x * cca - Tv.y * csa;
            ima += Tv.x * csa + Tv.y * cca;
            reb += Tv.x * ccb - Tv.y * csb;
            imb += Tv.x * csb + Tv.y * ccb;
            float na = cca * sca - csa * ssa; csa = cca * ssa + csa * sca; cca = na;
            float nb = ccb * scb - csb * ssb; csb = ccb * ssb + csb * scb; ccb = nb;
        }
    }
    float2* xp = xft + (size_t)bc * 512;
    xp[mlo * 16 + ky] = make_float2(rea, ima);
    xp[(mlo + 16) * 16 + ky] = make_float2(reb, imb);
    if (t < 16) {
        int half = t >> 3, k = t & 7;
        float s = 0.f, q = 0.f;
        for (int rr = 0; rr < 32; ++rr) {
            s += s_cs[half][rr][k];
#pragma unroll
            for (int kk = 0; kk < 8; ++kk) q += s_cq[half][rr][kk];
        }
        float norm = fmaxf(sqrtf(q), 1e-12f);
        cr[bc * 16 + t] = s / (128.0f * norm);
    }
}

// ---------------- spectral mix (blocks 0..511) + MLP stage 1 (blocks 512..767) ----------------
__global__ void __launch_bounds__(512) k_mixmlp(const float2* __restrict__ xft,
                                                const float* __restrict__ w1r,
                                                const float* __restrict__ w1i,
                                                const float* __restrict__ w2r,
                                                const float* __restrict__ w2i,
                                                const float* __restrict__ cr,
                                                const float* __restrict__ g1w,
                                                const float* __restrict__ g1b,
                                                float* __restrict__ hmid,
                                                float2* __restrict__ F) {
    __shared__ __align__(16) char smem[36864];
    int t = threadIdx.x;
    int bid = blockIdx.x;
    if (bid < 512) {
        float2* s_w = (float2*)smem;               // [64][64] (i,o)
        float2* s_x = (float2*)(smem + 32768);     // [8][64]  (b,i)
        int m = (bid & 7) + 8 * ((bid >> 3) & 3);  // XCD swizzle
        int e = bid >> 5;                          // ky
        const float* wr; const float* wi; int mm;
        if (m < 16) { wr = w1r; wi = w1i; mm = m; } else { wr = w2r; wi = w2i; mm = m - 16; }
        int off = mm * 16 + e;
        for (int u = t; u < 4096; u += 512) {
            s_w[u] = make_float2(wr[(u << 8) + off], wi[(u << 8) + off]);
        }
        {
            int bb = t >> 6, i = t & 63;
            s_x[bb * 64 + i] = xft[((size_t)(bb * 64 + i) * 32 + m) * 16 + e];
        }
        __syncthreads();
        int bb = t >> 6, o = t & 63;
        float re = 0.f, im = 0.f;
#pragma unroll 8
        for (int i = 0; i < 64; ++i) {
            float2 xv = s_x[bb * 64 + i];
            float2 wv = s_w[i * 64 + o];
            re += xv.x * wv.x - xv.y * wv.y;
            im += xv.x * wv.y + xv.y * wv.x;
        }
        F[((size_t)(bb * 16 + e) * 32 + m) * 64 + o] = make_float2(re, im);
    } else {
        float* s_cr   = (float*)smem;              // [8][1024]
        float* s_wave = (float*)(smem + 32768);    // [8][8]
        int j = bid - 512;
        for (int u = t; u < 8192; u += 512) s_cr[u] = cr[u];
        const float* wrow = g1w + (size_t)j * 2048;
        float w0 = wrow[4 * t], w1 = wrow[4 * t + 2];
        __syncthreads();
        float acc[8];
#pragma unroll
        for (int b = 0; b < 8; ++b) {
            float2 v = *(const float2*)(s_cr + b * 1024 + 2 * t);
            acc[b] = v.x * w0 + v.y * w1;
        }
#pragma unroll
        for (int d = 32; d > 0; d >>= 1) {
#pragma unroll
            for (int b = 0; b < 8; ++b) acc[b] += __shfl_down(acc[b], d, 64);
        }
        int wv = t >> 6;
        if ((t & 63) == 0) {
#pragma unroll
            for (int b = 0; b < 8; ++b) s_wave[wv * 8 + b] = acc[b];
        }
        __syncthreads();
        if (t < 8) {
            float a = g1b[j];
            for (int q = 0; q < 8; ++q) a += s_wave[q * 8 + t];
            hmid[t * 256 + j] = gelu_f(a);
        }
    }
}

// ---------------- inverse B (fused inva + mlp2) + 1x1 conv + corr + bias (+GELU) ----------------
__global__ void __launch_bounds__(256, 4) k_invb(const float2* __restrict__ F,
                                                 const float* __restrict__ hin,
                                                 const float* __restrict__ cwTl,
                                                 const float* __restrict__ cbl,
                                                 const float* __restrict__ hmid,
                                                 const float* __restrict__ g2w,
                                                 const float* __restrict__ g2b,
                                                 const float2* __restrict__ trig,
                                                 float* __restrict__ hout,
                                                 int do_gelu) {
    int blk = blockIdx.x;
    int b = blk >> 7, h = blk & 127;
    __shared__ __align__(16) float s_cwT[64][64];   // [c][o]
    __shared__ __align__(16) float2 s_g[16][64];    // [ky][o]
    __shared__ float2 s_t[128];
    __shared__ float s_co[64];
    __shared__ float s_part[4][64];
    int t = threadIdx.x;
    if (t < 128) s_t[t] = trig[t];
    {
        float* cw0 = &s_cwT[0][0];
        for (int u = t; u < 4096; u += 256) cw0[u] = cwTl[u];
    }
    // ---- mlp2 partials (corr) ----
    {
        int o = t & 63, q = t >> 6;
        const float* hv = hmid + b * 256 + q * 64;
        const float* gw = g2w + o * 256 + q * 64;
        float a = 0.f;
#pragma unroll 8
        for (int v = 0; v < 64; ++v) a += hv[v] * gw[v];
        s_part[q][o] = a;
    }
    // ---- G-phase (fused inva) ----
    {
        float2 rot = trig[h];              // e^{+2pi i h/128}, uniform
        int o = t & 63, ky0 = t >> 6;
        const float2* Fb = F + (size_t)b * 32768 + o;
        float a0r=0.f,a0i=0.f,a1r=0.f,a1i=0.f,a2r=0.f,a2i=0.f,a3r=0.f,a3i=0.f;
        float zr = 1.f, zi = 0.f;
        for (int m = 0; m < 16; ++m) {
            const float2* fm = Fb + m * 64;
            float2 f0 = fm[(ky0     ) * 2048];
            float2 f1 = fm[(ky0 +  4) * 2048];
            float2 f2 = fm[(ky0 +  8) * 2048];
            float2 f3 = fm[(ky0 + 12) * 2048];
            a0r += f0.x*zr - f0.y*zi; a0i += f0.x*zi + f0.y*zr;
            a1r += f1.x*zr - f1.y*zi; a1i += f1.x*zi + f1.y*zr;
            a2r += f2.x*zr - f2.y*zi; a2i += f2.x*zi + f2.y*zr;
            a3r += f3.x*zr - f3.y*zi; a3i += f3.x*zi + f3.y*zr;
            float nz = zr*rot.x - zi*rot.y; zi = zr*rot.y + zi*rot.x; zr = nz;
        }
        float z2r = zr, z2i = -zi;         // m=16 -> kx=112 = conj
        for (int m = 16; m < 32; ++m) {
            const float2* fm = Fb + m * 64;
            float2 f0 = fm[(ky0     ) * 2048];
            float2 f1 = fm[(ky0 +  4) * 2048];
            float2 f2 = fm[(ky0 +  8) * 2048];
            float2 f3 = fm[(ky0 + 12) * 2048];
            a0r += f0.x*z2r - f0.y*z2i; a0i += f0.x*z2i + f0.y*z2r;
            a1r += f1.x*z2r - f1.y*z2i; a1i += f1.x*z2i + f1.y*z2r;
            a2r += f2.x*z2r - f2.y*z2i; a2i += f2.x*z2i + f2.y*z2r;
            a3r += f3.x*z2r - f3.y*z2i; a3i += f3.x*z2i + f3.y*z2r;
            float nz = z2r*rot.x - z2i*rot.y; z2i = z2r*rot.y + z2i*rot.x; z2r = nz;
        }
        s_g[ky0     ][o] = make_float2(a0r, a0i);
        s_g[ky0 +  4][o] = make_float2(a1r, a1i);
        s_g[ky0 +  8][o] = make_float2(a2r, a2i);
        s_g[ky0 + 12][o] = make_float2(a3r, a3i);
    }
    __syncthreads();
    if (t < 64)
        s_co[t] = s_part[0][t] + s_part[1][t] + s_part[2][t] + s_part[3][t]
                + g2b[t] + cbl[t];
    int ot2 = t >> 6;
    int wt6 = t & 63;
    int o0 = ot2 * 16;
    float acc[16][2];
#pragma unroll
    for (int i = 0; i < 16; ++i) { acc[i][0] = 0.f; acc[i][1] = 0.f; }
    float2 rw0 = s_t[wt6];
    float2 rw1 = s_t[wt6 + 64];
    float z0r = 1.f, z0i = 0.f, z1r = 1.f, z1i = 0.f;
    const float invn = 1.0f / 16384.0f;
    for (int ky = 0; ky < 16; ++ky) {
        float fs = (ky == 0) ? invn : (2.f * invn);   // invn folded into twiddle
        float tc0 = fs * z0r, ts0 = fs * z0i;
        float tc1 = fs * z1r, ts1 = fs * z1i;
        const float4* gk = (const float4*)(&s_g[ky][o0]);
#pragma unroll
        for (int i2 = 0; i2 < 8; ++i2) {
            float4 g2 = gk[i2];
            acc[2*i2][0]   += g2.x * tc0 - g2.y * ts0;
            acc[2*i2][1]   += g2.x * tc1 - g2.y * ts1;
            acc[2*i2+1][0] += g2.z * tc0 - g2.w * ts0;
            acc[2*i2+1][1] += g2.z * tc1 - g2.w * ts1;
        }
        float nz0 = z0r * rw0.x - z0i * rw0.y; z0i = z0r * rw0.y + z0i * rw0.x; z0r = nz0;
        float nz1 = z1r * rw1.x - z1i * rw1.y; z1i = z1r * rw1.y + z1i * rw1.x; z1r = nz1;
    }
    // ---- conv: direct global reads ----
    const float* hp = hin + ((size_t)(b * 64) * 128 + h) * 128;
    for (int cc = 0; cc < 64; cc += 4) {
        float hv0[4], hv1[4];
#pragma unroll
        for (int c = 0; c < 4; ++c) {
            hv0[c] = hp[(size_t)(cc + c) * 16384 + wt6];
            hv1[c] = hp[(size_t)(cc + c) * 16384 + wt6 + 64];
        }
#pragma unroll
        for (int c = 0; c < 4; ++c) {
            const float4* cwp = (const float4*)(&s_cwT[cc + c][o0]);
#pragma unroll
            for (int i4 = 0; i4 < 4; ++i4) {
                float4 cv = cwp[i4];
                acc[4*i4][0]   += cv.x * hv0[c]; acc[4*i4][1]   += cv.x * hv1[c];
                acc[4*i4+1][0] += cv.y * hv0[c]; acc[4*i4+1][1] += cv.y * hv1[c];
                acc[4*i4+2][0] += cv.z * hv0[c]; acc[4*i4+2][1] += cv.z * hv1[c];
                acc[4*i4+3][0] += cv.w * hv0[c]; acc[4*i4+3][1] += cv.w * hv1[c];
            }
        }
    }
    __syncthreads();   // s_co written by t<64 after first barrier; read below
#pragma unroll
    for (int i = 0; i < 16; ++i) {
        int o = o0 + i;
        float co = s_co[o];
        float* outp = hout + ((size_t)(b * 64 + o) * 128 + h) * 128;
        float v0 = acc[i][0] + co;
        float v1 = acc[i][1] + co;
        if (do_gelu) { v0 = gelu_f(v0); v1 = gelu_f(v1); }
        outp[wt6] = v0;
        outp[wt6 + 64] = v1;
    }
}

// ---------------- FINAL layer: inverse B (fused inva + mlp2) + conv + head ----------------
// (256,2): >=128 VGPR needed (acc[16][2] + a32[32][2]) — (256,3) spilled (R7).
__global__ void __launch_bounds__(256, 2) k_invbh(const float2* __restrict__ F,
                                                  const float* __restrict__ hin,
                                                  const float* __restrict__ cwTl,
                                                  const float* __restrict__ cbl,
                                                  const float* __restrict__ hmid,
                                                  const float* __restrict__ g2w,
                                                  const float* __restrict__ g2b,
                                                  const float2* __restrict__ trig,
                                                  const float* __restrict__ fc1wT,
                                                  const float* __restrict__ fc1b,
                                                  const float* __restrict__ fc2w,
                                                  const float* __restrict__ fc2b,
                                                  float* __restrict__ out) {
    int blk = blockIdx.x;                 // 0..951
    int b = blk / 119;
    int h = blk - b * 119;
    __shared__ __align__(16) char smem[32768];
    float*  s_cwT = (float*)smem;                 // [64][64]  (phase A)
    float2* s_g   = (float2*)(smem + 16384);      // [16][64]  (phase A)
    float*  s_hall= (float*)smem;                 // [64][128] (head overlay)
    __shared__ __align__(16) float s_w8[16][128]; // head weight chunk
    __shared__ float2 s_t[128];
    __shared__ float s_co[64];
    __shared__ float s_b1[128];
    __shared__ float s_w2[128];
    __shared__ float s_red[4][132];
    __shared__ float s_part[4][64];
    int t = threadIdx.x;
    if (t < 128) s_t[t] = trig[t];
    else { s_b1[t - 128] = fc1b[t - 128]; s_w2[t - 128] = fc2w[t - 128]; }
    for (int u = t; u < 4096; u += 256) s_cwT[u] = cwTl[u];
    // ---- mlp2 partials (corr) ----
    {
        int o = t & 63, q = t >> 6;
        const float* hv = hmid + b * 256 + q * 64;
        const float* gw = g2w + o * 256 + q * 64;
        float a = 0.f;
#pragma unroll 8
        for (int v = 0; v < 64; ++v) a += hv[v] * gw[v];
        s_part[q][o] = a;
    }
    // ---- G-phase (fused inva) ----
    {
        float2 rot = trig[h];
        int o = t & 63, ky0 = t >> 6;
        const float2* Fb = F + (size_t)b * 32768 + o;
        float a0r=0.f,a0i=0.f,a1r=0.f,a1i=0.f,a2r=0.f,a2i=0.f,a3r=0.f,a3i=0.f;
        float zr = 1.f, zi = 0.f;
        for (int m = 0; m < 16; ++m) {
            const float2* fm = Fb + m * 64;
            float2 f0 = fm[(ky0     ) * 2048];
            float2 f1 = fm[(ky0 +  4) * 2048];
            float2 f2 = fm[(ky0 +  8) * 2048];
            float2 f3 = fm[(ky0 + 12) * 2048];
            a0r += f0.x*zr - f0.y*zi; a0i += f0.x*zi + f0.y*zr;
            a1r += f1.x*zr - f1.y*zi; a1i += f1.x*zi + f1.y*zr;
            a2r += f2.x*zr - f2.y*zi; a2i += f2.x*zi + f2.y*zr;
            a3r += f3.x*zr - f3.y*zi; a3i += f3.x*zi + f3.y*zr;
            float nz = zr*rot.x - zi*rot.y; zi = zr*rot.y + zi*rot.x; zr = nz;
        }
        float z2r = zr, z2i = -zi;
        for (int m = 16; m < 32; ++m) {
            const float2* fm = Fb + m * 64;
            float2 f0 = fm[(ky0     ) * 2048];
            float2 f1 = fm[(ky0 +  4) * 2048];
            float2 f2 = fm[(ky0 +  8) * 2048];
            float2 f3 = fm[(ky0 + 12) * 2048];
            a0r += f0.x*z2r - f0.y*z2i; a0i += f0.x*z2i + f0.y*z2r;
            a1r += f1.x*z2r - f1.y*z2i; a1i += f1.x*z2i + f1.y*z2r;
            a2r += f2.x*z2r - f2.y*z2i; a2i += f2.x*z2i + f2.y*z2r;
            a3r += f3.x*z2r - f3.y*z2i; a3i += f3.x*z2i + f3.y*z2r;
            float nz = z2r*rot.x - z2i*rot.y; z2i = z2r*rot.y + z2i*rot.x; z2r = nz;
        }
        float2* sg = (float2*)(smem + 16384);
        sg[(ky0     ) * 64 + o] = make_float2(a0r, a0i);
        sg[(ky0 +  4) * 64 + o] = make_float2(a1r, a1i);
        sg[(ky0 +  8) * 64 + o] = make_float2(a2r, a2i);
        sg[(ky0 + 12) * 64 + o] = make_float2(a3r, a3i);
    }
    __syncthreads();
    if (t < 64)
        s_co[t] = s_part[0][t] + s_part[1][t] + s_part[2][t] + s_part[3][t]
                + g2b[t] + cbl[t];
    int ot2 = t >> 6;
    int wt6 = t & 63;
    int o0 = ot2 * 16;
    float acc[16][2];
#pragma unroll
    for (int i = 0; i < 16; ++i) { acc[i][0] = 0.f; acc[i][1] = 0.f; }
    float2 rw0 = s_t[wt6];
    float2 rw1 = s_t[wt6 + 64];
    float z0r = 1.f, z0i = 0.f, z1r = 1.f, z1i = 0.f;
    const float invn = 1.0f / 16384.0f;
    for (int ky = 0; ky < 16; ++ky) {
        float fs = (ky == 0) ? invn : (2.f * invn);
        float tc0 = fs * z0r, ts0 = fs * z0i;
        float tc1 = fs * z1r, ts1 = fs * z1i;
        const float4* gk = (const float4*)(s_g + ky * 64 + o0);
#pragma unroll
        for (int i2 = 0; i2 < 8; ++i2) {
            float4 g2 = gk[i2];
            acc[2*i2][0]   += g2.x * tc0 - g2.y * ts0;
            acc[2*i2][1]   += g2.x * tc1 - g2.y * ts1;
            acc[2*i2+1][0] += g2.z * tc0 - g2.w * ts0;
            acc[2*i2+1][1] += g2.z * tc1 - g2.w * ts1;
        }
        float nz0 = z0r * rw0.x - z0i * rw0.y; z0i = z0r * rw0.y + z0i * rw0.x; z0r = nz0;
        float nz1 = z1r * rw1.x - z1i * rw1.y; z1i = z1r * rw1.y + z1i * rw1.x; z1r = nz1;
    }
    // ---- conv: direct global reads ----
    const float* hp = hin + ((size_t)(b * 64) * 128 + h) * 128;
    for (int cc = 0; cc < 64; cc += 8) {
        float hv0[8], hv1[8];
#pragma unroll
        for (int c = 0; c < 8; ++c) {
            hv0[c] = hp[(size_t)(cc + c) * 16384 + wt6];
            hv1[c] = hp[(size_t)(cc + c) * 16384 + wt6 + 64];
        }
#pragma unroll
        for (int c = 0; c < 8; ++c) {
            const float4* cwp = (const float4*)(s_cwT + (cc + c) * 64 + o0);
#pragma unroll
            for (int i4 = 0; i4 < 4; ++i4) {
                float4 cv = cwp[i4];
                acc[4*i4][0]   += cv.x * hv0[c]; acc[4*i4][1]   += cv.x * hv1[c];
                acc[4*i4+1][0] += cv.y * hv0[c]; acc[4*i4+1][1] += cv.y * hv1[c];
                acc[4*i4+2][0] += cv.z * hv0[c]; acc[4*i4+2][1] += cv.z * hv1[c];
                acc[4*i4+3][0] += cv.w * hv0[c]; acc[4*i4+3][1] += cv.w * hv1[c];
            }
        }
    }
    // ---- features into LDS overlay (no GELU final layer) ----
    __syncthreads();
#pragma unroll
    for (int i = 0; i < 16; ++i) {
        float co = s_co[o0 + i];
        s_hall[(o0 + i) * 128 + wt6]      = acc[i][0] + co;
        s_hall[(o0 + i) * 128 + wt6 + 64] = acc[i][1] + co;
    }
    // ---- head: fc1 (wave-uniform j-tile 32) + GELU + fc2 ----
    int j0 = ot2 * 32;
    float a32[32][2];
#pragma unroll
    for (int i = 0; i < 32; ++i) { a32[i][0] = 0.f; a32[i][1] = 0.f; }
    for (int cc = 0; cc < 64; cc += 16) {
        __syncthreads();
        for (int u = t; u < 2048; u += 256)
            s_w8[u >> 7][u & 127] = fc1wT[(cc + (u >> 7)) * 128 + (u & 127)];
        __syncthreads();
        for (int c = 0; c < 16; ++c) {
            float hv0 = s_hall[(cc + c) * 128 + wt6];
            float hv1 = s_hall[(cc + c) * 128 + wt6 + 64];
            const float4* wp = (const float4*)(&s_w8[c][j0]);
#pragma unroll
            for (int q = 0; q < 8; ++q) {
                float4 wx = wp[q];
                a32[4*q][0]   += wx.x * hv0; a32[4*q][1]   += wx.x * hv1;
                a32[4*q+1][0] += wx.y * hv0; a32[4*q+1][1] += wx.y * hv1;
                a32[4*q+2][0] += wx.z * hv0; a32[4*q+2][1] += wx.z * hv1;
                a32[4*q+3][0] += wx.w * hv0; a32[4*q+3][1] += wx.w * hv1;
            }
        }
    }
    float sum0 = 0.f, sum1 = 0.f;
#pragma unroll
    for (int i = 0; i < 32; ++i) {
        float b1 = s_b1[j0 + i];
        float w2 = s_w2[j0 + i];
        sum0 += gelu_f(a32[i][0] + b1) * w2;
        sum1 += gelu_f(a32[i][1] + b1) * w2;
    }
    s_red[ot2][wt6] = sum0;
    s_red[ot2][wt6 + 64] = sum1;
    __syncthreads();
    if (t < NS) {
        out[b * (NS * NS) + h * NS + t] =
            fc2b[0] + s_red[0][t] + s_red[1][t] + s_red[2][t] + s_red[3][t];
    }
}

extern "C" void kernel_launch(void* const* d_in, const int* in_sizes, int n_in,
                              void* d_out, int out_size, void* d_ws, size_t ws_size,
                              hipStream_t stream) {
    const float* x    = (const float*)d_in[0];
    const float* sw1r = (const float*)d_in[1];
    const float* sw1i = (const float*)d_in[2];
    const float* sw2r = (const float*)d_in[3];
    const float* sw2i = (const float*)d_in[4];
    const float* g1w  = (const float*)d_in[5];
    const float* g1b  = (const float*)d_in[6];
    const float* g2w  = (const float*)d_in[7];
    const float* g2b  = (const float*)d_in[8];
    const float* cw   = (const float*)d_in[9];
    const float* cb   = (const float*)d_in[10];
    const float* fc0w = (const float*)d_in[11];
    const float* fc0b = (const float*)d_in[12];
    const float* fc1w = (const float*)d_in[13];
    const float* fc1b = (const float*)d_in[14];
    const float* fc2w = (const float*)d_in[15];
    const float* fc2b = (const float*)d_in[16];
    float* out = (float*)d_out;

    char* ws = (char*)d_ws;
    const size_t SZ_H   = (size_t)NB * NC * NH * NW * 4;      // 33554432
    const size_t SZ_XFT = (size_t)NB * NC * 32 * 16 * 8;      // 2097152
    const size_t SZ_F   = SZ_XFT;                             // 2097152
    size_t off = 0;
    float2* trig = (float2*)(ws + off); off += 1024;
    float2* wdft = (float2*)(ws + off); off += 2048 * 8;
    float*  f1T  = (float*)(ws + off);  off += 8192 * 4;
    float*  cwT  = (float*)(ws + off);  off += 16384 * 4;
    float*  hA   = (float*)(ws + off);  off += SZ_H;
    float*  hB   = (float*)(ws + off);  off += SZ_H;
    float2* xft  = (float2*)(ws + off); off += SZ_XFT;
    float2* F    = (float2*)(ws + off); off += SZ_F;
    float*  cr   = (float*)(ws + off);  off += (size_t)NB * NC * 16 * 4;
    float*  hmid = (float*)(ws + off);  off += (size_t)NB * 256 * 4;
    (void)ws_size; (void)in_sizes; (void)n_in; (void)out_size;

    k_trig<<<1, 128, 0, stream>>>(trig);
    k_tab<<<16, 128, 0, stream>>>(wdft);
    k_tc<<<96, 256, 0, stream>>>(fc1w, cw, f1T, cwT);
    k_fc0<<<512, 256, 0, stream>>>(x, fc0w, fc0b, hA);

    float* hcur = hA;
    float* hnxt = hB;
    for (int l = 0; l < 4; ++l) {
        const float* w1r = sw1r + (size_t)l * 1048576;
        const float* w1i = sw1i + (size_t)l * 1048576;
        const float* w2r = sw2r + (size_t)l * 1048576;
        const float* w2i = sw2i + (size_t)l * 1048576;
        const float* g1w_l = g1w + (size_t)l * 524288;
        const float* g1b_l = g1b + l * 256;
        const float* g2w_l = g2w + (size_t)l * 16384;
        const float* g2b_l = g2b + l * 64;
        const float* cwT_l = cwT + (size_t)l * 4096;
        const float* cb_l  = cb + l * 64;

        k_dft2<<<512, 256, 0, stream>>>(hcur, xft, cr, wdft, trig);
        k_mixmlp<<<768, 512, 0, stream>>>(xft, w1r, w1i, w2r, w2i,
                                          cr, g1w_l, g1b_l, hmid, F);
        if (l < 3) {
            k_invb<<<1024, 256, 0, stream>>>(F, hcur, cwT_l, cb_l, hmid,
                                             g2w_l, g2b_l, trig, hnxt, 1);
            float* tmp = hcur; hcur = hnxt; hnxt = tmp;
        } else {
            k_invbh<<<NB * NS, 256, 0, stream>>>(F, hcur, cwT_l, cb_l, hmid,
                                                 g2w_l, g2b_l, trig,
                                                 f1T, fc1b, fc2w, fc2b, out);
        }
    }
}

// Round 11
// 455.753 us; speedup vs baseline: 1.3105x; 1.0966x over previous
//
#include <hip/hip_runtime.h>
#include <math.h>

#define NB 8
#define NC 64
#define NH 128
#define NW 128
#define NS 119
#define NPIX 113288   // 8*119*119

typedef __attribute__((ext_vector_type(8))) short bf16x8;
typedef __attribute__((ext_vector_type(4))) float f32x4;
typedef __attribute__((ext_vector_type(4))) unsigned short ushort4v;

__device__ __forceinline__ float gelu_f(float v) {
    return 0.5f * v * (1.0f + erff(v * 0.70710678118654752f));
}

__device__ __forceinline__ unsigned short f2bf(float x) {
    unsigned int u = __builtin_bit_cast(unsigned int, x);
    u += 0x7FFFu + ((u >> 16) & 1u);
    return (unsigned short)(u >> 16);
}

// ---------------- trig table: trig[t] = (cos, sin)(2*pi*t/128) ----------------
__global__ void __launch_bounds__(128) k_trig(float2* __restrict__ trig) {
    int t = threadIdx.x;
    double a = (double)t * (3.14159265358979323846 / 64.0);
    trig[t] = make_float2((float)cos(a), (float)sin(a));
}

// ---------------- W-DFT matrix in MFMA B-fragment order (bf16) ----------------
// WM[w][n]: n=2q -> cos(2pi q w/128), n=2q+1 -> -sin(2pi q w/128)
// frag f = ni*4+k; lane l elem e holds WM[k*32 + (l>>4)*8 + e][ni*16 + (l&15)]
__global__ void __launch_bounds__(256) k_tabm(short* __restrict__ wmf) {
    int idx = blockIdx.x * 256 + threadIdx.x;   // 0..4095
    int f = idx >> 9;
    int l = (idx >> 3) & 63;
    int e = idx & 7;
    int ni = f >> 2, k = f & 3;
    int w = k * 32 + (l >> 4) * 8 + e;
    int n = ni * 16 + (l & 15);
    int q = n >> 1;
    int prod = (q * w) & 127;
    double a = (double)prod * (3.14159265358979323846 / 64.0);
    float v = (float)((n & 1) ? -sin(a) : cos(a));
    unsigned int u = __builtin_bit_cast(unsigned int, v);
    u += 0x7FFFu + ((u >> 16) & 1u);
    wmf[idx] = (short)(u >> 16);
}

// ---------------- transposes: fc1wT[c][j] = fc1w[j][c]; cwT[l][c][o] = cw[l][o][c] ----------------
__global__ void __launch_bounds__(256) k_tc(const float* __restrict__ fc1w,
                                            const float* __restrict__ cw,
                                            float* __restrict__ fc1wT,
                                            float* __restrict__ cwT) {
    int u = blockIdx.x * 256 + threadIdx.x;   // 0..24575
    if (u < 8192) {
        int c = u >> 7, j = u & 127;
        fc1wT[u] = fc1w[j * 64 + c];
    } else {
        int v = u - 8192;                      // 0..16383
        int l = v >> 12, idx = v & 4095;
        int c = idx >> 6, o = idx & 63;
        cwT[v] = cw[l * 4096 + o * 64 + c];
    }
}

// ---------------- fc0 + grid concat + transpose + zero pad ----------------
__global__ void __launch_bounds__(256) k_fc0(const float* __restrict__ x,
                                             const float* __restrict__ w,
                                             const float* __restrict__ bia,
                                             float* __restrict__ h) {
    __shared__ float sw[320];
    __shared__ float sb[64];
    int t = threadIdx.x;
    for (int u = t; u < 320; u += 256) sw[u] = w[u];
    if (t < 64) sb[t] = bia[t];
    __syncthreads();
    int p = blockIdx.x * 256 + t;            // 0 .. 131071
    int b = p >> 14;
    int rem = p & 16383;
    int r = rem >> 7, wc = rem & 127;
    float v0 = 0.f, v1 = 0.f, v2 = 0.f, gx = 0.f, gy = 0.f;
    bool inside = (r < NS) && (wc < NS);
    if (inside) {
        const float* xp = x + ((size_t)(b * NS + r) * NS + wc) * 3;
        v0 = xp[0]; v1 = xp[1]; v2 = xp[2];
        gx = (float)r * (1.0f / 118.0f);
        gy = (float)wc * (1.0f / 118.0f);
    }
    float* hp = h + (size_t)b * NC * NH * NW + rem;
    for (int c = 0; c < 64; ++c) {
        float val = 0.f;
        if (inside) {
            const float* wr = sw + c * 5;
            val = v0 * wr[0] + v1 * wr[1] + v2 * wr[2] + gx * wr[3] + gy * wr[4] + sb[c];
        }
        hp[c * (NH * NW)] = val;
    }
}

// ---------------- fused 2D partial DFT (MFMA phase-1) + CFT: one block per (b,c) ----
// phase 1: T[128][16] complex = X[128][128] x WM[128][32] via mfma bf16 (fp32 accum)
// phase 2: xft[m][ky] = sum_h T[h][ky] e^{-2pi i kx(m) h/128} (fp32 VALU)
// CFT partials from global (exact fp32), during iter 0.
__global__ void __launch_bounds__(256) k_dft2(const float* __restrict__ h,
                                              float2* __restrict__ xft,
                                              float* __restrict__ cr,
                                              const short* __restrict__ wmf,
                                              const float2* __restrict__ trig) {
    __shared__ __align__(16) short sxb[32][136];   // bf16 X chunk; 272B row stride
    __shared__ float2 sT[128][17];
    __shared__ float2 st[128];
    __shared__ float s_cs[2][32][8];
    __shared__ float s_cq[2][32][8];
    int t = threadIdx.x;
    int bc = blockIdx.x;
    if (t < 128) st[t] = trig[t];
    int lane = t & 63, wv = t >> 6;
    int mi = wv >> 1, ni = wv & 1;      // wave -> (M-tile, N-tile)
    bf16x8 bfrag[4];
    {
        const short* wp = wmf + ((size_t)(ni * 4) * 64 + lane) * 8;
#pragma unroll
        for (int k = 0; k < 4; ++k) bfrag[k] = *(const bf16x8*)(wp + k * 512);
    }
    const float* src = h + (size_t)bc * 16384;
    const short* abase = &sxb[mi * 16 + (lane & 15)][(lane >> 4) * 8];
    for (int it = 0; it < 4; ++it) {
        __syncthreads();
        // stage 32 rows -> bf16 LDS (coalesced float4 reads, b64 LDS writes)
#pragma unroll
        for (int j = 0; j < 4; ++j) {
            int idx4 = t + j * 256;
            float4 v = *(const float4*)(src + (size_t)it * 4096 + (size_t)idx4 * 4);
            ushort4v pk;
            pk.x = f2bf(v.x); pk.y = f2bf(v.y); pk.z = f2bf(v.z); pk.w = f2bf(v.w);
            int row = idx4 >> 5, c4 = (idx4 & 31) * 4;
            *(ushort4v*)(&sxb[row][c4]) = pk;
        }
        if (it == 0) {
            // CFT partials, exact fp32 from global (L1/L2-hot)
            int rr = t >> 3, k = t & 7;
            const float* rowp = src + rr * 128;
            float cs0 = 0.f, cq0 = 0.f, cs1 = 0.f, cq1 = 0.f;
#pragma unroll
            for (int g = 0; g < 4; ++g) {
                float a = rowp[g * 8 + k];       cs0 += a;  cq0 += a * a;
                float b = rowp[32 + g * 8 + k];  cs1 += b;  cq1 += b * b;
            }
            s_cs[0][rr][k] = cs0; s_cs[1][rr][k] = cs1;
            s_cq[0][rr][k] = cq0; s_cq[1][rr][k] = cq1;
        }
        __syncthreads();
        f32x4 D = {0.f, 0.f, 0.f, 0.f};
#pragma unroll
        for (int k = 0; k < 4; ++k) {
            bf16x8 a = *(const bf16x8*)(abase + k * 32);
            D = __builtin_amdgcn_mfma_f32_16x16x32_bf16(a, bfrag[k], D, 0, 0, 0);
        }
        // D[row][col]: row = (lane>>4)*4 + reg, col = lane&15  [m89]
        int row = it * 32 + mi * 16 + ((lane >> 4) << 2);
        int col = ni * 16 + (lane & 15);       // n index; float offset in sT row = n
        float* sTf = (float*)&sT[0][0];
#pragma unroll
        for (int r = 0; r < 4; ++r) sTf[(size_t)(row + r) * 34 + col] = D[r];
    }
    __syncthreads();
    // ---- phase 2: H-direction partial DFT (fp32) ----
    int ky = t & 15;
    int mlo = t >> 4;
    int kxa = mlo, kxb = 112 + mlo;
    float2 sva = st[kxa]; float sca = sva.x, ssa = -sva.y;
    float2 svb = st[kxb]; float scb = svb.x, ssb = -svb.y;
    float rea = 0.f, ima = 0.f, reb = 0.f, imb = 0.f;
    for (int h0 = 0; h0 < 128; h0 += 16) {
        float2 bva = st[(kxa * h0) & 127]; float cca = bva.x, csa = -bva.y;
        float2 bvb = st[(kxb * h0) & 127]; float ccb = bvb.x, csb = -bvb.y;
#pragma unroll
        for (int j = 0; j < 16; ++j) {
            float2 Tv = sT[h0 + j][ky];
            rea += Tv.x * cca - Tv.y * csa;
            ima += Tv.x * csa + Tv.y * cca;
            reb += Tv.x * ccb - Tv.y * csb;
            imb += Tv.x * csb + Tv.y * ccb;
            float na = cca * sca - csa * ssa; csa = cca * ssa + csa * sca; cca = na;
            float nb = ccb * scb - csb * ssb; csb = ccb * ssb + csb * scb; ccb = nb;
        }
    }
    float2* xp = xft + (size_t)bc * 512;
    xp[mlo * 16 + ky] = make_float2(rea, ima);
    xp[(mlo + 16) * 16 + ky] = make_float2(reb, imb);
    if (t < 16) {
        int half = t >> 3, k = t & 7;
        float s = 0.f, q = 0.f;
        for (int rr = 0; rr < 32; ++rr) {
            s += s_cs[half][rr][k];
#pragma unroll
            for (int kk = 0; kk < 8; ++kk) q += s_cq[half][rr][kk];
        }
        float norm = fmaxf(sqrtf(q), 1e-12f);
        cr[bc * 16 + t] = s / (128.0f * norm);
    }
}

// ---------------- spectral mix (blocks 0..511) + MLP stage 1 (blocks 512..767) ----------------
__global__ void __launch_bounds__(512) k_mixmlp(const float2* __restrict__ xft,
                                                const float* __restrict__ w1r,
                                                const float* __restrict__ w1i,
                                                const float* __restrict__ w2r,
                                                const float* __restrict__ w2i,
                                                const float* __restrict__ cr,
                                                const float* __restrict__ g1w,
                                                const float* __restrict__ g1b,
                                                float* __restrict__ hmid,
                                                float2* __restrict__ F) {
    __shared__ __align__(16) char smem[36864];
    int t = threadIdx.x;
    int bid = blockIdx.x;
    if (bid < 512) {
        float2* s_w = (float2*)smem;               // [64][64] (i,o)
        float2* s_x = (float2*)(smem + 32768);     // [8][64]  (b,i)
        int m = (bid & 7) + 8 * ((bid >> 3) & 3);  // XCD swizzle
        int e = bid >> 5;                          // ky
        const float* wr; const float* wi; int mm;
        if (m < 16) { wr = w1r; wi = w1i; mm = m; } else { wr = w2r; wi = w2i; mm = m - 16; }
        int off = mm * 16 + e;
        for (int u = t; u < 4096; u += 512) {
            s_w[u] = make_float2(wr[(u << 8) + off], wi[(u << 8) + off]);
        }
        {
            int bb = t >> 6, i = t & 63;
            s_x[bb * 64 + i] = xft[((size_t)(bb * 64 + i) * 32 + m) * 16 + e];
        }
        __syncthreads();
        int bb = t >> 6, o = t & 63;
        float re = 0.f, im = 0.f;
#pragma unroll 8
        for (int i = 0; i < 64; ++i) {
            float2 xv = s_x[bb * 64 + i];
            float2 wv = s_w[i * 64 + o];
            re += xv.x * wv.x - xv.y * wv.y;
            im += xv.x * wv.y + xv.y * wv.x;
        }
        F[((size_t)(bb * 16 + e) * 32 + m) * 64 + o] = make_float2(re, im);
    } else {
        float* s_cr   = (float*)smem;              // [8][1024]
        float* s_wave = (float*)(smem + 32768);    // [8][8]
        int j = bid - 512;
        for (int u = t; u < 8192; u += 512) s_cr[u] = cr[u];
        const float* wrow = g1w + (size_t)j * 2048;
        float w0 = wrow[4 * t], w1 = wrow[4 * t + 2];
        __syncthreads();
        float acc[8];
#pragma unroll
        for (int b = 0; b < 8; ++b) {
            float2 v = *(const float2*)(s_cr + b * 1024 + 2 * t);
            acc[b] = v.x * w0 + v.y * w1;
        }
#pragma unroll
        for (int d = 32; d > 0; d >>= 1) {
#pragma unroll
            for (int b = 0; b < 8; ++b) acc[b] += __shfl_down(acc[b], d, 64);
        }
        int wv = t >> 6;
        if ((t & 63) == 0) {
#pragma unroll
            for (int b = 0; b < 8; ++b) s_wave[wv * 8 + b] = acc[b];
        }
        __syncthreads();
        if (t < 8) {
            float a = g1b[j];
            for (int q = 0; q < 8; ++q) a += s_wave[q * 8 + t];
            hmid[t * 256 + j] = gelu_f(a);
        }
    }
}

// ---------------- inverse B (fused inva + mlp2) + 1x1 conv + corr + bias (+GELU) ----------------
__global__ void __launch_bounds__(256, 4) k_invb(const float2* __restrict__ F,
                                                 const float* __restrict__ hin,
                                                 const float* __restrict__ cwTl,
                                                 const float* __restrict__ cbl,
                                                 const float* __restrict__ hmid,
                                                 const float* __restrict__ g2w,
                                                 const float* __restrict__ g2b,
                                                 const float2* __restrict__ trig,
                                                 float* __restrict__ hout,
                                                 int do_gelu) {
    int blk = blockIdx.x;
    int b = blk >> 7, h = blk & 127;
    __shared__ __align__(16) float s_cwT[64][64];   // [c][o]
    __shared__ __align__(16) float2 s_g[16][64];    // [ky][o]
    __shared__ float2 s_t[128];
    __shared__ float s_co[64];
    __shared__ float s_part[4][64];
    int t = threadIdx.x;
    if (t < 128) s_t[t] = trig[t];
    {
        float* cw0 = &s_cwT[0][0];
        for (int u = t; u < 4096; u += 256) cw0[u] = cwTl[u];
    }
    // ---- mlp2 partials (corr) ----
    {
        int o = t & 63, q = t >> 6;
        const float* hv = hmid + b * 256 + q * 64;
        const float* gw = g2w + o * 256 + q * 64;
        float a = 0.f;
#pragma unroll 8
        for (int v = 0; v < 64; ++v) a += hv[v] * gw[v];
        s_part[q][o] = a;
    }
    // ---- G-phase (fused inva) ----
    {
        float2 rot = trig[h];              // e^{+2pi i h/128}, uniform
        int o = t & 63, ky0 = t >> 6;
        const float2* Fb = F + (size_t)b * 32768 + o;
        float a0r=0.f,a0i=0.f,a1r=0.f,a1i=0.f,a2r=0.f,a2i=0.f,a3r=0.f,a3i=0.f;
        float zr = 1.f, zi = 0.f;
        for (int m = 0; m < 16; ++m) {
            const float2* fm = Fb + m * 64;
            float2 f0 = fm[(ky0     ) * 2048];
            float2 f1 = fm[(ky0 +  4) * 2048];
            float2 f2 = fm[(ky0 +  8) * 2048];
            float2 f3 = fm[(ky0 + 12) * 2048];
            a0r += f0.x*zr - f0.y*zi; a0i += f0.x*zi + f0.y*zr;
            a1r += f1.x*zr - f1.y*zi; a1i += f1.x*zi + f1.y*zr;
            a2r += f2.x*zr - f2.y*zi; a2i += f2.x*zi + f2.y*zr;
            a3r += f3.x*zr - f3.y*zi; a3i += f3.x*zi + f3.y*zr;
            float nz = zr*rot.x - zi*rot.y; zi = zr*rot.y + zi*rot.x; zr = nz;
        }
        float z2r = zr, z2i = -zi;         // m=16 -> kx=112 = conj
        for (int m = 16; m < 32; ++m) {
            const float2* fm = Fb + m * 64;
            float2 f0 = fm[(ky0     ) * 2048];
            float2 f1 = fm[(ky0 +  4) * 2048];
            float2 f2 = fm[(ky0 +  8) * 2048];
            float2 f3 = fm[(ky0 + 12) * 2048];
            a0r += f0.x*z2r - f0.y*z2i; a0i += f0.x*z2i + f0.y*z2r;
            a1r += f1.x*z2r - f1.y*z2i; a1i += f1.x*z2i + f1.y*z2r;
            a2r += f2.x*z2r - f2.y*z2i; a2i += f2.x*z2i + f2.y*z2r;
            a3r += f3.x*z2r - f3.y*z2i; a3i += f3.x*z2i + f3.y*z2r;
            float nz = z2r*rot.x - z2i*rot.y; z2i = z2r*rot.y + z2i*rot.x; z2r = nz;
        }
        s_g[ky0     ][o] = make_float2(a0r, a0i);
        s_g[ky0 +  4][o] = make_float2(a1r, a1i);
        s_g[ky0 +  8][o] = make_float2(a2r, a2i);
        s_g[ky0 + 12][o] = make_float2(a3r, a3i);
    }
    __syncthreads();
    if (t < 64)
        s_co[t] = s_part[0][t] + s_part[1][t] + s_part[2][t] + s_part[3][t]
                + g2b[t] + cbl[t];
    int ot2 = t >> 6;
    int wt6 = t & 63;
    int o0 = ot2 * 16;
    float acc[16][2];
#pragma unroll
    for (int i = 0; i < 16; ++i) { acc[i][0] = 0.f; acc[i][1] = 0.f; }
    float2 rw0 = s_t[wt6];
    float2 rw1 = s_t[wt6 + 64];
    float z0r = 1.f, z0i = 0.f, z1r = 1.f, z1i = 0.f;
    const float invn = 1.0f / 16384.0f;
    for (int ky = 0; ky < 16; ++ky) {
        float fs = (ky == 0) ? invn : (2.f * invn);   // invn folded into twiddle
        float tc0 = fs * z0r, ts0 = fs * z0i;
        float tc1 = fs * z1r, ts1 = fs * z1i;
        const float4* gk = (const float4*)(&s_g[ky][o0]);
#pragma unroll
        for (int i2 = 0; i2 < 8; ++i2) {
            float4 g2 = gk[i2];
            acc[2*i2][0]   += g2.x * tc0 - g2.y * ts0;
            acc[2*i2][1]   += g2.x * tc1 - g2.y * ts1;
            acc[2*i2+1][0] += g2.z * tc0 - g2.w * ts0;
            acc[2*i2+1][1] += g2.z * tc1 - g2.w * ts1;
        }
        float nz0 = z0r * rw0.x - z0i * rw0.y; z0i = z0r * rw0.y + z0i * rw0.x; z0r = nz0;
        float nz1 = z1r * rw1.x - z1i * rw1.y; z1i = z1r * rw1.y + z1i * rw1.x; z1r = nz1;
    }
    // ---- conv: direct global reads ----
    const float* hp = hin + ((size_t)(b * 64) * 128 + h) * 128;
    for (int cc = 0; cc < 64; cc += 4) {
        float hv0[4], hv1[4];
#pragma unroll
        for (int c = 0; c < 4; ++c) {
            hv0[c] = hp[(size_t)(cc + c) * 16384 + wt6];
            hv1[c] = hp[(size_t)(cc + c) * 16384 + wt6 + 64];
        }
#pragma unroll
        for (int c = 0; c < 4; ++c) {
            const float4* cwp = (const float4*)(&s_cwT[cc + c][o0]);
#pragma unroll
            for (int i4 = 0; i4 < 4; ++i4) {
                float4 cv = cwp[i4];
                acc[4*i4][0]   += cv.x * hv0[c]; acc[4*i4][1]   += cv.x * hv1[c];
                acc[4*i4+1][0] += cv.y * hv0[c]; acc[4*i4+1][1] += cv.y * hv1[c];
                acc[4*i4+2][0] += cv.z * hv0[c]; acc[4*i4+2][1] += cv.z * hv1[c];
                acc[4*i4+3][0] += cv.w * hv0[c]; acc[4*i4+3][1] += cv.w * hv1[c];
            }
        }
    }
    __syncthreads();
#pragma unroll
    for (int i = 0; i < 16; ++i) {
        int o = o0 + i;
        float co = s_co[o];
        float* outp = hout + ((size_t)(b * 64 + o) * 128 + h) * 128;
        float v0 = acc[i][0] + co;
        float v1 = acc[i][1] + co;
        if (do_gelu) { v0 = gelu_f(v0); v1 = gelu_f(v1); }
        outp[wt6] = v0;
        outp[wt6 + 64] = v1;
    }
}

// ---------------- FINAL layer: inverse B (fused inva + mlp2) + conv + head ----------------
// (256,2): >=128 VGPR needed (acc[16][2] + a32[32][2]) — (256,3) spilled (R7).
__global__ void __launch_bounds__(256, 2) k_invbh(const float2* __restrict__ F,
                                                  const float* __restrict__ hin,
                                                  const float* __restrict__ cwTl,
                                                  const float* __restrict__ cbl,
                                                  const float* __restrict__ hmid,
                                                  const float* __restrict__ g2w,
                                                  const float* __restrict__ g2b,
                                                  const float2* __restrict__ trig,
                                                  const float* __restrict__ fc1wT,
                                                  const float* __restrict__ fc1b,
                                                  const float* __restrict__ fc2w,
                                                  const float* __restrict__ fc2b,
                                                  float* __restrict__ out) {
    int blk = blockIdx.x;                 // 0..951
    int b = blk / 119;
    int h = blk - b * 119;
    __shared__ __align__(16) char smem[32768];
    float*  s_cwT = (float*)smem;                 // [64][64]  (phase A)
    float2* s_g   = (float2*)(smem + 16384);      // [16][64]  (phase A)
    float*  s_hall= (float*)smem;                 // [64][128] (head overlay)
    __shared__ __align__(16) float s_w8[16][128]; // head weight chunk
    __shared__ float2 s_t[128];
    __shared__ float s_co[64];
    __shared__ float s_b1[128];
    __shared__ float s_w2[128];
    __shared__ float s_red[4][132];
    __shared__ float s_part[4][64];
    int t = threadIdx.x;
    if (t < 128) s_t[t] = trig[t];
    else { s_b1[t - 128] = fc1b[t - 128]; s_w2[t - 128] = fc2w[t - 128]; }
    for (int u = t; u < 4096; u += 256) s_cwT[u] = cwTl[u];
    // ---- mlp2 partials (corr) ----
    {
        int o = t & 63, q = t >> 6;
        const float* hv = hmid + b * 256 + q * 64;
        const float* gw = g2w + o * 256 + q * 64;
        float a = 0.f;
#pragma unroll 8
        for (int v = 0; v < 64; ++v) a += hv[v] * gw[v];
        s_part[q][o] = a;
    }
    // ---- G-phase (fused inva) ----
    {
        float2 rot = trig[h];
        int o = t & 63, ky0 = t >> 6;
        const float2* Fb = F + (size_t)b * 32768 + o;
        float a0r=0.f,a0i=0.f,a1r=0.f,a1i=0.f,a2r=0.f,a2i=0.f,a3r=0.f,a3i=0.f;
        float zr = 1.f, zi = 0.f;
        for (int m = 0; m < 16; ++m) {
            const float2* fm = Fb + m * 64;
            float2 f0 = fm[(ky0     ) * 2048];
            float2 f1 = fm[(ky0 +  4) * 2048];
            float2 f2 = fm[(ky0 +  8) * 2048];
            float2 f3 = fm[(ky0 + 12) * 2048];
            a0r += f0.x*zr - f0.y*zi; a0i += f0.x*zi + f0.y*zr;
            a1r += f1.x*zr - f1.y*zi; a1i += f1.x*zi + f1.y*zr;
            a2r += f2.x*zr - f2.y*zi; a2i += f2.x*zi + f2.y*zr;
            a3r += f3.x*zr - f3.y*zi; a3i += f3.x*zi + f3.y*zr;
            float nz = zr*rot.x - zi*rot.y; zi = zr*rot.y + zi*rot.x; zr = nz;
        }
        float z2r = zr, z2i = -zi;
        for (int m = 16; m < 32; ++m) {
            const float2* fm = Fb + m * 64;
            float2 f0 = fm[(ky0     ) * 2048];
            float2 f1 = fm[(ky0 +  4) * 2048];
            float2 f2 = fm[(ky0 +  8) * 2048];
            float2 f3 = fm[(ky0 + 12) * 2048];
            a0r += f0.x*z2r - f0.y*z2i; a0i += f0.x*z2i + f0.y*z2r;
            a1r += f1.x*z2r - f1.y*z2i; a1i += f1.x*z2i + f1.y*z2r;
            a2r += f2.x*z2r - f2.y*z2i; a2i += f2.x*z2i + f2.y*z2r;
            a3r += f3.x*z2r - f3.y*z2i; a3i += f3.x*z2i + f3.y*z2r;
            float nz = z2r*rot.x - z2i*rot.y; z2i = z2r*rot.y + z2i*rot.x; z2r = nz;
        }
        float2* sg = (float2*)(smem + 16384);
        sg[(ky0     ) * 64 + o] = make_float2(a0r, a0i);
        sg[(ky0 +  4) * 64 + o] = make_float2(a1r, a1i);
        sg[(ky0 +  8) * 64 + o] = make_float2(a2r, a2i);
        sg[(ky0 + 12) * 64 + o] = make_float2(a3r, a3i);
    }
    __syncthreads();
    if (t < 64)
        s_co[t] = s_part[0][t] + s_part[1][t] + s_part[2][t] + s_part[3][t]
                + g2b[t] + cbl[t];
    int ot2 = t >> 6;
    int wt6 = t & 63;
    int o0 = ot2 * 16;
    float acc[16][2];
#pragma unroll
    for (int i = 0; i < 16; ++i) { acc[i][0] = 0.f; acc[i][1] = 0.f; }
    float2 rw0 = s_t[wt6];
    float2 rw1 = s_t[wt6 + 64];
    float z0r = 1.f, z0i = 0.f, z1r = 1.f, z1i = 0.f;
    const float invn = 1.0f / 16384.0f;
    for (int ky = 0; ky < 16; ++ky) {
        float fs = (ky == 0) ? invn : (2.f * invn);
        float tc0 = fs * z0r, ts0 = fs * z0i;
        float tc1 = fs * z1r, ts1 = fs * z1i;
        const float4* gk = (const float4*)(s_g + ky * 64 + o0);
#pragma unroll
        for (int i2 = 0; i2 < 8; ++i2) {
            float4 g2 = gk[i2];
            acc[2*i2][0]   += g2.x * tc0 - g2.y * ts0;
            acc[2*i2][1]   += g2.x * tc1 - g2.y * ts1;
            acc[2*i2+1][0] += g2.z * tc0 - g2.w * ts0;
            acc[2*i2+1][1] += g2.z * tc1 - g2.w * ts1;
        }
        float nz0 = z0r * rw0.x - z0i * rw0.y; z0i = z0r * rw0.y + z0i * rw0.x; z0r = nz0;
        float nz1 = z1r * rw1.x - z1i * rw1.y; z1i = z1r * rw1.y + z1i * rw1.x; z1r = nz1;
    }
    // ---- conv: direct global reads ----
    const float* hp = hin + ((size_t)(b * 64) * 128 + h) * 128;
    for (int cc = 0; cc < 64; cc += 8) {
        float hv0[8], hv1[8];
#pragma unroll
        for (int c = 0; c < 8; ++c) {
            hv0[c] = hp[(size_t)(cc + c) * 16384 + wt6];
            hv1[c] = hp[(size_t)(cc + c) * 16384 + wt6 + 64];
        }
#pragma unroll
        for (int c = 0; c < 8; ++c) {
            const float4* cwp = (const float4*)(s_cwT + (cc + c) * 64 + o0);
#pragma unroll
            for (int i4 = 0; i4 < 4; ++i4) {
                float4 cv = cwp[i4];
                acc[4*i4][0]   += cv.x * hv0[c]; acc[4*i4][1]   += cv.x * hv1[c];
                acc[4*i4+1][0] += cv.y * hv0[c]; acc[4*i4+1][1] += cv.y * hv1[c];
                acc[4*i4+2][0] += cv.z * hv0[c]; acc[4*i4+2][1] += cv.z * hv1[c];
                acc[4*i4+3][0] += cv.w * hv0[c]; acc[4*i4+3][1] += cv.w * hv1[c];
            }
        }
    }
    // ---- features into LDS overlay (no GELU final layer) ----
    __syncthreads();
#pragma unroll
    for (int i = 0; i < 16; ++i) {
        float co = s_co[o0 + i];
        s_hall[(o0 + i) * 128 + wt6]      = acc[i][0] + co;
        s_hall[(o0 + i) * 128 + wt6 + 64] = acc[i][1] + co;
    }
    // ---- head: fc1 (wave-uniform j-tile 32) + GELU + fc2 ----
    int j0 = ot2 * 32;
    float a32[32][2];
#pragma unroll
    for (int i = 0; i < 32; ++i) { a32[i][0] = 0.f; a32[i][1] = 0.f; }
    for (int cc = 0; cc < 64; cc += 16) {
        __syncthreads();
        for (int u = t; u < 2048; u += 256)
            s_w8[u >> 7][u & 127] = fc1wT[(cc + (u >> 7)) * 128 + (u & 127)];
        __syncthreads();
        for (int c = 0; c < 16; ++c) {
            float hv0 = s_hall[(cc + c) * 128 + wt6];
            float hv1 = s_hall[(cc + c) * 128 + wt6 + 64];
            const float4* wp = (const float4*)(&s_w8[c][j0]);
#pragma unroll
            for (int q = 0; q < 8; ++q) {
                float4 wx = wp[q];
                a32[4*q][0]   += wx.x * hv0; a32[4*q][1]   += wx.x * hv1;
                a32[4*q+1][0] += wx.y * hv0; a32[4*q+1][1] += wx.y * hv1;
                a32[4*q+2][0] += wx.z * hv0; a32[4*q+2][1] += wx.z * hv1;
                a32[4*q+3][0] += wx.w * hv0; a32[4*q+3][1] += wx.w * hv1;
            }
        }
    }
    float sum0 = 0.f, sum1 = 0.f;
#pragma unroll
    for (int i = 0; i < 32; ++i) {
        float b1 = s_b1[j0 + i];
        float w2 = s_w2[j0 + i];
        sum0 += gelu_f(a32[i][0] + b1) * w2;
        sum1 += gelu_f(a32[i][1] + b1) * w2;
    }
    s_red[ot2][wt6] = sum0;
    s_red[ot2][wt6 + 64] = sum1;
    __syncthreads();
    if (t < NS) {
        out[b * (NS * NS) + h * NS + t] =
            fc2b[0] + s_red[0][t] + s_red[1][t] + s_red[2][t] + s_red[3][t];
    }
}

extern "C" void kernel_launch(void* const* d_in, const int* in_sizes, int n_in,
                              void* d_out, int out_size, void* d_ws, size_t ws_size,
                              hipStream_t stream) {
    const float* x    = (const float*)d_in[0];
    const float* sw1r = (const float*)d_in[1];
    const float* sw1i = (const float*)d_in[2];
    const float* sw2r = (const float*)d_in[3];
    const float* sw2i = (const float*)d_in[4];
    const float* g1w  = (const float*)d_in[5];
    const float* g1b  = (const float*)d_in[6];
    const float* g2w  = (const float*)d_in[7];
    const float* g2b  = (const float*)d_in[8];
    const float* cw   = (const float*)d_in[9];
    const float* cb   = (const float*)d_in[10];
    const float* fc0w = (const float*)d_in[11];
    const float* fc0b = (const float*)d_in[12];
    const float* fc1w = (const float*)d_in[13];
    const float* fc1b = (const float*)d_in[14];
    const float* fc2w = (const float*)d_in[15];
    const float* fc2b = (const float*)d_in[16];
    float* out = (float*)d_out;

    char* ws = (char*)d_ws;
    const size_t SZ_H   = (size_t)NB * NC * NH * NW * 4;      // 33554432
    const size_t SZ_XFT = (size_t)NB * NC * 32 * 16 * 8;      // 2097152
    const size_t SZ_F   = SZ_XFT;                             // 2097152
    size_t off = 0;
    float2* trig = (float2*)(ws + off); off += 1024;
    short*  wmf  = (short*)(ws + off);  off += 4096 * 2;
    float*  f1T  = (float*)(ws + off);  off += 8192 * 4;
    float*  cwT  = (float*)(ws + off);  off += 16384 * 4;
    off = (off + 255) & ~(size_t)255;
    float*  hA   = (float*)(ws + off);  off += SZ_H;
    float*  hB   = (float*)(ws + off);  off += SZ_H;
    float2* xft  = (float2*)(ws + off); off += SZ_XFT;
    float2* F    = (float2*)(ws + off); off += SZ_F;
    float*  cr   = (float*)(ws + off);  off += (size_t)NB * NC * 16 * 4;
    float*  hmid = (float*)(ws + off);  off += (size_t)NB * 256 * 4;
    (void)ws_size; (void)in_sizes; (void)n_in; (void)out_size;

    k_trig<<<1, 128, 0, stream>>>(trig);
    k_tabm<<<16, 256, 0, stream>>>(wmf);
    k_tc<<<96, 256, 0, stream>>>(fc1w, cw, f1T, cwT);
    k_fc0<<<512, 256, 0, stream>>>(x, fc0w, fc0b, hA);

    float* hcur = hA;
    float* hnxt = hB;
    for (int l = 0; l < 4; ++l) {
        const float* w1r = sw1r + (size_t)l * 1048576;
        const float* w1i = sw1i + (size_t)l * 1048576;
        const float* w2r = sw2r + (size_t)l * 1048576;
        const float* w2i = sw2i + (size_t)l * 1048576;
        const float* g1w_l = g1w + (size_t)l * 524288;
        const float* g1b_l = g1b + l * 256;
        const float* g2w_l = g2w + (size_t)l * 16384;
        const float* g2b_l = g2b + l * 64;
        const float* cwT_l = cwT + (size_t)l * 4096;
        const float* cb_l  = cb + l * 64;

        k_dft2<<<512, 256, 0, stream>>>(hcur, xft, cr, wmf, trig);
        k_mixmlp<<<768, 512, 0, stream>>>(xft, w1r, w1i, w2r, w2i,
                                          cr, g1w_l, g1b_l, hmid, F);
        if (l < 3) {
            k_invb<<<1024, 256, 0, stream>>>(F, hcur, cwT_l, cb_l, hmid,
                                             g2w_l, g2b_l, trig, hnxt, 1);
            float* tmp = hcur; hcur = hnxt; hnxt = tmp;
        } else {
            k_invbh<<<NB * NS, 256, 0, stream>>>(F, hcur, cwT_l, cb_l, hmid,
                                                 g2w_l, g2b_l, trig,
                                                 f1T, fc1b, fc2w, fc2b, out);
        }
    }
}

// Round 13
// 453.409 us; speedup vs baseline: 1.3173x; 1.0052x over previous
//
#include <hip/hip_runtime.h>
#include <math.h>

#define NB 8
#define NC 64
#define NH 128
#define NW 128
#define NS 119
#define NPIX 113288   // 8*119*119

typedef __attribute__((ext_vector_type(8))) short bf16x8;
typedef __attribute__((ext_vector_type(4))) float f32x4;
typedef __attribute__((ext_vector_type(4))) unsigned short ushort4v;

__device__ __forceinline__ float gelu_f(float v) {
    return 0.5f * v * (1.0f + erff(v * 0.70710678118654752f));
}

__device__ __forceinline__ unsigned short f2bf(float x) {
    unsigned int u = __builtin_bit_cast(unsigned int, x);
    u += 0x7FFFu + ((u >> 16) & 1u);
    return (unsigned short)(u >> 16);
}

// ---------------- trig table: trig[t] = (cos, sin)(2*pi*t/128) ----------------
__global__ void __launch_bounds__(128) k_trig(float2* __restrict__ trig) {
    int t = threadIdx.x;
    double a = (double)t * (3.14159265358979323846 / 64.0);
    trig[t] = make_float2((float)cos(a), (float)sin(a));
}

// ---------------- W-DFT matrix in MFMA B-fragment order (bf16) ----------------
__global__ void __launch_bounds__(256) k_tabm(short* __restrict__ wmf) {
    int idx = blockIdx.x * 256 + threadIdx.x;   // 0..4095
    int f = idx >> 9;
    int l = (idx >> 3) & 63;
    int e = idx & 7;
    int ni = f >> 2, k = f & 3;
    int w = k * 32 + (l >> 4) * 8 + e;
    int n = ni * 16 + (l & 15);
    int q = n >> 1;
    int prod = (q * w) & 127;
    double a = (double)prod * (3.14159265358979323846 / 64.0);
    float v = (float)((n & 1) ? -sin(a) : cos(a));
    wmf[idx] = (short)f2bf(v);
}

// ---------------- transposes: fc1wT[c][j] = fc1w[j][c]; cwT[l][c][o] = cw[l][o][c] ----------------
__global__ void __launch_bounds__(256) k_tc(const float* __restrict__ fc1w,
                                            const float* __restrict__ cw,
                                            float* __restrict__ fc1wT,
                                            float* __restrict__ cwT) {
    int u = blockIdx.x * 256 + threadIdx.x;   // 0..24575
    if (u < 8192) {
        int c = u >> 7, j = u & 127;
        fc1wT[u] = fc1w[j * 64 + c];
    } else {
        int v = u - 8192;                      // 0..16383
        int l = v >> 12, idx = v & 4095;
        int c = idx >> 6, o = idx & 63;
        cwT[v] = cw[l * 4096 + o * 64 + c];
    }
}

// ---------------- fc0 + grid concat + transpose + zero pad ----------------
__global__ void __launch_bounds__(256) k_fc0(const float* __restrict__ x,
                                             const float* __restrict__ w,
                                             const float* __restrict__ bia,
                                             float* __restrict__ h) {
    __shared__ float sw[320];
    __shared__ float sb[64];
    int t = threadIdx.x;
    for (int u = t; u < 320; u += 256) sw[u] = w[u];
    if (t < 64) sb[t] = bia[t];
    __syncthreads();
    int p = blockIdx.x * 256 + t;            // 0 .. 131071
    int b = p >> 14;
    int rem = p & 16383;
    int r = rem >> 7, wc = rem & 127;
    float v0 = 0.f, v1 = 0.f, v2 = 0.f, gx = 0.f, gy = 0.f;
    bool inside = (r < NS) && (wc < NS);
    if (inside) {
        const float* xp = x + ((size_t)(b * NS + r) * NS + wc) * 3;
        v0 = xp[0]; v1 = xp[1]; v2 = xp[2];
        gx = (float)r * (1.0f / 118.0f);
        gy = (float)wc * (1.0f / 118.0f);
    }
    float* hp = h + (size_t)b * NC * NH * NW + rem;
    for (int c = 0; c < 64; ++c) {
        float val = 0.f;
        if (inside) {
            const float* wr = sw + c * 5;
            val = v0 * wr[0] + v1 * wr[1] + v2 * wr[2] + gx * wr[3] + gy * wr[4] + sb[c];
        }
        hp[c * (NH * NW)] = val;
    }
}

// ---------------- fused 2D partial DFT (MFMA phase-1) + CFT ----------------
__global__ void __launch_bounds__(256) k_dft2(const float* __restrict__ h,
                                              float2* __restrict__ xft,
                                              float* __restrict__ cr,
                                              const short* __restrict__ wmf,
                                              const float2* __restrict__ trig) {
    __shared__ __align__(16) short sxb[32][136];
    __shared__ float2 sT[128][17];
    __shared__ float2 st[128];
    __shared__ float s_cs[2][32][8];
    __shared__ float s_cq[2][32][8];
    int t = threadIdx.x;
    int bc = blockIdx.x;
    if (t < 128) st[t] = trig[t];
    int lane = t & 63, wv = t >> 6;
    int mi = wv >> 1, ni = wv & 1;
    bf16x8 bfrag[4];
    {
        const short* wp = wmf + ((size_t)(ni * 4) * 64 + lane) * 8;
#pragma unroll
        for (int k = 0; k < 4; ++k) bfrag[k] = *(const bf16x8*)(wp + k * 512);
    }
    const float* src = h + (size_t)bc * 16384;
    const short* abase = &sxb[mi * 16 + (lane & 15)][(lane >> 4) * 8];
    for (int it = 0; it < 4; ++it) {
        __syncthreads();
#pragma unroll
        for (int j = 0; j < 4; ++j) {
            int idx4 = t + j * 256;
            float4 v = *(const float4*)(src + (size_t)it * 4096 + (size_t)idx4 * 4);
            ushort4v pk;
            pk.x = f2bf(v.x); pk.y = f2bf(v.y); pk.z = f2bf(v.z); pk.w = f2bf(v.w);
            int row = idx4 >> 5, c4 = (idx4 & 31) * 4;
            *(ushort4v*)(&sxb[row][c4]) = pk;
        }
        if (it == 0) {
            int rr = t >> 3, k = t & 7;
            const float* rowp = src + rr * 128;
            float cs0 = 0.f, cq0 = 0.f, cs1 = 0.f, cq1 = 0.f;
#pragma unroll
            for (int g = 0; g < 4; ++g) {
                float a = rowp[g * 8 + k];       cs0 += a;  cq0 += a * a;
                float b = rowp[32 + g * 8 + k];  cs1 += b;  cq1 += b * b;
            }
            s_cs[0][rr][k] = cs0; s_cs[1][rr][k] = cs1;
            s_cq[0][rr][k] = cq0; s_cq[1][rr][k] = cq1;
        }
        __syncthreads();
        f32x4 D = {0.f, 0.f, 0.f, 0.f};
#pragma unroll
        for (int k = 0; k < 4; ++k) {
            bf16x8 a = *(const bf16x8*)(abase + k * 32);
            D = __builtin_amdgcn_mfma_f32_16x16x32_bf16(a, bfrag[k], D, 0, 0, 0);
        }
        int row = it * 32 + mi * 16 + ((lane >> 4) << 2);
        int col = ni * 16 + (lane & 15);
        float* sTf = (float*)&sT[0][0];
#pragma unroll
        for (int r = 0; r < 4; ++r) sTf[(size_t)(row + r) * 34 + col] = D[r];
    }
    __syncthreads();
    int ky = t & 15;
    int mlo = t >> 4;
    int kxa = mlo, kxb = 112 + mlo;
    float2 sva = st[kxa]; float sca = sva.x, ssa = -sva.y;
    float2 svb = st[kxb]; float scb = svb.x, ssb = -svb.y;
    float rea = 0.f, ima = 0.f, reb = 0.f, imb = 0.f;
    for (int h0 = 0; h0 < 128; h0 += 16) {
        float2 bva = st[(kxa * h0) & 127]; float cca = bva.x, csa = -bva.y;
        float2 bvb = st[(kxb * h0) & 127]; float ccb = bvb.x, csb = -bvb.y;
#pragma unroll
        for (int j = 0; j < 16; ++j) {
            float2 Tv = sT[h0 + j][ky];
            rea += Tv.x * cca - Tv.y * csa;
            ima += Tv.x * csa + Tv.y * cca;
            reb += Tv.x * ccb - Tv.y * csb;
            imb += Tv.x * csb + Tv.y * ccb;
            float na = cca * sca - csa * ssa; csa = cca * ssa + csa * sca; cca = na;
            float nb = ccb * scb - csb * ssb; csb = ccb * ssb + csb * scb; ccb = nb;
        }
    }
    float2* xp = xft + (size_t)bc * 512;
    xp[mlo * 16 + ky] = make_float2(rea, ima);
    xp[(mlo + 16) * 16 + ky] = make_float2(reb, imb);
    if (t < 16) {
        int half = t >> 3, k = t & 7;
        float s = 0.f, q = 0.f;
        for (int rr = 0; rr < 32; ++rr) {
            s += s_cs[half][rr][k];
#pragma unroll
            for (int kk = 0; kk < 8; ++kk) q += s_cq[half][rr][kk];
        }
        float norm = fmaxf(sqrtf(q), 1e-12f);
        cr[bc * 16 + t] = s / (128.0f * norm);
    }
}

// ---------------- spectral mix (blocks 0..511) + MLP stage 1 (blocks 512..767) ----------------
__global__ void __launch_bounds__(512) k_mixmlp(const float2* __restrict__ xft,
                                                const float* __restrict__ w1r,
                                                const float* __restrict__ w1i,
                                                const float* __restrict__ w2r,
                                                const float* __restrict__ w2i,
                                                const float* __restrict__ cr,
                                                const float* __restrict__ g1w,
                                                const float* __restrict__ g1b,
                                                float* __restrict__ hmid,
                                                float2* __restrict__ F) {
    __shared__ __align__(16) char smem[36864];
    int t = threadIdx.x;
    int bid = blockIdx.x;
    if (bid < 512) {
        float2* s_w = (float2*)smem;               // [64][64] (i,o)
        float2* s_x = (float2*)(smem + 32768);     // [8][64]  (b,i)
        int m = (bid & 7) + 8 * ((bid >> 3) & 3);  // XCD swizzle
        int e = bid >> 5;                          // ky
        const float* wr; const float* wi; int mm;
        if (m < 16) { wr = w1r; wi = w1i; mm = m; } else { wr = w2r; wi = w2i; mm = m - 16; }
        int off = mm * 16 + e;
        for (int u = t; u < 4096; u += 512) {
            s_w[u] = make_float2(wr[(u << 8) + off], wi[(u << 8) + off]);
        }
        {
            int bb = t >> 6, i = t & 63;
            s_x[bb * 64 + i] = xft[((size_t)(bb * 64 + i) * 32 + m) * 16 + e];
        }
        __syncthreads();
        int bb = t >> 6, o = t & 63;
        float re = 0.f, im = 0.f;
#pragma unroll 8
        for (int i = 0; i < 64; ++i) {
            float2 xv = s_x[bb * 64 + i];
            float2 wv = s_w[i * 64 + o];
            re += xv.x * wv.x - xv.y * wv.y;
            im += xv.x * wv.y + xv.y * wv.x;
        }
        F[((size_t)(bb * 16 + e) * 32 + m) * 64 + o] = make_float2(re, im);
    } else {
        float* s_cr   = (float*)smem;              // [8][1024]
        float* s_wave = (float*)(smem + 32768);    // [8][8]
        int j = bid - 512;
        for (int u = t; u < 8192; u += 512) s_cr[u] = cr[u];
        const float* wrow = g1w + (size_t)j * 2048;
        float w0 = wrow[4 * t], w1 = wrow[4 * t + 2];
        __syncthreads();
        float acc[8];
#pragma unroll
        for (int b = 0; b < 8; ++b) {
            float2 v = *(const float2*)(s_cr + b * 1024 + 2 * t);
            acc[b] = v.x * w0 + v.y * w1;
        }
#pragma unroll
        for (int d = 32; d > 0; d >>= 1) {
#pragma unroll
            for (int b = 0; b < 8; ++b) acc[b] += __shfl_down(acc[b], d, 64);
        }
        int wv = t >> 6;
        if ((t & 63) == 0) {
#pragma unroll
            for (int b = 0; b < 8; ++b) s_wave[wv * 8 + b] = acc[b];
        }
        __syncthreads();
        if (t < 8) {
            float a = g1b[j];
            for (int q = 0; q < 8; ++q) a += s_wave[q * 8 + t];
            hmid[t * 256 + j] = gelu_f(a);
        }
    }
}

// ---------------- inverse B (fused inva + mlp2) + 1x1 conv + corr + bias (+GELU) ----------------
// G-phase twiddles via uniform table lookups (no serial rotation chain).
__global__ void __launch_bounds__(256, 4) k_invb(const float2* __restrict__ F,
                                                 const float* __restrict__ hin,
                                                 const float* __restrict__ cwTl,
                                                 const float* __restrict__ cbl,
                                                 const float* __restrict__ hmid,
                                                 const float* __restrict__ g2w,
                                                 const float* __restrict__ g2b,
                                                 const float2* __restrict__ trig,
                                                 float* __restrict__ hout,
                                                 int do_gelu) {
    int blk = blockIdx.x;
    int b = blk >> 7, h = blk & 127;
    __shared__ __align__(16) float s_cwT[64][64];   // [c][o]
    __shared__ __align__(16) float2 s_g[16][64];    // [ky][o]
    __shared__ float2 s_t[128];
    __shared__ float s_co[64];
    __shared__ float s_part[4][64];
    int t = threadIdx.x;
    if (t < 128) s_t[t] = trig[t];
    {
        float* cw0 = &s_cwT[0][0];
        for (int u = t; u < 4096; u += 256) cw0[u] = cwTl[u];
    }
    // ---- mlp2 partials (corr) ----
    {
        int o = t & 63, q = t >> 6;
        const float* hv = hmid + b * 256 + q * 64;
        const float* gw = g2w + o * 256 + q * 64;
        float a = 0.f;
#pragma unroll 8
        for (int v = 0; v < 64; ++v) a += hv[v] * gw[v];
        s_part[q][o] = a;
    }
    // ---- G-phase (fused inva), table twiddles: all m independent ----
    {
        int o = t & 63, ky0 = t >> 6;
        const float2* Fb = F + (size_t)b * 32768 + o;
        float a0r=0.f,a0i=0.f,a1r=0.f,a1i=0.f,a2r=0.f,a2i=0.f,a3r=0.f,a3i=0.f;
#pragma unroll 4
        for (int m = 0; m < 32; ++m) {
            int kx = (m < 16) ? m : (96 + m);
            float2 wz = trig[(kx * h) & 127];      // block-uniform (scalar load)
            const float2* fm = Fb + m * 64;
            float2 f0 = fm[(ky0     ) * 2048];
            float2 f1 = fm[(ky0 +  4) * 2048];
            float2 f2 = fm[(ky0 +  8) * 2048];
            float2 f3 = fm[(ky0 + 12) * 2048];
            a0r += f0.x*wz.x - f0.y*wz.y; a0i += f0.x*wz.y + f0.y*wz.x;
            a1r += f1.x*wz.x - f1.y*wz.y; a1i += f1.x*wz.y + f1.y*wz.x;
            a2r += f2.x*wz.x - f2.y*wz.y; a2i += f2.x*wz.y + f2.y*wz.x;
            a3r += f3.x*wz.x - f3.y*wz.y; a3i += f3.x*wz.y + f3.y*wz.x;
        }
        s_g[ky0     ][o] = make_float2(a0r, a0i);
        s_g[ky0 +  4][o] = make_float2(a1r, a1i);
        s_g[ky0 +  8][o] = make_float2(a2r, a2i);
        s_g[ky0 + 12][o] = make_float2(a3r, a3i);
    }
    __syncthreads();
    if (t < 64)
        s_co[t] = s_part[0][t] + s_part[1][t] + s_part[2][t] + s_part[3][t]
                + g2b[t] + cbl[t];
    int ot2 = t >> 6;
    int wt6 = t & 63;
    int o0 = ot2 * 16;
    float acc[16][2];
#pragma unroll
    for (int i = 0; i < 16; ++i) { acc[i][0] = 0.f; acc[i][1] = 0.f; }
    float2 rw0 = s_t[wt6];
    float2 rw1 = s_t[wt6 + 64];
    float z0r = 1.f, z0i = 0.f, z1r = 1.f, z1i = 0.f;
    const float invn = 1.0f / 16384.0f;
    for (int ky = 0; ky < 16; ++ky) {
        float fs = (ky == 0) ? invn : (2.f * invn);   // invn folded into twiddle
        float tc0 = fs * z0r, ts0 = fs * z0i;
        float tc1 = fs * z1r, ts1 = fs * z1i;
        const float4* gk = (const float4*)(&s_g[ky][o0]);
#pragma unroll
        for (int i2 = 0; i2 < 8; ++i2) {
            float4 g2 = gk[i2];
            acc[2*i2][0]   += g2.x * tc0 - g2.y * ts0;
            acc[2*i2][1]   += g2.x * tc1 - g2.y * ts1;
            acc[2*i2+1][0] += g2.z * tc0 - g2.w * ts0;
            acc[2*i2+1][1] += g2.z * tc1 - g2.w * ts1;
        }
        float nz0 = z0r * rw0.x - z0i * rw0.y; z0i = z0r * rw0.y + z0i * rw0.x; z0r = nz0;
        float nz1 = z1r * rw1.x - z1i * rw1.y; z1i = z1r * rw1.y + z1i * rw1.x; z1r = nz1;
    }
    // ---- conv: direct global reads ----
    const float* hp = hin + ((size_t)(b * 64) * 128 + h) * 128;
    for (int cc = 0; cc < 64; cc += 4) {
        float hv0[4], hv1[4];
#pragma unroll
        for (int c = 0; c < 4; ++c) {
            hv0[c] = hp[(size_t)(cc + c) * 16384 + wt6];
            hv1[c] = hp[(size_t)(cc + c) * 16384 + wt6 + 64];
        }
#pragma unroll
        for (int c = 0; c < 4; ++c) {
            const float4* cwp = (const float4*)(&s_cwT[cc + c][o0]);
#pragma unroll
            for (int i4 = 0; i4 < 4; ++i4) {
                float4 cv = cwp[i4];
                acc[4*i4][0]   += cv.x * hv0[c]; acc[4*i4][1]   += cv.x * hv1[c];
                acc[4*i4+1][0] += cv.y * hv0[c]; acc[4*i4+1][1] += cv.y * hv1[c];
                acc[4*i4+2][0] += cv.z * hv0[c]; acc[4*i4+2][1] += cv.z * hv1[c];
                acc[4*i4+3][0] += cv.w * hv0[c]; acc[4*i4+3][1] += cv.w * hv1[c];
            }
        }
    }
    __syncthreads();
#pragma unroll
    for (int i = 0; i < 16; ++i) {
        int o = o0 + i;
        float co = s_co[o];
        float* outp = hout + ((size_t)(b * 64 + o) * 128 + h) * 128;
        float v0 = acc[i][0] + co;
        float v1 = acc[i][1] + co;
        if (do_gelu) { v0 = gelu_f(v0); v1 = gelu_f(v1); }
        outp[wt6] = v0;
        outp[wt6 + 64] = v1;
    }
}

// ---------------- FINAL layer: inverse B (fused inva + mlp2) + conv + head ----------------
// (256,2): >=128 VGPR needed (acc[16][2] + a32[32][2]) — (256,3) spilled (R7).
__global__ void __launch_bounds__(256, 2) k_invbh(const float2* __restrict__ F,
                                                  const float* __restrict__ hin,
                                                  const float* __restrict__ cwTl,
                                                  const float* __restrict__ cbl,
                                                  const float* __restrict__ hmid,
                                                  const float* __restrict__ g2w,
                                                  const float* __restrict__ g2b,
                                                  const float2* __restrict__ trig,
                                                  const float* __restrict__ fc1wT,
                                                  const float* __restrict__ fc1b,
                                                  const float* __restrict__ fc2w,
                                                  const float* __restrict__ fc2b,
                                                  float* __restrict__ out) {
    int blk = blockIdx.x;                 // 0..951
    int b = blk / 119;
    int h = blk - b * 119;
    __shared__ __align__(16) char smem[32768];
    float*  s_cwT = (float*)smem;                 // [64][64]  (phase A)
    float2* s_g   = (float2*)(smem + 16384);      // [16][64]  (phase A)
    float*  s_hall= (float*)smem;                 // [64][128] (head overlay)
    __shared__ __align__(16) float s_w8[16][128]; // head weight chunk
    __shared__ float2 s_t[128];
    __shared__ float s_co[64];
    __shared__ float s_b1[128];
    __shared__ float s_w2[128];
    __shared__ float s_red[4][132];
    __shared__ float s_part[4][64];
    int t = threadIdx.x;
    if (t < 128) s_t[t] = trig[t];
    else { s_b1[t - 128] = fc1b[t - 128]; s_w2[t - 128] = fc2w[t - 128]; }
    for (int u = t; u < 4096; u += 256) s_cwT[u] = cwTl[u];
    // ---- mlp2 partials (corr) ----
    {
        int o = t & 63, q = t >> 6;
        const float* hv = hmid + b * 256 + q * 64;
        const float* gw = g2w + o * 256 + q * 64;
        float a = 0.f;
#pragma unroll 8
        for (int v = 0; v < 64; ++v) a += hv[v] * gw[v];
        s_part[q][o] = a;
    }
    // ---- G-phase (fused inva), table twiddles ----
    {
        int o = t & 63, ky0 = t >> 6;
        const float2* Fb = F + (size_t)b * 32768 + o;
        float a0r=0.f,a0i=0.f,a1r=0.f,a1i=0.f,a2r=0.f,a2i=0.f,a3r=0.f,a3i=0.f;
#pragma unroll 4
        for (int m = 0; m < 32; ++m) {
            int kx = (m < 16) ? m : (96 + m);
            float2 wz = trig[(kx * h) & 127];
            const float2* fm = Fb + m * 64;
            float2 f0 = fm[(ky0     ) * 2048];
            float2 f1 = fm[(ky0 +  4) * 2048];
            float2 f2 = fm[(ky0 +  8) * 2048];
            float2 f3 = fm[(ky0 + 12) * 2048];
            a0r += f0.x*wz.x - f0.y*wz.y; a0i += f0.x*wz.y + f0.y*wz.x;
            a1r += f1.x*wz.x - f1.y*wz.y; a1i += f1.x*wz.y + f1.y*wz.x;
            a2r += f2.x*wz.x - f2.y*wz.y; a2i += f2.x*wz.y + f2.y*wz.x;
            a3r += f3.x*wz.x - f3.y*wz.y; a3i += f3.x*wz.y + f3.y*wz.x;
        }
        float2* sg = (float2*)(smem + 16384);
        sg[(ky0     ) * 64 + o] = make_float2(a0r, a0i);
        sg[(ky0 +  4) * 64 + o] = make_float2(a1r, a1i);
        sg[(ky0 +  8) * 64 + o] = make_float2(a2r, a2i);
        sg[(ky0 + 12) * 64 + o] = make_float2(a3r, a3i);
    }
    __syncthreads();
    if (t < 64)
        s_co[t] = s_part[0][t] + s_part[1][t] + s_part[2][t] + s_part[3][t]
                + g2b[t] + cbl[t];
    int ot2 = t >> 6;
    int wt6 = t & 63;
    int o0 = ot2 * 16;
    float acc[16][2];
#pragma unroll
    for (int i = 0; i < 16; ++i) { acc[i][0] = 0.f; acc[i][1] = 0.f; }
    float2 rw0 = s_t[wt6];
    float2 rw1 = s_t[wt6 + 64];
    float z0r = 1.f, z0i = 0.f, z1r = 1.f, z1i = 0.f;
    const float invn = 1.0f / 16384.0f;
    for (int ky = 0; ky < 16; ++ky) {
        float fs = (ky == 0) ? invn : (2.f * invn);
        float tc0 = fs * z0r, ts0 = fs * z0i;
        float tc1 = fs * z1r, ts1 = fs * z1i;
        const float4* gk = (const float4*)(s_g + ky * 64 + o0);
#pragma unroll
        for (int i2 = 0; i2 < 8; ++i2) {
            float4 g2 = gk[i2];
            acc[2*i2][0]   += g2.x * tc0 - g2.y * ts0;
            acc[2*i2][1]   += g2.x * tc1 - g2.y * ts1;
            acc[2*i2+1][0] += g2.z * tc0 - g2.w * ts0;
            acc[2*i2+1][1] += g2.z * tc1 - g2.w * ts1;
        }
        float nz0 = z0r * rw0.x - z0i * rw0.y; z0i = z0r * rw0.y + z0i * rw0.x; z0r = nz0;
        float nz1 = z1r * rw1.x - z1i * rw1.y; z1i = z1r * rw1.y + z1i * rw1.x; z1r = nz1;
    }
    // ---- conv: direct global reads ----
    const float* hp = hin + ((size_t)(b * 64) * 128 + h) * 128;
    for (int cc = 0; cc < 64; cc += 8) {
        float hv0[8], hv1[8];
#pragma unroll
        for (int c = 0; c < 8; ++c) {
            hv0[c] = hp[(size_t)(cc + c) * 16384 + wt6];
            hv1[c] = hp[(size_t)(cc + c) * 16384 + wt6 + 64];
        }
#pragma unroll
        for (int c = 0; c < 8; ++c) {
            const float4* cwp = (const float4*)(s_cwT + (cc + c) * 64 + o0);
#pragma unroll
            for (int i4 = 0; i4 < 4; ++i4) {
                float4 cv = cwp[i4];
                acc[4*i4][0]   += cv.x * hv0[c]; acc[4*i4][1]   += cv.x * hv1[c];
                acc[4*i4+1][0] += cv.y * hv0[c]; acc[4*i4+1][1] += cv.y * hv1[c];
                acc[4*i4+2][0] += cv.z * hv0[c]; acc[4*i4+2][1] += cv.z * hv1[c];
                acc[4*i4+3][0] += cv.w * hv0[c]; acc[4*i4+3][1] += cv.w * hv1[c];
            }
        }
    }
    // ---- features into LDS overlay (no GELU final layer) ----
    __syncthreads();
#pragma unroll
    for (int i = 0; i < 16; ++i) {
        float co = s_co[o0 + i];
        s_hall[(o0 + i) * 128 + wt6]      = acc[i][0] + co;
        s_hall[(o0 + i) * 128 + wt6 + 64] = acc[i][1] + co;
    }
    // ---- head: fc1 (wave-uniform j-tile 32) + GELU + fc2 ----
    int j0 = ot2 * 32;
    float a32[32][2];
#pragma unroll
    for (int i = 0; i < 32; ++i) { a32[i][0] = 0.f; a32[i][1] = 0.f; }
    for (int cc = 0; cc < 64; cc += 16) {
        __syncthreads();
        for (int u = t; u < 2048; u += 256)
            s_w8[u >> 7][u & 127] = fc1wT[(cc + (u >> 7)) * 128 + (u & 127)];
        __syncthreads();
        for (int c = 0; c < 16; ++c) {
            float hv0 = s_hall[(cc + c) * 128 + wt6];
            float hv1 = s_hall[(cc + c) * 128 + wt6 + 64];
            const float4* wp = (const float4*)(&s_w8[c][j0]);
#pragma unroll
            for (int q = 0; q < 8; ++q) {
                float4 wx = wp[q];
                a32[4*q][0]   += wx.x * hv0; a32[4*q][1]   += wx.x * hv1;
                a32[4*q+1][0] += wx.y * hv0; a32[4*q+1][1] += wx.y * hv1;
                a32[4*q+2][0] += wx.z * hv0; a32[4*q+2][1] += wx.z * hv1;
                a32[4*q+3][0] += wx.w * hv0; a32[4*q+3][1] += wx.w * hv1;
            }
        }
    }
    float sum0 = 0.f, sum1 = 0.f;
#pragma unroll
    for (int i = 0; i < 32; ++i) {
        float b1 = s_b1[j0 + i];
        float w2 = s_w2[j0 + i];
        sum0 += gelu_f(a32[i][0] + b1) * w2;
        sum1 += gelu_f(a32[i][1] + b1) * w2;
    }
    s_red[ot2][wt6] = sum0;
    s_red[ot2][wt6 + 64] = sum1;
    __syncthreads();
    if (t < NS) {
        out[b * (NS * NS) + h * NS + t] =
            fc2b[0] + s_red[0][t] + s_red[1][t] + s_red[2][t] + s_red[3][t];
    }
}

extern "C" void kernel_launch(void* const* d_in, const int* in_sizes, int n_in,
                              void* d_out, int out_size, void* d_ws, size_t ws_size,
                              hipStream_t stream) {
    const float* x    = (const float*)d_in[0];
    const float* sw1r = (const float*)d_in[1];
    const float* sw1i = (const float*)d_in[2];
    const float* sw2r = (const float*)d_in[3];
    const float* sw2i = (const float*)d_in[4];
    const float* g1w  = (const float*)d_in[5];
    const float* g1b  = (const float*)d_in[6];
    const float* g2w  = (const float*)d_in[7];
    const float* g2b  = (const float*)d_in[8];
    const float* cw   = (const float*)d_in[9];
    const float* cb   = (const float*)d_in[10];
    const float* fc0w = (const float*)d_in[11];
    const float* fc0b = (const float*)d_in[12];
    const float* fc1w = (const float*)d_in[13];
    const float* fc1b = (const float*)d_in[14];
    const float* fc2w = (const float*)d_in[15];
    const float* fc2b = (const float*)d_in[16];
    float* out = (float*)d_out;

    char* ws = (char*)d_ws;
    const size_t SZ_H   = (size_t)NB * NC * NH * NW * 4;      // 33554432
    const size_t SZ_XFT = (size_t)NB * NC * 32 * 16 * 8;      // 2097152
    const size_t SZ_F   = SZ_XFT;                             // 2097152
    size_t off = 0;
    float2* trig = (float2*)(ws + off); off += 1024;
    short*  wmf  = (short*)(ws + off);  off += 4096 * 2;
    float*  f1T  = (float*)(ws + off);  off += 8192 * 4;
    float*  cwT  = (float*)(ws + off);  off += 16384 * 4;
    off = (off + 255) & ~(size_t)255;
    float*  hA   = (float*)(ws + off);  off += SZ_H;
    float*  hB   = (float*)(ws + off);  off += SZ_H;
    float2* xft  = (float2*)(ws + off); off += SZ_XFT;
    float2* F    = (float2*)(ws + off); off += SZ_F;
    float*  cr   = (float*)(ws + off);  off += (size_t)NB * NC * 16 * 4;
    float*  hmid = (float*)(ws + off);  off += (size_t)NB * 256 * 4;
    (void)ws_size; (void)in_sizes; (void)n_in; (void)out_size;

    k_trig<<<1, 128, 0, stream>>>(trig);
    k_tabm<<<16, 256, 0, stream>>>(wmf);
    k_tc<<<96, 256, 0, stream>>>(fc1w, cw, f1T, cwT);
    k_fc0<<<512, 256, 0, stream>>>(x, fc0w, fc0b, hA);

    float* hcur = hA;
    float* hnxt = hB;
    for (int l = 0; l < 4; ++l) {
        const float* w1r = sw1r + (size_t)l * 1048576;
        const float* w1i = sw1i + (size_t)l * 1048576;
        const float* w2r = sw2r + (size_t)l * 1048576;
        const float* w2i = sw2i + (size_t)l * 1048576;
        const float* g1w_l = g1w + (size_t)l * 524288;
        const float* g1b_l = g1b + l * 256;
        const float* g2w_l = g2w + (size_t)l * 16384;
        const float* g2b_l = g2b + l * 64;
        const float* cwT_l = cwT + (size_t)l * 4096;
        const float* cb_l  = cb + l * 64;

        k_dft2<<<512, 256, 0, stream>>>(hcur, xft, cr, wmf, trig);
        k_mixmlp<<<768, 512, 0, stream>>>(xft, w1r, w1i, w2r, w2i,
                                          cr, g1w_l, g1b_l, hmid, F);
        if (l < 3) {
            k_invb<<<1024, 256, 0, stream>>>(F, hcur, cwT_l, cb_l, hmid,
                                             g2w_l, g2b_l, trig, hnxt, 1);
            float* tmp = hcur; hcur = hnxt; hnxt = tmp;
        } else {
            k_invbh<<<NB * NS, 256, 0, stream>>>(F, hcur, cwT_l, cb_l, hmid,
                                                 g2w_l, g2b_l, trig,
                                                 f1T, fc1b, fc2w, fc2b, out);
        }
    }
}

// Round 14
// 436.745 us; speedup vs baseline: 1.3675x; 1.0382x over previous
//
#include <hip/hip_runtime.h>
#include <math.h>

#define NB 8
#define NC 64
#define NH 128
#define NW 128
#define NS 119
#define NPIX 113288   // 8*119*119

typedef __attribute__((ext_vector_type(8))) short bf16x8;
typedef __attribute__((ext_vector_type(4))) float f32x4;
typedef __attribute__((ext_vector_type(4))) unsigned short ushort4v;

__device__ __forceinline__ float gelu_f(float v) {
    return 0.5f * v * (1.0f + erff(v * 0.70710678118654752f));
}

__device__ __forceinline__ unsigned short f2bf(float x) {
    unsigned int u = __builtin_bit_cast(unsigned int, x);
    u += 0x7FFFu + ((u >> 16) & 1u);
    return (unsigned short)(u >> 16);
}
__device__ __forceinline__ float bf2f(unsigned short s) {
    unsigned int u = (unsigned int)s << 16;
    return __builtin_bit_cast(float, u);
}

// ---------------- trig table: trig[t] = (cos, sin)(2*pi*t/128) ----------------
__global__ void __launch_bounds__(128) k_trig(float2* __restrict__ trig) {
    int t = threadIdx.x;
    double a = (double)t * (3.14159265358979323846 / 64.0);
    trig[t] = make_float2((float)cos(a), (float)sin(a));
}

// ---------------- W-DFT matrix in MFMA B-fragment order (bf16) ----------------
__global__ void __launch_bounds__(256) k_tabm(short* __restrict__ wmf) {
    int idx = blockIdx.x * 256 + threadIdx.x;   // 0..4095
    int f = idx >> 9;
    int l = (idx >> 3) & 63;
    int e = idx & 7;
    int ni = f >> 2, k = f & 3;
    int w = k * 32 + (l >> 4) * 8 + e;
    int n = ni * 16 + (l & 15);
    int q = n >> 1;
    int prod = (q * w) & 127;
    double a = (double)prod * (3.14159265358979323846 / 64.0);
    float v = (float)((n & 1) ? -sin(a) : cos(a));
    wmf[idx] = (short)f2bf(v);
}

// ---------------- iDFT-W twiddle B-table, frag order, hi+lo ----------------
// B[k][w]: k=2q -> fs_q cos(2pi q w/128), k=2q+1 -> -fs_q sin(...); fs folded
__global__ void __launch_bounds__(256) k_tabi(short* __restrict__ bt) {
    int idx = blockIdx.x * 256 + threadIdx.x;   // 0..4095
    int wt = idx >> 9, l = (idx >> 3) & 63, e = idx & 7;
    int k = (l >> 4) * 8 + e;
    int w = wt * 16 + (l & 15);
    int q = k >> 1;
    double a = (double)((q * w) & 127) * (3.14159265358979323846 / 64.0);
    double fs = (q == 0) ? (1.0 / 16384.0) : (2.0 / 16384.0);
    float val = (float)((k & 1) ? (-fs * sin(a)) : (fs * cos(a)));
    unsigned short hi = f2bf(val);
    unsigned short lo = f2bf(val - bf2f(hi));
    bt[idx] = (short)hi;
    bt[4096 + idx] = (short)lo;
}

// ---------------- transposes: fc1wT[c][j] = fc1w[j][c]; cwT[l][c][o] = cw[l][o][c] ----------------
__global__ void __launch_bounds__(256) k_tc(const float* __restrict__ fc1w,
                                            const float* __restrict__ cw,
                                            float* __restrict__ fc1wT,
                                            float* __restrict__ cwT) {
    int u = blockIdx.x * 256 + threadIdx.x;   // 0..24575
    if (u < 8192) {
        int c = u >> 7, j = u & 127;
        fc1wT[u] = fc1w[j * 64 + c];
    } else {
        int v = u - 8192;                      // 0..16383
        int l = v >> 12, idx = v & 4095;
        int c = idx >> 6, o = idx & 63;
        cwT[v] = cw[l * 4096 + o * 64 + c];
    }
}

// ---------------- fc0 + grid concat + transpose + zero pad ----------------
__global__ void __launch_bounds__(256) k_fc0(const float* __restrict__ x,
                                             const float* __restrict__ w,
                                             const float* __restrict__ bia,
                                             float* __restrict__ h) {
    __shared__ float sw[320];
    __shared__ float sb[64];
    int t = threadIdx.x;
    for (int u = t; u < 320; u += 256) sw[u] = w[u];
    if (t < 64) sb[t] = bia[t];
    __syncthreads();
    int p = blockIdx.x * 256 + t;            // 0 .. 131071
    int b = p >> 14;
    int rem = p & 16383;
    int r = rem >> 7, wc = rem & 127;
    float v0 = 0.f, v1 = 0.f, v2 = 0.f, gx = 0.f, gy = 0.f;
    bool inside = (r < NS) && (wc < NS);
    if (inside) {
        const float* xp = x + ((size_t)(b * NS + r) * NS + wc) * 3;
        v0 = xp[0]; v1 = xp[1]; v2 = xp[2];
        gx = (float)r * (1.0f / 118.0f);
        gy = (float)wc * (1.0f / 118.0f);
    }
    float* hp = h + (size_t)b * NC * NH * NW + rem;
    for (int c = 0; c < 64; ++c) {
        float val = 0.f;
        if (inside) {
            const float* wr = sw + c * 5;
            val = v0 * wr[0] + v1 * wr[1] + v2 * wr[2] + gx * wr[3] + gy * wr[4] + sb[c];
        }
        hp[c * (NH * NW)] = val;
    }
}

// ---------------- fused 2D partial DFT (MFMA phase-1) + CFT ----------------
__global__ void __launch_bounds__(256) k_dft2(const float* __restrict__ h,
                                              float2* __restrict__ xft,
                                              float* __restrict__ cr,
                                              const short* __restrict__ wmf,
                                              const float2* __restrict__ trig) {
    __shared__ __align__(16) short sxb[32][136];
    __shared__ float2 sT[128][17];
    __shared__ float2 st[128];
    __shared__ float s_cs[2][32][8];
    __shared__ float s_cq[2][32][8];
    int t = threadIdx.x;
    int bc = blockIdx.x;
    if (t < 128) st[t] = trig[t];
    int lane = t & 63, wv = t >> 6;
    int mi = wv >> 1, ni = wv & 1;
    bf16x8 bfrag[4];
    {
        const short* wp = wmf + ((size_t)(ni * 4) * 64 + lane) * 8;
#pragma unroll
        for (int k = 0; k < 4; ++k) bfrag[k] = *(const bf16x8*)(wp + k * 512);
    }
    const float* src = h + (size_t)bc * 16384;
    const short* abase = &sxb[mi * 16 + (lane & 15)][(lane >> 4) * 8];
    for (int it = 0; it < 4; ++it) {
        __syncthreads();
#pragma unroll
        for (int j = 0; j < 4; ++j) {
            int idx4 = t + j * 256;
            float4 v = *(const float4*)(src + (size_t)it * 4096 + (size_t)idx4 * 4);
            ushort4v pk;
            pk.x = f2bf(v.x); pk.y = f2bf(v.y); pk.z = f2bf(v.z); pk.w = f2bf(v.w);
            int row = idx4 >> 5, c4 = (idx4 & 31) * 4;
            *(ushort4v*)(&sxb[row][c4]) = pk;
        }
        if (it == 0) {
            int rr = t >> 3, k = t & 7;
            const float* rowp = src + rr * 128;
            float cs0 = 0.f, cq0 = 0.f, cs1 = 0.f, cq1 = 0.f;
#pragma unroll
            for (int g = 0; g < 4; ++g) {
                float a = rowp[g * 8 + k];       cs0 += a;  cq0 += a * a;
                float b = rowp[32 + g * 8 + k];  cs1 += b;  cq1 += b * b;
            }
            s_cs[0][rr][k] = cs0; s_cs[1][rr][k] = cs1;
            s_cq[0][rr][k] = cq0; s_cq[1][rr][k] = cq1;
        }
        __syncthreads();
        f32x4 D = {0.f, 0.f, 0.f, 0.f};
#pragma unroll
        for (int k = 0; k < 4; ++k) {
            bf16x8 a = *(const bf16x8*)(abase + k * 32);
            D = __builtin_amdgcn_mfma_f32_16x16x32_bf16(a, bfrag[k], D, 0, 0, 0);
        }
        int row = it * 32 + mi * 16 + ((lane >> 4) << 2);
        int col = ni * 16 + (lane & 15);
        float* sTf = (float*)&sT[0][0];
#pragma unroll
        for (int r = 0; r < 4; ++r) sTf[(size_t)(row + r) * 34 + col] = D[r];
    }
    __syncthreads();
    int ky = t & 15;
    int mlo = t >> 4;
    int kxa = mlo, kxb = 112 + mlo;
    float2 sva = st[kxa]; float sca = sva.x, ssa = -sva.y;
    float2 svb = st[kxb]; float scb = svb.x, ssb = -svb.y;
    float rea = 0.f, ima = 0.f, reb = 0.f, imb = 0.f;
    for (int h0 = 0; h0 < 128; h0 += 16) {
        float2 bva = st[(kxa * h0) & 127]; float cca = bva.x, csa = -bva.y;
        float2 bvb = st[(kxb * h0) & 127]; float ccb = bvb.x, csb = -bvb.y;
#pragma unroll
        for (int j = 0; j < 16; ++j) {
            float2 Tv = sT[h0 + j][ky];
            rea += Tv.x * cca - Tv.y * csa;
            ima += Tv.x * csa + Tv.y * cca;
            reb += Tv.x * ccb - Tv.y * csb;
            imb += Tv.x * csb + Tv.y * ccb;
            float na = cca * sca - csa * ssa; csa = cca * ssa + csa * sca; cca = na;
            float nb = ccb * scb - csb * ssb; csb = ccb * ssb + csb * scb; ccb = nb;
        }
    }
    float2* xp = xft + (size_t)bc * 512;
    xp[mlo * 16 + ky] = make_float2(rea, ima);
    xp[(mlo + 16) * 16 + ky] = make_float2(reb, imb);
    if (t < 16) {
        int half = t >> 3, k = t & 7;
        float s = 0.f, q = 0.f;
        for (int rr = 0; rr < 32; ++rr) {
            s += s_cs[half][rr][k];
#pragma unroll
            for (int kk = 0; kk < 8; ++kk) q += s_cq[half][rr][kk];
        }
        float norm = fmaxf(sqrtf(q), 1e-12f);
        cr[bc * 16 + t] = s / (128.0f * norm);
    }
}

// ---------------- spectral mix (blocks 0..511) + MLP stage 1 (blocks 512..767) ----------------
__global__ void __launch_bounds__(512) k_mixmlp(const float2* __restrict__ xft,
                                                const float* __restrict__ w1r,
                                                const float* __restrict__ w1i,
                                                const float* __restrict__ w2r,
                                                const float* __restrict__ w2i,
                                                const float* __restrict__ cr,
                                                const float* __restrict__ g1w,
                                                const float* __restrict__ g1b,
                                                float* __restrict__ hmid,
                                                float2* __restrict__ F) {
    __shared__ __align__(16) char smem[36864];
    int t = threadIdx.x;
    int bid = blockIdx.x;
    if (bid < 512) {
        float2* s_w = (float2*)smem;               // [64][64] (i,o)
        float2* s_x = (float2*)(smem + 32768);     // [8][64]  (b,i)
        int m = (bid & 7) + 8 * ((bid >> 3) & 3);  // XCD swizzle
        int e = bid >> 5;                          // ky
        const float* wr; const float* wi; int mm;
        if (m < 16) { wr = w1r; wi = w1i; mm = m; } else { wr = w2r; wi = w2i; mm = m - 16; }
        int off = mm * 16 + e;
        for (int u = t; u < 4096; u += 512) {
            s_w[u] = make_float2(wr[(u << 8) + off], wi[(u << 8) + off]);
        }
        {
            int bb = t >> 6, i = t & 63;
            s_x[bb * 64 + i] = xft[((size_t)(bb * 64 + i) * 32 + m) * 16 + e];
        }
        __syncthreads();
        int bb = t >> 6, o = t & 63;
        float re = 0.f, im = 0.f;
#pragma unroll 8
        for (int i = 0; i < 64; ++i) {
            float2 xv = s_x[bb * 64 + i];
            float2 wv = s_w[i * 64 + o];
            re += xv.x * wv.x - xv.y * wv.y;
            im += xv.x * wv.y + xv.y * wv.x;
        }
        F[((size_t)(bb * 16 + e) * 32 + m) * 64 + o] = make_float2(re, im);
    } else {
        float* s_cr   = (float*)smem;              // [8][1024]
        float* s_wave = (float*)(smem + 32768);    // [8][8]
        int j = bid - 512;
        for (int u = t; u < 8192; u += 512) s_cr[u] = cr[u];
        const float* wrow = g1w + (size_t)j * 2048;
        float w0 = wrow[4 * t], w1 = wrow[4 * t + 2];
        __syncthreads();
        float acc[8];
#pragma unroll
        for (int b = 0; b < 8; ++b) {
            float2 v = *(const float2*)(s_cr + b * 1024 + 2 * t);
            acc[b] = v.x * w0 + v.y * w1;
        }
#pragma unroll
        for (int d = 32; d > 0; d >>= 1) {
#pragma unroll
            for (int b = 0; b < 8; ++b) acc[b] += __shfl_down(acc[b], d, 64);
        }
        int wv = t >> 6;
        if ((t & 63) == 0) {
#pragma unroll
            for (int b = 0; b < 8; ++b) s_wave[wv * 8 + b] = acc[b];
        }
        __syncthreads();
        if (t < 8) {
            float a = g1b[j];
            for (int q = 0; q < 8; ++q) a += s_wave[q * 8 + t];
            hmid[t * 256 + j] = gelu_f(a);
        }
    }
}

// ---------------- inverse B: MFMA iDFT + conv (4-product hi/lo), fused inva + mlp2 ----------------
__global__ void __launch_bounds__(256, 3) k_invb(const float2* __restrict__ F,
                                                 const float* __restrict__ hin,
                                                 const float* __restrict__ cwTl,
                                                 const float* __restrict__ cbl,
                                                 const float* __restrict__ hmid,
                                                 const float* __restrict__ g2w,
                                                 const float* __restrict__ g2b,
                                                 const float2* __restrict__ trig,
                                                 const short* __restrict__ bt,
                                                 float* __restrict__ hout,
                                                 int do_gelu) {
    int blk = blockIdx.x;
    int b = blk >> 7, h = blk & 127;
    __shared__ __align__(16) short s_ht[2][128][72];       // hi/lo transposed h (36864B)
    __shared__ __align__(16) short s_ab[2 * 4 * 64 * 8];   // G A-frags hi/lo (8192B)
    __shared__ float s_co[64];
    __shared__ float s_part[4][64];
    int t = threadIdx.x;
    int lane = t & 63, wv = t >> 6;
    // ---- mlp2 partials ----
    {
        int o = t & 63, q = t >> 6;
        const float* hv = hmid + b * 256 + q * 64;
        const float* gw = g2w + o * 256 + q * 64;
        float a = 0.f;
#pragma unroll 8
        for (int v = 0; v < 64; ++v) a += hv[v] * gw[v];
        s_part[q][o] = a;
    }
    // ---- G-phase (table twiddles) -> hi/lo A-frags in LDS ----
    {
        int o = t & 63, ky0 = t >> 6;
        const float2* Fb = F + (size_t)b * 32768 + o;
        float ar[4] = {0.f, 0.f, 0.f, 0.f};
        float ai[4] = {0.f, 0.f, 0.f, 0.f};
#pragma unroll 4
        for (int m = 0; m < 32; ++m) {
            int kx = (m < 16) ? m : (96 + m);
            float2 wz = trig[(kx * h) & 127];      // block-uniform
            const float2* fm = Fb + m * 64;
#pragma unroll
            for (int j = 0; j < 4; ++j) {
                float2 f = fm[(ky0 + 4 * j) * 2048];
                ar[j] += f.x * wz.x - f.y * wz.y;
                ai[j] += f.x * wz.y + f.y * wz.x;
            }
        }
        int otile = o >> 4, ol = o & 15;
#pragma unroll
        for (int j = 0; j < 4; ++j) {
            unsigned short hr = f2bf(ar[j]);
            unsigned short hii = f2bf(ai[j]);
            unsigned short lr = f2bf(ar[j] - bf2f(hr));
            unsigned short li = f2bf(ai[j] - bf2f(hii));
            int lanei = (j << 4) | ol;
            *(unsigned int*)(s_ab + (otile * 64 + lanei) * 8 + 2 * ky0)
                = (unsigned int)hr | ((unsigned int)hii << 16);
            *(unsigned int*)(s_ab + ((4 + otile) * 64 + lanei) * 8 + 2 * ky0)
                = (unsigned int)lr | ((unsigned int)li << 16);
        }
    }
    // ---- stage hT hi/lo (coalesced global, bf16 split) ----
    {
        const float* hp = hin + (size_t)(b * 64) * 16384 + h * 128;
        for (int u = t; u < 8192; u += 256) {
            int c = u >> 7, w = u & 127;
            float x = hp[(size_t)c * 16384 + w];
            unsigned short hi = f2bf(x);
            s_ht[0][w][c] = (short)hi;
            s_ht[1][w][c] = (short)f2bf(x - bf2f(hi));
        }
    }
    __syncthreads();                               // (1) s_part/s_ab/s_ht stable
    if (t < 64)
        s_co[t] = s_part[0][t] + s_part[1][t] + s_part[2][t] + s_part[3][t]
                + g2b[t] + cbl[t];
    // ---- cw A-frags (hi/lo) direct from global (L2-hot 16KB) ----
    bf16x8 cwa_hi[2], cwa_lo[2];
    {
        int orow = wv * 16 + (lane & 15);
#pragma unroll
        for (int kc = 0; kc < 2; ++kc) {
#pragma unroll
            for (int e = 0; e < 8; ++e) {
                int c = kc * 32 + (lane >> 4) * 8 + e;
                float x = cwTl[c * 64 + orow];
                unsigned short hi = f2bf(x);
                cwa_hi[kc][e] = (short)hi;
                cwa_lo[kc][e] = (short)f2bf(x - bf2f(hi));
            }
        }
    }
    bf16x8 ga_hi = *(const bf16x8*)(s_ab + (wv * 64 + lane) * 8);
    bf16x8 ga_lo = *(const bf16x8*)(s_ab + ((4 + wv) * 64 + lane) * 8);
    __syncthreads();                               // (2) s_co visible
    // ---- MFMA loop: 8 w-tiles, 12 MFMA each (4-product splits) ----
#pragma unroll
    for (int wt = 0; wt < 8; ++wt) {
        f32x4 acc = {0.f, 0.f, 0.f, 0.f};
        bf16x8 bh = *(const bf16x8*)(bt + (wt * 64 + lane) * 8);
        bf16x8 bl = *(const bf16x8*)(bt + 4096 + (wt * 64 + lane) * 8);
        acc = __builtin_amdgcn_mfma_f32_16x16x32_bf16(ga_hi, bh, acc, 0, 0, 0);
        acc = __builtin_amdgcn_mfma_f32_16x16x32_bf16(ga_hi, bl, acc, 0, 0, 0);
        acc = __builtin_amdgcn_mfma_f32_16x16x32_bf16(ga_lo, bh, acc, 0, 0, 0);
        acc = __builtin_amdgcn_mfma_f32_16x16x32_bf16(ga_lo, bl, acc, 0, 0, 0);
#pragma unroll
        for (int kc = 0; kc < 2; ++kc) {
            const short* hb = &s_ht[0][wt * 16 + (lane & 15)][kc * 32 + (lane >> 4) * 8];
            const short* lb = &s_ht[1][wt * 16 + (lane & 15)][kc * 32 + (lane >> 4) * 8];
            bf16x8 hbh = *(const bf16x8*)hb;
            bf16x8 hbl = *(const bf16x8*)lb;
            acc = __builtin_amdgcn_mfma_f32_16x16x32_bf16(cwa_hi[kc], hbh, acc, 0, 0, 0);
            acc = __builtin_amdgcn_mfma_f32_16x16x32_bf16(cwa_hi[kc], hbl, acc, 0, 0, 0);
            acc = __builtin_amdgcn_mfma_f32_16x16x32_bf16(cwa_lo[kc], hbh, acc, 0, 0, 0);
            acc = __builtin_amdgcn_mfma_f32_16x16x32_bf16(cwa_lo[kc], hbl, acc, 0, 0, 0);
        }
        int wcol = wt * 16 + (lane & 15);
        int obase = wv * 16 + ((lane >> 4) << 2);
#pragma unroll
        for (int r = 0; r < 4; ++r) {
            int o = obase + r;
            float v = acc[r] + s_co[o];
            if (do_gelu) v = gelu_f(v);
            hout[((size_t)(b * 64 + o) * 128 + h) * 128 + wcol] = v;
        }
    }
}

// ---------------- FINAL layer: inverse B (fused inva + mlp2) + conv + head (scalar fp32) ----------------
__global__ void __launch_bounds__(256, 2) k_invbh(const float2* __restrict__ F,
                                                  const float* __restrict__ hin,
                                                  const float* __restrict__ cwTl,
                                                  const float* __restrict__ cbl,
                                                  const float* __restrict__ hmid,
                                                  const float* __restrict__ g2w,
                                                  const float* __restrict__ g2b,
                                                  const float2* __restrict__ trig,
                                                  const float* __restrict__ fc1wT,
                                                  const float* __restrict__ fc1b,
                                                  const float* __restrict__ fc2w,
                                                  const float* __restrict__ fc2b,
                                                  float* __restrict__ out) {
    int blk = blockIdx.x;                 // 0..951
    int b = blk / 119;
    int h = blk - b * 119;
    __shared__ __align__(16) char smem[32768];
    float*  s_cwT = (float*)smem;                 // [64][64]  (phase A)
    float2* s_g   = (float2*)(smem + 16384);      // [16][64]  (phase A)
    float*  s_hall= (float*)smem;                 // [64][128] (head overlay)
    __shared__ __align__(16) float s_w8[16][128]; // head weight chunk
    __shared__ float2 s_t[128];
    __shared__ float s_co[64];
    __shared__ float s_b1[128];
    __shared__ float s_w2[128];
    __shared__ float s_red[4][132];
    __shared__ float s_part[4][64];
    int t = threadIdx.x;
    if (t < 128) s_t[t] = trig[t];
    else { s_b1[t - 128] = fc1b[t - 128]; s_w2[t - 128] = fc2w[t - 128]; }
    for (int u = t; u < 4096; u += 256) s_cwT[u] = cwTl[u];
    {
        int o = t & 63, q = t >> 6;
        const float* hv = hmid + b * 256 + q * 64;
        const float* gw = g2w + o * 256 + q * 64;
        float a = 0.f;
#pragma unroll 8
        for (int v = 0; v < 64; ++v) a += hv[v] * gw[v];
        s_part[q][o] = a;
    }
    {
        int o = t & 63, ky0 = t >> 6;
        const float2* Fb = F + (size_t)b * 32768 + o;
        float a0r=0.f,a0i=0.f,a1r=0.f,a1i=0.f,a2r=0.f,a2i=0.f,a3r=0.f,a3i=0.f;
#pragma unroll 4
        for (int m = 0; m < 32; ++m) {
            int kx = (m < 16) ? m : (96 + m);
            float2 wz = trig[(kx * h) & 127];
            const float2* fm = Fb + m * 64;
            float2 f0 = fm[(ky0     ) * 2048];
            float2 f1 = fm[(ky0 +  4) * 2048];
            float2 f2 = fm[(ky0 +  8) * 2048];
            float2 f3 = fm[(ky0 + 12) * 2048];
            a0r += f0.x*wz.x - f0.y*wz.y; a0i += f0.x*wz.y + f0.y*wz.x;
            a1r += f1.x*wz.x - f1.y*wz.y; a1i += f1.x*wz.y + f1.y*wz.x;
            a2r += f2.x*wz.x - f2.y*wz.y; a2i += f2.x*wz.y + f2.y*wz.x;
            a3r += f3.x*wz.x - f3.y*wz.y; a3i += f3.x*wz.y + f3.y*wz.x;
        }
        float2* sg = (float2*)(smem + 16384);
        sg[(ky0     ) * 64 + o] = make_float2(a0r, a0i);
        sg[(ky0 +  4) * 64 + o] = make_float2(a1r, a1i);
        sg[(ky0 +  8) * 64 + o] = make_float2(a2r, a2i);
        sg[(ky0 + 12) * 64 + o] = make_float2(a3r, a3i);
    }
    __syncthreads();
    if (t < 64)
        s_co[t] = s_part[0][t] + s_part[1][t] + s_part[2][t] + s_part[3][t]
                + g2b[t] + cbl[t];
    int ot2 = t >> 6;
    int wt6 = t & 63;
    int o0 = ot2 * 16;
    float acc[16][2];
#pragma unroll
    for (int i = 0; i < 16; ++i) { acc[i][0] = 0.f; acc[i][1] = 0.f; }
    float2 rw0 = s_t[wt6];
    float2 rw1 = s_t[wt6 + 64];
    float z0r = 1.f, z0i = 0.f, z1r = 1.f, z1i = 0.f;
    const float invn = 1.0f / 16384.0f;
    for (int ky = 0; ky < 16; ++ky) {
        float fs = (ky == 0) ? invn : (2.f * invn);
        float tc0 = fs * z0r, ts0 = fs * z0i;
        float tc1 = fs * z1r, ts1 = fs * z1i;
        const float4* gk = (const float4*)(s_g + ky * 64 + o0);
#pragma unroll
        for (int i2 = 0; i2 < 8; ++i2) {
            float4 g2 = gk[i2];
            acc[2*i2][0]   += g2.x * tc0 - g2.y * ts0;
            acc[2*i2][1]   += g2.x * tc1 - g2.y * ts1;
            acc[2*i2+1][0] += g2.z * tc0 - g2.w * ts0;
            acc[2*i2+1][1] += g2.z * tc1 - g2.w * ts1;
        }
        float nz0 = z0r * rw0.x - z0i * rw0.y; z0i = z0r * rw0.y + z0i * rw0.x; z0r = nz0;
        float nz1 = z1r * rw1.x - z1i * rw1.y; z1i = z1r * rw1.y + z1i * rw1.x; z1r = nz1;
    }
    const float* hp = hin + ((size_t)(b * 64) * 128 + h) * 128;
    for (int cc = 0; cc < 64; cc += 8) {
        float hv0[8], hv1[8];
#pragma unroll
        for (int c = 0; c < 8; ++c) {
            hv0[c] = hp[(size_t)(cc + c) * 16384 + wt6];
            hv1[c] = hp[(size_t)(cc + c) * 16384 + wt6 + 64];
        }
#pragma unroll
        for (int c = 0; c < 8; ++c) {
            const float4* cwp = (const float4*)(s_cwT + (cc + c) * 64 + o0);
#pragma unroll
            for (int i4 = 0; i4 < 4; ++i4) {
                float4 cv = cwp[i4];
                acc[4*i4][0]   += cv.x * hv0[c]; acc[4*i4][1]   += cv.x * hv1[c];
                acc[4*i4+1][0] += cv.y * hv0[c]; acc[4*i4+1][1] += cv.y * hv1[c];
                acc[4*i4+2][0] += cv.z * hv0[c]; acc[4*i4+2][1] += cv.z * hv1[c];
                acc[4*i4+3][0] += cv.w * hv0[c]; acc[4*i4+3][1] += cv.w * hv1[c];
            }
        }
    }
    __syncthreads();
#pragma unroll
    for (int i = 0; i < 16; ++i) {
        float co = s_co[o0 + i];
        s_hall[(o0 + i) * 128 + wt6]      = acc[i][0] + co;
        s_hall[(o0 + i) * 128 + wt6 + 64] = acc[i][1] + co;
    }
    int j0 = ot2 * 32;
    float a32[32][2];
#pragma unroll
    for (int i = 0; i < 32; ++i) { a32[i][0] = 0.f; a32[i][1] = 0.f; }
    for (int cc = 0; cc < 64; cc += 16) {
        __syncthreads();
        for (int u = t; u < 2048; u += 256)
            s_w8[u >> 7][u & 127] = fc1wT[(cc + (u >> 7)) * 128 + (u & 127)];
        __syncthreads();
        for (int c = 0; c < 16; ++c) {
            float hv0 = s_hall[(cc + c) * 128 + wt6];
            float hv1 = s_hall[(cc + c) * 128 + wt6 + 64];
            const float4* wp = (const float4*)(&s_w8[c][j0]);
#pragma unroll
            for (int q = 0; q < 8; ++q) {
                float4 wx = wp[q];
                a32[4*q][0]   += wx.x * hv0; a32[4*q][1]   += wx.x * hv1;
                a32[4*q+1][0] += wx.y * hv0; a32[4*q+1][1] += wx.y * hv1;
                a32[4*q+2][0] += wx.z * hv0; a32[4*q+2][1] += wx.z * hv1;
                a32[4*q+3][0] += wx.w * hv0; a32[4*q+3][1] += wx.w * hv1;
            }
        }
    }
    float sum0 = 0.f, sum1 = 0.f;
#pragma unroll
    for (int i = 0; i < 32; ++i) {
        float b1 = s_b1[j0 + i];
        float w2 = s_w2[j0 + i];
        sum0 += gelu_f(a32[i][0] + b1) * w2;
        sum1 += gelu_f(a32[i][1] + b1) * w2;
    }
    s_red[ot2][wt6] = sum0;
    s_red[ot2][wt6 + 64] = sum1;
    __syncthreads();
    if (t < NS) {
        out[b * (NS * NS) + h * NS + t] =
            fc2b[0] + s_red[0][t] + s_red[1][t] + s_red[2][t] + s_red[3][t];
    }
}

extern "C" void kernel_launch(void* const* d_in, const int* in_sizes, int n_in,
                              void* d_out, int out_size, void* d_ws, size_t ws_size,
                              hipStream_t stream) {
    const float* x    = (const float*)d_in[0];
    const float* sw1r = (const float*)d_in[1];
    const float* sw1i = (const float*)d_in[2];
    const float* sw2r = (const float*)d_in[3];
    const float* sw2i = (const float*)d_in[4];
    const float* g1w  = (const float*)d_in[5];
    const float* g1b  = (const float*)d_in[6];
    const float* g2w  = (const float*)d_in[7];
    const float* g2b  = (const float*)d_in[8];
    const float* cw   = (const float*)d_in[9];
    const float* cb   = (const float*)d_in[10];
    const float* fc0w = (const float*)d_in[11];
    const float* fc0b = (const float*)d_in[12];
    const float* fc1w = (const float*)d_in[13];
    const float* fc1b = (const float*)d_in[14];
    const float* fc2w = (const float*)d_in[15];
    const float* fc2b = (const float*)d_in[16];
    float* out = (float*)d_out;

    char* ws = (char*)d_ws;
    const size_t SZ_H   = (size_t)NB * NC * NH * NW * 4;      // 33554432
    const size_t SZ_XFT = (size_t)NB * NC * 32 * 16 * 8;      // 2097152
    const size_t SZ_F   = SZ_XFT;                             // 2097152
    size_t off = 0;
    float2* trig = (float2*)(ws + off); off += 1024;
    short*  wmf  = (short*)(ws + off);  off += 4096 * 2;
    short*  bt   = (short*)(ws + off);  off += 8192 * 2;
    float*  f1T  = (float*)(ws + off);  off += 8192 * 4;
    float*  cwT  = (float*)(ws + off);  off += 16384 * 4;
    off = (off + 255) & ~(size_t)255;
    float*  hA   = (float*)(ws + off);  off += SZ_H;
    float*  hB   = (float*)(ws + off);  off += SZ_H;
    float2* xft  = (float2*)(ws + off); off += SZ_XFT;
    float2* F    = (float2*)(ws + off); off += SZ_F;
    float*  cr   = (float*)(ws + off);  off += (size_t)NB * NC * 16 * 4;
    float*  hmid = (float*)(ws + off);  off += (size_t)NB * 256 * 4;
    (void)ws_size; (void)in_sizes; (void)n_in; (void)out_size;

    k_trig<<<1, 128, 0, stream>>>(trig);
    k_tabm<<<16, 256, 0, stream>>>(wmf);
    k_tabi<<<16, 256, 0, stream>>>(bt);
    k_tc<<<96, 256, 0, stream>>>(fc1w, cw, f1T, cwT);
    k_fc0<<<512, 256, 0, stream>>>(x, fc0w, fc0b, hA);

    float* hcur = hA;
    float* hnxt = hB;
    for (int l = 0; l < 4; ++l) {
        const float* w1r = sw1r + (size_t)l * 1048576;
        const float* w1i = sw1i + (size_t)l * 1048576;
        const float* w2r = sw2r + (size_t)l * 1048576;
        const float* w2i = sw2i + (size_t)l * 1048576;
        const float* g1w_l = g1w + (size_t)l * 524288;
        const float* g1b_l = g1b + l * 256;
        const float* g2w_l = g2w + (size_t)l * 16384;
        const float* g2b_l = g2b + l * 64;
        const float* cwT_l = cwT + (size_t)l * 4096;
        const float* cb_l  = cb + l * 64;

        k_dft2<<<512, 256, 0, stream>>>(hcur, xft, cr, wmf, trig);
        k_mixmlp<<<768, 512, 0, stream>>>(xft, w1r, w1i, w2r, w2i,
                                          cr, g1w_l, g1b_l, hmid, F);
        if (l < 3) {
            k_invb<<<1024, 256, 0, stream>>>(F, hcur, cwT_l, cb_l, hmid,
                                             g2w_l, g2b_l, trig, bt, hnxt, 1);
            float* tmp = hcur; hcur = hnxt; hnxt = tmp;
        } else {
            k_invbh<<<NB * NS, 256, 0, stream>>>(F, hcur, cwT_l, cb_l, hmid,
                                                 g2w_l, g2b_l, trig,
                                                 f1T, fc1b, fc2w, fc2b, out);
        }
    }
}